// Round 2
// baseline (2759.475 us; speedup 1.0000x reference)
//
#include <hip/hip_runtime.h>

#define NNODE 20000
#define NE    600000
#define DF    128
#define DOUT  16
#define NB    64
#define RNG   313   // ceil(20000/64)

static inline int ceil_div(int a, int b) { return (a + b - 1) / b; }

// ---------------- CSR build, atomic-free (owner-computes) ----------------
struct RelA {
    const int* row; const int* col; const float* w;
    int* cnt; float* degS; float* degD; int self;
};
struct ParamsA { RelA r[4]; };

__global__ __launch_bounds__(256) void build_cnt_deg_k(ParamsA P) {
    __shared__ int   s_cnt[RNG];
    __shared__ float s_dS[RNG];
    __shared__ float s_dD[RNG];
    RelA R = P.r[blockIdx.y];
    int lo = blockIdx.x * RNG;
    int hi = lo + RNG; if (hi > NNODE) hi = NNODE;
    int rng = hi - lo;
    for (int i = threadIdx.x; i < RNG; i += 256) { s_cnt[i] = 0; s_dS[i] = 0.f; s_dD[i] = 0.f; }
    __syncthreads();
    bool hasS = (R.degS != nullptr);
    for (int e = threadIdx.x; e < NE; e += 256) {
        int c = R.col[e];
        float we = R.w[e];
        if ((unsigned)(c - lo) < (unsigned)rng) {
            atomicAdd(&s_cnt[c - lo], 1);
            atomicAdd(&s_dD[c - lo], we);
        }
        if (hasS) {
            int r = R.row[e];
            if ((unsigned)(r - lo) < (unsigned)rng) atomicAdd(&s_dS[r - lo], we);
        }
    }
    __syncthreads();
    for (int i = lo + threadIdx.x; i < hi; i += 256) {
        R.cnt[i]  = s_cnt[i - lo];
        R.degD[i] = s_dD[i - lo] + (R.self ? 1.0f : 0.0f);
        if (hasS) R.degS[i] = s_dS[i - lo];
    }
}

struct RelC {
    const int* row; const int* col; const float* w;
    const float* dinvS; const float* dinvD;
    const int* rowptr; int* esrc; float* enorm;
};
struct ParamsC { RelC r[4]; };

__global__ __launch_bounds__(256) void build_csr_k(ParamsC P) {
    __shared__ int s_cur[RNG];
    RelC R = P.r[blockIdx.y];
    int lo = blockIdx.x * RNG;
    int hi = lo + RNG; if (hi > NNODE) hi = NNODE;
    int rng = hi - lo;
    for (int i = threadIdx.x; i < RNG; i += 256) s_cur[i] = 0;
    __syncthreads();
    for (int e = threadIdx.x; e < NE; e += 256) {
        int c = R.col[e];
        if ((unsigned)(c - lo) < (unsigned)rng) {
            int r = R.row[e];
            float nrm = R.dinvS[r] * R.w[e] * R.dinvD[c];
            int pos = R.rowptr[c] + atomicAdd(&s_cur[c - lo], 1);
            R.esrc[pos]  = r;
            R.enorm[pos] = nrm;
        }
    }
}

__global__ void to_dinv_k(float* a, int n) {
    int i = blockIdx.x * blockDim.x + threadIdx.x;
    if (i < n) { float d = a[i]; a[i] = d > 0.f ? rsqrtf(d) : 0.f; }
}

// exclusive scan over NNODE counts per relation; blockIdx.x = relation
__global__ void exscan4_k(const int* __restrict__ cnt_all, int* __restrict__ rowptr_all) {
    __shared__ int sums[1024];
    const int* cnt = cnt_all + (size_t)blockIdx.x * NNODE;
    int* rowptr = rowptr_all + (size_t)blockIdx.x * (NNODE + 1);
    int t = threadIdx.x;
    int chunk = (NNODE + 1023) >> 10;
    int b = t * chunk; if (b > NNODE) b = NNODE;
    int e = b + chunk; if (e > NNODE) e = NNODE;
    int s = 0;
    for (int i = b; i < e; ++i) s += cnt[i];
    sums[t] = s;
    __syncthreads();
    for (int off = 1; off < 1024; off <<= 1) {
        int v = (t >= off) ? sums[t - off] : 0;
        __syncthreads();
        sums[t] += v;
        __syncthreads();
    }
    int run = (t == 0) ? 0 : sums[t - 1];
    for (int i = b; i < e; ++i) { rowptr[i] = run; run += cnt[i]; }
    if (t == 1023) rowptr[NNODE] = run;
}

// ---------------- SpMM / GEMM / heads (unchanged from R1) ----------------
__global__ __launch_bounds__(256) void spmm_k(const float* __restrict__ x,
                                              const int* __restrict__ rowptr,
                                              const int* __restrict__ esrc,
                                              const float* __restrict__ enorm,
                                              const float* __restrict__ dinv_self,
                                              float* __restrict__ out, int n) {
    int wid = (blockIdx.x * blockDim.x + threadIdx.x) >> 6;
    int lane = threadIdx.x & 63;
    if (wid >= n) return;
    float a0 = 0.f, a1 = 0.f;
    if (dinv_self) {
        float dv = dinv_self[wid];
        float sc = dv * dv;
        const float* xs = x + (size_t)wid * DF;
        a0 = xs[lane] * sc;
        a1 = xs[lane + 64] * sc;
    }
    int b = rowptr[wid], e = rowptr[wid + 1];
    int i = b;
    for (; i + 1 < e; i += 2) {
        int s0 = esrc[i], s1 = esrc[i + 1];
        float n0 = enorm[i], n1 = enorm[i + 1];
        const float* x0 = x + (size_t)s0 * DF;
        const float* x1 = x + (size_t)s1 * DF;
        a0 += x0[lane] * n0;
        a1 += x0[lane + 64] * n0;
        a0 += x1[lane] * n1;
        a1 += x1[lane + 64] * n1;
    }
    if (i < e) {
        int s0 = esrc[i];
        float n0 = enorm[i];
        const float* x0 = x + (size_t)s0 * DF;
        a0 += x0[lane] * n0;
        a1 += x0[lane + 64] * n0;
    }
    float* o = out + (size_t)wid * DF;
    o[lane] = a0;
    o[lane + 64] = a1;
}

__global__ __launch_bounds__(256) void gemm2_k(const float* __restrict__ A1,
                                               const float* __restrict__ A2,
                                               const float* __restrict__ Wa,
                                               const float* __restrict__ Wb,
                                               const float* __restrict__ ba,
                                               const float* __restrict__ bb,
                                               float* __restrict__ out, int n) {
    __shared__ float As[16][256];
    int r0 = blockIdx.x * 16;
    int t = threadIdx.x;
    for (int idx = t; idx < 16 * 256; idx += 256) {
        int r = idx >> 8, k = idx & 255;
        int row = r0 + r;
        float v = 0.f;
        if (row < n) v = (k < 128) ? A1[(size_t)row * 128 + k] : A2[(size_t)row * 128 + (k - 128)];
        As[r][k] = v;
    }
    __syncthreads();
    int col = t & 127;
    int rb = (t >> 7) * 8;  // 0 or 8
    float acc[8] = {0.f, 0.f, 0.f, 0.f, 0.f, 0.f, 0.f, 0.f};
    for (int k = 0; k < 128; ++k) {
        float wv = Wa[k * 128 + col];
#pragma unroll
        for (int r = 0; r < 8; ++r) acc[r] += As[rb + r][k] * wv;
    }
    for (int k = 0; k < 128; ++k) {
        float wv = Wb[k * 128 + col];
#pragma unroll
        for (int r = 0; r < 8; ++r) acc[r] += As[rb + r][k + 128] * wv;
    }
    float bias = ba[col] + bb[col];
#pragma unroll
    for (int r = 0; r < 8; ++r) {
        int row = r0 + rb + r;
        if (row < n) {
            float v = 0.5f * (acc[r] + bias);
            out[(size_t)row * 128 + col] = v > 0.f ? v : 0.f;
        }
    }
}

__global__ __launch_bounds__(256) void lin16_k(const float* __restrict__ x,
                                               const float* __restrict__ W,
                                               const float* __restrict__ b,
                                               float* __restrict__ out, int n) {
    int idx = blockIdx.x * blockDim.x + threadIdx.x;
    int row = idx >> 4, c = idx & 15;
    if (row >= n) return;
    const float* xr = x + (size_t)row * 128;
    float acc = b[c];
    for (int k = 0; k < 128; ++k) acc += xr[k] * W[k * 16 + c];
    out[(size_t)row * 16 + c] = acc;
}

extern "C" void kernel_launch(void* const* d_in, const int* in_sizes, int n_in,
                              void* d_out, int out_size, void* d_ws, size_t ws_size,
                              hipStream_t stream) {
    (void)in_sizes; (void)n_in; (void)out_size; (void)ws_size;

    const float* x_gen  = (const float*)d_in[0];
    const float* x_rain = (const float*)d_in[1];
    const int* ei_gg = (const int*)d_in[2];
    const int* ei_gr = (const int*)d_in[3];
    const int* ei_rg = (const int*)d_in[4];
    const int* ei_rr = (const int*)d_in[5];
    const float* w_gg = (const float*)d_in[6];
    const float* w_gr = (const float*)d_in[7];
    const float* w_rg = (const float*)d_in[8];
    const float* w_rr = (const float*)d_in[9];
    const float* W_conv = (const float*)d_in[10];  // [2][4][128][128]
    const float* b_conv = (const float*)d_in[11];  // [2][4][128]
    const float* W_lg = (const float*)d_in[12];
    const float* b_lg = (const float*)d_in[13];
    const float* W_lr = (const float*)d_in[14];
    const float* b_lr = (const float*)d_in[15];

    float* out_gen  = (float*)d_out;
    float* out_rain = out_gen + (size_t)NNODE * DOUT;

    char* p = (char*)d_ws;
    auto alloc = [&](size_t bytes) -> void* {
        void* r = (void*)p;
        p += (bytes + 255) & ~(size_t)255;
        return r;
    };

    // degree / dinv arrays: [gg | gr_s | gr_d | rg_s | rg_d | rr], each 20000 f32
    float* deg = (float*)alloc(6 * NNODE * sizeof(float));
    float* deg_gg   = deg;
    float* deg_gr_s = deg + 1 * NNODE;
    float* deg_gr_d = deg + 2 * NNODE;
    float* deg_rg_s = deg + 3 * NNODE;
    float* deg_rg_d = deg + 4 * NNODE;
    float* deg_rr   = deg + 5 * NNODE;

    int*   cnt_all    = (int*)alloc(4 * (size_t)NNODE * sizeof(int));
    int*   rowptr_all = (int*)alloc(4 * (size_t)(NNODE + 1) * sizeof(int));
    int*   esrc_all   = (int*)alloc(4 * (size_t)NE * sizeof(int));
    float* enorm_all  = (float*)alloc(4 * (size_t)NE * sizeof(float));

    float* agg_gg = (float*)alloc((size_t)NNODE * DF * sizeof(float));
    float* agg_gr = (float*)alloc((size_t)NNODE * DF * sizeof(float));
    float* agg_rg = (float*)alloc((size_t)NNODE * DF * sizeof(float));
    float* agg_rr = (float*)alloc((size_t)NNODE * DF * sizeof(float));
    float* xg_buf = (float*)alloc((size_t)NNODE * DF * sizeof(float));
    float* xr_buf = (float*)alloc((size_t)NNODE * DF * sizeof(float));

    int* cnt[4]; int* rowptr[4]; int* esrc[4]; float* enorm[4];
    for (int r = 0; r < 4; ++r) {
        cnt[r]    = cnt_all + (size_t)r * NNODE;
        rowptr[r] = rowptr_all + (size_t)r * (NNODE + 1);
        esrc[r]   = esrc_all + (size_t)r * NE;
        enorm[r]  = enorm_all + (size_t)r * NE;
    }

    // ---- phase A: counts + weighted degrees (no global atomics) ----
    ParamsA PA;
    PA.r[0] = { ei_gg, ei_gg + NE, w_gg, cnt[0], nullptr,  deg_gg,   1 };
    PA.r[1] = { ei_gr, ei_gr + NE, w_gr, cnt[1], deg_gr_s, deg_gr_d, 0 };
    PA.r[2] = { ei_rg, ei_rg + NE, w_rg, cnt[2], deg_rg_s, deg_rg_d, 0 };
    PA.r[3] = { ei_rr, ei_rr + NE, w_rr, cnt[3], nullptr,  deg_rr,   1 };
    build_cnt_deg_k<<<dim3(NB, 4), 256, 0, stream>>>(PA);

    exscan4_k<<<4, 1024, 0, stream>>>(cnt_all, rowptr_all);
    to_dinv_k<<<ceil_div(6 * NNODE, 256), 256, 0, stream>>>(deg, 6 * NNODE);

    // ---- phase C: CSR scatter with LDS cursors (no global atomics) ----
    ParamsC PC;
    PC.r[0] = { ei_gg, ei_gg + NE, w_gg, deg_gg,   deg_gg,   rowptr[0], esrc[0], enorm[0] };
    PC.r[1] = { ei_gr, ei_gr + NE, w_gr, deg_gr_s, deg_gr_d, rowptr[1], esrc[1], enorm[1] };
    PC.r[2] = { ei_rg, ei_rg + NE, w_rg, deg_rg_s, deg_rg_d, rowptr[2], esrc[2], enorm[2] };
    PC.r[3] = { ei_rr, ei_rr + NE, w_rr, deg_rr,   deg_rr,   rowptr[3], esrc[3], enorm[3] };
    build_csr_k<<<dim3(NB, 4), 256, 0, stream>>>(PC);

    // ---- layers ----
    int sb = ceil_div(NNODE, 4);  // 4 waves per block, 1 dst node per wave
    int gb = ceil_div(NNODE, 16);
    for (int l = 0; l < 2; ++l) {
        const float* xg = (l == 0) ? x_gen  : xg_buf;
        const float* xr = (l == 0) ? x_rain : xr_buf;
        spmm_k<<<sb, 256, 0, stream>>>(xg, rowptr[0], esrc[0], enorm[0], deg_gg, agg_gg, NNODE);
        spmm_k<<<sb, 256, 0, stream>>>(xg, rowptr[1], esrc[1], enorm[1], nullptr, agg_gr, NNODE);
        spmm_k<<<sb, 256, 0, stream>>>(xr, rowptr[2], esrc[2], enorm[2], nullptr, agg_rg, NNODE);
        spmm_k<<<sb, 256, 0, stream>>>(xr, rowptr[3], esrc[3], enorm[3], deg_rr, agg_rr, NNODE);
        const float* Wl = W_conv + (size_t)l * 4 * DF * DF;
        const float* bl = b_conv + (size_t)l * 4 * DF;
        gemm2_k<<<gb, 256, 0, stream>>>(agg_gg, agg_rg, Wl + 0 * DF * DF, Wl + 2 * DF * DF,
                                        bl + 0 * DF, bl + 2 * DF, xg_buf, NNODE);
        gemm2_k<<<gb, 256, 0, stream>>>(agg_gr, agg_rr, Wl + 1 * DF * DF, Wl + 3 * DF * DF,
                                        bl + 1 * DF, bl + 3 * DF, xr_buf, NNODE);
    }

    // ---- output heads ----
    lin16_k<<<ceil_div(NNODE * DOUT, 256), 256, 0, stream>>>(xg_buf, W_lg, b_lg, out_gen, NNODE);
    lin16_k<<<ceil_div(NNODE * DOUT, 256), 256, 0, stream>>>(xr_buf, W_lr, b_lr, out_rain, NNODE);
}

// Round 3
// 728.022 us; speedup vs baseline: 3.7904x; 3.7904x over previous
//
#include <hip/hip_runtime.h>

#define NNODE 20000
#define NE    600000
#define DF    128
#define DOUT  16

static inline int ceil_div(int a, int b) { return (a + b - 1) / b; }

// ---------------- phase A: count (returning slot) + src degrees ----------------
struct PassAP {
    const int* row[4]; const int* col[4]; const float* w[4];
    int* cnt[4]; float* degS[4]; int* eoff[4];
};
__global__ __launch_bounds__(256) void passA_k(PassAP P) {
    int r = blockIdx.y;
    int e = blockIdx.x * 256 + threadIdx.x;
    if (e >= NE) return;
    int c = P.col[r][e];
    P.eoff[r][e] = atomicAdd(&P.cnt[r][c], 1);
    float* dS = P.degS[r];
    if (dS) atomicAdd(&dS[P.row[r][e]], P.w[r][e]);
}

// exclusive scan over NNODE counts per relation; blockIdx.x = relation
__global__ void exscan4_k(const int* __restrict__ cnt_all, int* __restrict__ rowptr_all) {
    __shared__ int sums[1024];
    const int* cnt = cnt_all + (size_t)blockIdx.x * NNODE;
    int* rowptr = rowptr_all + (size_t)blockIdx.x * (NNODE + 1);
    int t = threadIdx.x;
    int chunk = (NNODE + 1023) >> 10;
    int b = t * chunk; if (b > NNODE) b = NNODE;
    int e = b + chunk; if (e > NNODE) e = NNODE;
    int s = 0;
    for (int i = b; i < e; ++i) s += cnt[i];
    sums[t] = s;
    __syncthreads();
    for (int off = 1; off < 1024; off <<= 1) {
        int v = (t >= off) ? sums[t - off] : 0;
        __syncthreads();
        sums[t] += v;
        __syncthreads();
    }
    int run = (t == 0) ? 0 : sums[t - 1];
    for (int i = b; i < e; ++i) { rowptr[i] = run; run += cnt[i]; }
    if (t == 1023) rowptr[NNODE] = run;
}

// ---------------- scatter: atomic-free (precomputed slots) ----------------
struct ScatP {
    const int* row[4]; const int* col[4]; const float* w[4];
    const int* rowptr[4]; const int* eoff[4];
    int* esrc[4]; float* ew[4];
};
__global__ __launch_bounds__(256) void scatterP_k(ScatP P) {
    int r = blockIdx.y;
    int e = blockIdx.x * 256 + threadIdx.x;
    if (e >= NE) return;
    int c = P.col[r][e];
    int pos = P.rowptr[r][c] + P.eoff[r][e];
    P.esrc[r][pos] = P.row[r][e];
    P.ew[r][pos]   = P.w[r][e];
}

// ---------------- dst degrees from CSR (segmented sum, no atomics) ----------------
struct DegDP { const int* rowptr[4]; const float* ew[4]; float* degD[4]; float selfw[4]; };
__global__ __launch_bounds__(256) void degD_k(DegDP P) {
    int r = blockIdx.y;
    int node = (blockIdx.x * 256 + threadIdx.x) >> 6;
    int lane = threadIdx.x & 63;
    if (node >= NNODE) return;
    int b = P.rowptr[r][node], e = P.rowptr[r][node + 1];
    float s = 0.f;
    for (int i = b + lane; i < e; i += 64) s += P.ew[r][i];
#pragma unroll
    for (int off = 32; off > 0; off >>= 1) s += __shfl_xor(s, off, 64);
    if (lane == 0) P.degD[r][node] = s + P.selfw[r];
}

__global__ void to_dinv_k(float* a, int n) {
    int i = blockIdx.x * blockDim.x + threadIdx.x;
    if (i < n) { float d = a[i]; a[i] = d > 0.f ? rsqrtf(d) : 0.f; }
}

// ---------------- edge norms in place on permuted weights ----------------
struct NormP { const int* rowptr[4]; const int* esrc[4]; const float* dinvS[4]; const float* dinvD[4]; float* ew[4]; };
__global__ __launch_bounds__(256) void enorm_k(NormP P) {
    int r = blockIdx.y;
    int node = (blockIdx.x * 256 + threadIdx.x) >> 6;
    int lane = threadIdx.x & 63;
    if (node >= NNODE) return;
    int b = P.rowptr[r][node], e = P.rowptr[r][node + 1];
    float dd = P.dinvD[r][node];
    const float* dS = P.dinvS[r];
    const int* es = P.esrc[r];
    float* ew = P.ew[r];
    for (int i = b + lane; i < e; i += 64) ew[i] = dS[es[i]] * ew[i] * dd;
}

// ---------------- pull-SpMM, 4 relations batched ----------------
struct SpmmP {
    const float* x[4]; const int* rowptr[4]; const int* esrc[4];
    const float* enorm[4]; const float* dinv_self[4]; float* out[4];
};
__global__ __launch_bounds__(256) void spmm4_k(SpmmP P) {
    int r = blockIdx.y;
    int wid = (blockIdx.x * 256 + threadIdx.x) >> 6;
    int lane = threadIdx.x & 63;
    if (wid >= NNODE) return;
    const float* x = P.x[r];
    float a0 = 0.f, a1 = 0.f;
    const float* ds = P.dinv_self[r];
    if (ds) {
        float dv = ds[wid];
        float sc = dv * dv;
        const float* xs = x + (size_t)wid * DF;
        a0 = xs[lane] * sc;
        a1 = xs[lane + 64] * sc;
    }
    const int* rp = P.rowptr[r];
    int b = rp[wid], e = rp[wid + 1];
    const int* es = P.esrc[r];
    const float* en = P.enorm[r];
    int i = b;
    for (; i + 1 < e; i += 2) {
        int s0 = es[i], s1 = es[i + 1];
        float n0 = en[i], n1 = en[i + 1];
        const float* x0 = x + (size_t)s0 * DF;
        const float* x1 = x + (size_t)s1 * DF;
        a0 += x0[lane] * n0;
        a1 += x0[lane + 64] * n0;
        a0 += x1[lane] * n1;
        a1 += x1[lane + 64] * n1;
    }
    if (i < e) {
        int s0 = es[i];
        float n0 = en[i];
        const float* x0 = x + (size_t)s0 * DF;
        a0 += x0[lane] * n0;
        a1 += x0[lane + 64] * n0;
    }
    float* o = P.out[r] + (size_t)wid * DF;
    o[lane] = a0;
    o[lane + 64] = a1;
}

// ---------------- fused 2-GEMM epilogue, 2 dst types batched ----------------
struct Gemm2P {
    const float* A1[2]; const float* A2[2];
    const float* Wa[2]; const float* Wb[2];
    const float* ba[2]; const float* bb[2];
    float* out[2];
};
__global__ __launch_bounds__(256) void gemm2_k(Gemm2P P) {
    __shared__ float As[16][256];
    int g = blockIdx.y;
    const float* A1 = P.A1[g]; const float* A2 = P.A2[g];
    int r0 = blockIdx.x * 16;
    int t = threadIdx.x;
    for (int idx = t; idx < 16 * 256; idx += 256) {
        int r = idx >> 8, k = idx & 255;
        int row = r0 + r;
        float v = 0.f;
        if (row < NNODE) v = (k < 128) ? A1[(size_t)row * 128 + k] : A2[(size_t)row * 128 + (k - 128)];
        As[r][k] = v;
    }
    __syncthreads();
    int col = t & 127;
    int rb = (t >> 7) * 8;  // 0 or 8
    const float* Wa = P.Wa[g]; const float* Wb = P.Wb[g];
    float acc[8] = {0.f, 0.f, 0.f, 0.f, 0.f, 0.f, 0.f, 0.f};
    for (int k = 0; k < 128; ++k) {
        float wv = Wa[k * 128 + col];
#pragma unroll
        for (int r = 0; r < 8; ++r) acc[r] += As[rb + r][k] * wv;
    }
    for (int k = 0; k < 128; ++k) {
        float wv = Wb[k * 128 + col];
#pragma unroll
        for (int r = 0; r < 8; ++r) acc[r] += As[rb + r][k + 128] * wv;
    }
    float bias = P.ba[g][col] + P.bb[g][col];
    float* out = P.out[g];
#pragma unroll
    for (int r = 0; r < 8; ++r) {
        int row = r0 + rb + r;
        if (row < NNODE) {
            float v = 0.5f * (acc[r] + bias);
            out[(size_t)row * 128 + col] = v > 0.f ? v : 0.f;
        }
    }
}

struct Lin16P { const float* x[2]; const float* W[2]; const float* b[2]; float* out[2]; };
__global__ __launch_bounds__(256) void lin16_k(Lin16P P) {
    int g = blockIdx.y;
    int idx = blockIdx.x * 256 + threadIdx.x;
    int row = idx >> 4, c = idx & 15;
    if (row >= NNODE) return;
    const float* xr = P.x[g] + (size_t)row * 128;
    const float* W = P.W[g];
    float acc = P.b[g][c];
    for (int k = 0; k < 128; ++k) acc += xr[k] * W[k * 16 + c];
    P.out[g][(size_t)row * 16 + c] = acc;
}

extern "C" void kernel_launch(void* const* d_in, const int* in_sizes, int n_in,
                              void* d_out, int out_size, void* d_ws, size_t ws_size,
                              hipStream_t stream) {
    (void)in_sizes; (void)n_in; (void)out_size; (void)ws_size;

    const float* x_gen  = (const float*)d_in[0];
    const float* x_rain = (const float*)d_in[1];
    const int* ei[4] = {(const int*)d_in[2], (const int*)d_in[3], (const int*)d_in[4], (const int*)d_in[5]};
    const float* w[4] = {(const float*)d_in[6], (const float*)d_in[7], (const float*)d_in[8], (const float*)d_in[9]};
    const float* W_conv = (const float*)d_in[10];  // [2][4][128][128]
    const float* b_conv = (const float*)d_in[11];  // [2][4][128]
    const float* W_lg = (const float*)d_in[12];
    const float* b_lg = (const float*)d_in[13];
    const float* W_lr = (const float*)d_in[14];
    const float* b_lr = (const float*)d_in[15];

    float* out_gen  = (float*)d_out;
    float* out_rain = out_gen + (size_t)NNODE * DOUT;

    char* p = (char*)d_ws;
    auto alloc = [&](size_t bytes) -> void* {
        void* r = (void*)p;
        p += (bytes + 255) & ~(size_t)255;
        return r;
    };

    // deg block: [gg | gr_s | gr_d | rg_s | rg_d | rr]  (6*N floats, 480000 B — 256-aligned)
    float* deg = (float*)alloc(6 * (size_t)NNODE * sizeof(float));
    float* deg_gg   = deg;
    float* deg_gr_s = deg + 1 * NNODE;
    float* deg_gr_d = deg + 2 * NNODE;
    float* deg_rg_s = deg + 3 * NNODE;
    float* deg_rg_d = deg + 4 * NNODE;
    float* deg_rr   = deg + 5 * NNODE;
    int*   cnt_all  = (int*)alloc(4 * (size_t)NNODE * sizeof(int));  // contiguous after deg

    int*   rowptr_all = (int*)alloc(4 * (size_t)(NNODE + 1) * sizeof(int));
    int*   esrc_all   = (int*)alloc(4 * (size_t)NE * sizeof(int));
    float* ew_all     = (float*)alloc(4 * (size_t)NE * sizeof(float));  // becomes enorm in place

    float* agg_all = (float*)alloc(4 * (size_t)NNODE * DF * sizeof(float));
    float* agg_gg = agg_all + 0 * (size_t)NNODE * DF;
    float* agg_gr = agg_all + 1 * (size_t)NNODE * DF;
    float* agg_rg = agg_all + 2 * (size_t)NNODE * DF;
    float* agg_rr = agg_all + 3 * (size_t)NNODE * DF;
    float* xg_buf = (float*)alloc((size_t)NNODE * DF * sizeof(float));
    float* xr_buf = (float*)alloc((size_t)NNODE * DF * sizeof(float));

    // eoff aliases agg_all (dead by the time spmm writes agg)
    int* eoff_all = (int*)agg_all;

    int* cnt[4]; int* rowptr[4]; int* esrc[4]; float* ew[4]; int* eoff[4];
    for (int r = 0; r < 4; ++r) {
        cnt[r]    = cnt_all + (size_t)r * NNODE;
        rowptr[r] = rowptr_all + (size_t)r * (NNODE + 1);
        esrc[r]   = esrc_all + (size_t)r * NE;
        ew[r]     = ew_all + (size_t)r * NE;
        eoff[r]   = eoff_all + (size_t)r * NE;
    }

    const int* rows_[4]  = {ei[0], ei[1], ei[2], ei[3]};
    const int* cols_[4]  = {ei[0] + NE, ei[1] + NE, ei[2] + NE, ei[3] + NE};

    int ge = ceil_div(NE, 256);
    int nwb = ceil_div(NNODE, 4);  // wave-per-node blocks (4 waves/block)

    // zero deg (480000 B) + cnt (320000 B) in one shot — they are contiguous
    hipMemsetAsync(deg, 0, 6 * (size_t)NNODE * sizeof(float) + 4 * (size_t)NNODE * sizeof(int), stream);

    // ---- phase A: counts (slot-returning) + source degrees ----
    PassAP PA;
    for (int r = 0; r < 4; ++r) {
        PA.row[r] = rows_[r]; PA.col[r] = cols_[r]; PA.w[r] = w[r];
        PA.cnt[r] = cnt[r]; PA.eoff[r] = eoff[r];
    }
    PA.degS[0] = nullptr; PA.degS[1] = deg_gr_s; PA.degS[2] = deg_rg_s; PA.degS[3] = nullptr;
    passA_k<<<dim3(ge, 4), 256, 0, stream>>>(PA);

    exscan4_k<<<4, 1024, 0, stream>>>(cnt_all, rowptr_all);

    // ---- scatter (atomic-free) ----
    ScatP SC;
    for (int r = 0; r < 4; ++r) {
        SC.row[r] = rows_[r]; SC.col[r] = cols_[r]; SC.w[r] = w[r];
        SC.rowptr[r] = rowptr[r]; SC.eoff[r] = eoff[r];
        SC.esrc[r] = esrc[r]; SC.ew[r] = ew[r];
    }
    scatterP_k<<<dim3(ge, 4), 256, 0, stream>>>(SC);

    // ---- dst degrees from CSR ----
    DegDP DD;
    for (int r = 0; r < 4; ++r) { DD.rowptr[r] = rowptr[r]; DD.ew[r] = ew[r]; }
    DD.degD[0] = deg_gg; DD.degD[1] = deg_gr_d; DD.degD[2] = deg_rg_d; DD.degD[3] = deg_rr;
    DD.selfw[0] = 1.f; DD.selfw[1] = 0.f; DD.selfw[2] = 0.f; DD.selfw[3] = 1.f;
    degD_k<<<dim3(nwb, 4), 256, 0, stream>>>(DD);

    to_dinv_k<<<ceil_div(6 * NNODE, 256), 256, 0, stream>>>(deg, 6 * NNODE);

    // ---- edge norms in place ----
    NormP NP;
    for (int r = 0; r < 4; ++r) { NP.rowptr[r] = rowptr[r]; NP.esrc[r] = esrc[r]; NP.ew[r] = ew[r]; }
    NP.dinvS[0] = deg_gg;   NP.dinvD[0] = deg_gg;
    NP.dinvS[1] = deg_gr_s; NP.dinvD[1] = deg_gr_d;
    NP.dinvS[2] = deg_rg_s; NP.dinvD[2] = deg_rg_d;
    NP.dinvS[3] = deg_rr;   NP.dinvD[3] = deg_rr;
    enorm_k<<<dim3(nwb, 4), 256, 0, stream>>>(NP);

    // ---- layers ----
    for (int l = 0; l < 2; ++l) {
        const float* xg = (l == 0) ? x_gen  : xg_buf;
        const float* xr = (l == 0) ? x_rain : xr_buf;
        SpmmP SP;
        for (int r = 0; r < 4; ++r) {
            SP.rowptr[r] = rowptr[r]; SP.esrc[r] = esrc[r]; SP.enorm[r] = ew[r];
        }
        SP.x[0] = xg; SP.x[1] = xg; SP.x[2] = xr; SP.x[3] = xr;
        SP.dinv_self[0] = deg_gg; SP.dinv_self[1] = nullptr; SP.dinv_self[2] = nullptr; SP.dinv_self[3] = deg_rr;
        SP.out[0] = agg_gg; SP.out[1] = agg_gr; SP.out[2] = agg_rg; SP.out[3] = agg_rr;
        spmm4_k<<<dim3(nwb, 4), 256, 0, stream>>>(SP);

        const float* Wl = W_conv + (size_t)l * 4 * DF * DF;
        const float* bl = b_conv + (size_t)l * 4 * DF;
        Gemm2P GP;
        GP.A1[0] = agg_gg; GP.A2[0] = agg_rg;
        GP.Wa[0] = Wl + 0 * DF * DF; GP.Wb[0] = Wl + 2 * DF * DF;
        GP.ba[0] = bl + 0 * DF; GP.bb[0] = bl + 2 * DF;
        GP.out[0] = xg_buf;
        GP.A1[1] = agg_gr; GP.A2[1] = agg_rr;
        GP.Wa[1] = Wl + 1 * DF * DF; GP.Wb[1] = Wl + 3 * DF * DF;
        GP.ba[1] = bl + 1 * DF; GP.bb[1] = bl + 3 * DF;
        GP.out[1] = xr_buf;
        gemm2_k<<<dim3(ceil_div(NNODE, 16), 2), 256, 0, stream>>>(GP);
    }

    // ---- output heads ----
    Lin16P LP;
    LP.x[0] = xg_buf; LP.W[0] = W_lg; LP.b[0] = b_lg; LP.out[0] = out_gen;
    LP.x[1] = xr_buf; LP.W[1] = W_lr; LP.b[1] = b_lr; LP.out[1] = out_rain;
    lin16_k<<<dim3(ceil_div(NNODE * DOUT, 256), 2), 256, 0, stream>>>(LP);
}

// Round 4
// 662.567 us; speedup vs baseline: 4.1648x; 1.0988x over previous
//
#include <hip/hip_runtime.h>
#include <hip/hip_fp16.h>

#define NNODE 20000
#define NE    600000
#define DF    128
#define DOUT  16

static inline int ceil_div(int a, int b) { return (a + b - 1) / b; }

// ---------------- fp32 -> fp16 conversion (4 floats/thread) ----------------
struct CvtP { const float* in[2]; __half* out[2]; };
__global__ __launch_bounds__(256) void cvt_k(CvtP P) {
    int g = blockIdx.y;
    int i = blockIdx.x * 256 + threadIdx.x;           // float4 index
    const float4* in = (const float4*)P.in[g];
    __half2* out = (__half2*)P.out[g];
    float4 v = in[i];
    out[2 * i + 0] = __floats2half2_rn(v.x, v.y);
    out[2 * i + 1] = __floats2half2_rn(v.z, v.w);
}

// ---------------- phase A: count (returning slot) + src degrees ----------------
struct PassAP {
    const int* row[4]; const int* col[4]; const float* w[4];
    int* cnt[4]; float* degS[4]; int* eoff[4];
};
__global__ __launch_bounds__(256) void passA_k(PassAP P) {
    int r = blockIdx.y;
    int e = blockIdx.x * 256 + threadIdx.x;
    if (e >= NE) return;
    int c = P.col[r][e];
    P.eoff[r][e] = atomicAdd(&P.cnt[r][c], 1);
    float* dS = P.degS[r];
    if (dS) atomicAdd(&dS[P.row[r][e]], P.w[r][e]);
}

// exclusive scan over NNODE counts per relation; blockIdx.x = relation
__global__ void exscan4_k(const int* __restrict__ cnt_all, int* __restrict__ rowptr_all) {
    __shared__ int sums[1024];
    const int* cnt = cnt_all + (size_t)blockIdx.x * NNODE;
    int* rowptr = rowptr_all + (size_t)blockIdx.x * (NNODE + 1);
    int t = threadIdx.x;
    int chunk = (NNODE + 1023) >> 10;
    int b = t * chunk; if (b > NNODE) b = NNODE;
    int e = b + chunk; if (e > NNODE) e = NNODE;
    int s = 0;
    for (int i = b; i < e; ++i) s += cnt[i];
    sums[t] = s;
    __syncthreads();
    for (int off = 1; off < 1024; off <<= 1) {
        int v = (t >= off) ? sums[t - off] : 0;
        __syncthreads();
        sums[t] += v;
        __syncthreads();
    }
    int run = (t == 0) ? 0 : sums[t - 1];
    for (int i = b; i < e; ++i) { rowptr[i] = run; run += cnt[i]; }
    if (t == 1023) rowptr[NNODE] = run;
}

// ---------------- scatter: atomic-free (precomputed slots), int2 records ----------------
struct ScatP {
    const int* row[4]; const int* col[4]; const float* w[4];
    const int* rowptr[4]; const int* eoff[4];
    int2* edges[4];
};
__global__ __launch_bounds__(256) void scatterP_k(ScatP P) {
    int r = blockIdx.y;
    int e = blockIdx.x * 256 + threadIdx.x;
    if (e >= NE) return;
    int c = P.col[r][e];
    int pos = P.rowptr[r][c] + P.eoff[r][e];
    int2 v;
    v.x = P.row[r][e];
    v.y = __float_as_int(P.w[r][e]);
    P.edges[r][pos] = v;
}

// ---------------- dst degrees from CSR -> dinv directly (rsqrt folded) ----------------
struct DegDP { const int* rowptr[4]; const int2* edges[4]; float* dinvD[4]; float selfw[4]; };
__global__ __launch_bounds__(256) void degD_k(DegDP P) {
    int r = blockIdx.y;
    int node = (blockIdx.x * 256 + threadIdx.x) >> 6;
    int lane = threadIdx.x & 63;
    if (node >= NNODE) return;
    int b = P.rowptr[r][node], e = P.rowptr[r][node + 1];
    const int2* ed = P.edges[r];
    float s = 0.f;
    for (int i = b + lane; i < e; i += 64) s += __int_as_float(ed[i].y);
#pragma unroll
    for (int off = 32; off > 0; off >>= 1) s += __shfl_xor(s, off, 64);
    if (lane == 0) {
        float d = s + P.selfw[r];
        P.dinvD[r][node] = d > 0.f ? rsqrtf(d) : 0.f;
    }
}

__global__ void to_dinv_k(float* a, int n) {
    int i = blockIdx.x * blockDim.x + threadIdx.x;
    if (i < n) { float d = a[i]; a[i] = d > 0.f ? rsqrtf(d) : 0.f; }
}

// ---------------- pull-SpMM, fp16 gather, norm folded, 4 relations batched ----------------
struct SpmmP {
    const __half* x[4]; const int* rowptr[4]; const int2* edges[4];
    const float* dinvS[4]; const float* dinvD[4]; float* out[4]; int self[4];
};
__global__ __launch_bounds__(256) void spmm4_k(SpmmP P) {
    int r = blockIdx.y;
    int wid = (blockIdx.x * 256 + threadIdx.x) >> 6;
    int lane = threadIdx.x & 63;
    if (wid >= NNODE) return;
    const __half2* x = (const __half2*)P.x[r];  // row stride = 64 half2
    float dd = P.dinvD[r][wid];
    float a0 = 0.f, a1 = 0.f;
    if (P.self[r]) {
        float sc = dd * dd;
        float2 f = __half22float2(x[(size_t)wid * 64 + lane]);
        a0 = f.x * sc;
        a1 = f.y * sc;
    }
    const float* dS = P.dinvS[r];
    const int* rp = P.rowptr[r];
    int b = rp[wid], e = rp[wid + 1];
    const int2* ed = P.edges[r];
    int i = b;
    for (; i + 1 < e; i += 2) {
        int2 m0 = ed[i], m1 = ed[i + 1];
        float n0 = dS[m0.x] * __int_as_float(m0.y) * dd;
        float n1 = dS[m1.x] * __int_as_float(m1.y) * dd;
        float2 f0 = __half22float2(x[(size_t)m0.x * 64 + lane]);
        float2 f1 = __half22float2(x[(size_t)m1.x * 64 + lane]);
        a0 += f0.x * n0; a1 += f0.y * n0;
        a0 += f1.x * n1; a1 += f1.y * n1;
    }
    if (i < e) {
        int2 m0 = ed[i];
        float n0 = dS[m0.x] * __int_as_float(m0.y) * dd;
        float2 f0 = __half22float2(x[(size_t)m0.x * 64 + lane]);
        a0 += f0.x * n0; a1 += f0.y * n0;
    }
    float2* o = (float2*)(P.out[r] + (size_t)wid * DF);
    o[lane] = make_float2(a0, a1);
}

// ---------------- fused 2-GEMM epilogue -> fp16 out, 2 dst types batched ----------------
struct Gemm2P {
    const float* A1[2]; const float* A2[2];
    const float* Wa[2]; const float* Wb[2];
    const float* ba[2]; const float* bb[2];
    __half* out[2];
};
__global__ __launch_bounds__(256) void gemm2_k(Gemm2P P) {
    __shared__ float As[16][256];
    int g = blockIdx.y;
    const float* A1 = P.A1[g]; const float* A2 = P.A2[g];
    int r0 = blockIdx.x * 16;
    int t = threadIdx.x;
    for (int idx = t; idx < 16 * 256; idx += 256) {
        int r = idx >> 8, k = idx & 255;
        int row = r0 + r;
        float v = 0.f;
        if (row < NNODE) v = (k < 128) ? A1[(size_t)row * 128 + k] : A2[(size_t)row * 128 + (k - 128)];
        As[r][k] = v;
    }
    __syncthreads();
    int col = t & 127;
    int rb = (t >> 7) * 8;  // 0 or 8
    const float* Wa = P.Wa[g]; const float* Wb = P.Wb[g];
    float acc[8] = {0.f, 0.f, 0.f, 0.f, 0.f, 0.f, 0.f, 0.f};
    for (int k = 0; k < 128; ++k) {
        float wv = Wa[k * 128 + col];
#pragma unroll
        for (int r = 0; r < 8; ++r) acc[r] += As[rb + r][k] * wv;
    }
    for (int k = 0; k < 128; ++k) {
        float wv = Wb[k * 128 + col];
#pragma unroll
        for (int r = 0; r < 8; ++r) acc[r] += As[rb + r][k + 128] * wv;
    }
    float bias = P.ba[g][col] + P.bb[g][col];
    __half* out = P.out[g];
#pragma unroll
    for (int r = 0; r < 8; ++r) {
        int row = r0 + rb + r;
        if (row < NNODE) {
            float v = 0.5f * (acc[r] + bias);
            out[(size_t)row * 128 + col] = __float2half(v > 0.f ? v : 0.f);
        }
    }
}

struct Lin16P { const __half* x[2]; const float* W[2]; const float* b[2]; float* out[2]; };
__global__ __launch_bounds__(256) void lin16_k(Lin16P P) {
    int g = blockIdx.y;
    int idx = blockIdx.x * 256 + threadIdx.x;
    int row = idx >> 4, c = idx & 15;
    if (row >= NNODE) return;
    const __half* xr = P.x[g] + (size_t)row * 128;
    const float* W = P.W[g];
    float acc = P.b[g][c];
    for (int k = 0; k < 128; ++k) acc += __half2float(xr[k]) * W[k * 16 + c];
    P.out[g][(size_t)row * 16 + c] = acc;
}

extern "C" void kernel_launch(void* const* d_in, const int* in_sizes, int n_in,
                              void* d_out, int out_size, void* d_ws, size_t ws_size,
                              hipStream_t stream) {
    (void)in_sizes; (void)n_in; (void)out_size; (void)ws_size;

    const float* x_gen  = (const float*)d_in[0];
    const float* x_rain = (const float*)d_in[1];
    const int* ei[4] = {(const int*)d_in[2], (const int*)d_in[3], (const int*)d_in[4], (const int*)d_in[5]};
    const float* w[4] = {(const float*)d_in[6], (const float*)d_in[7], (const float*)d_in[8], (const float*)d_in[9]};
    const float* W_conv = (const float*)d_in[10];  // [2][4][128][128]
    const float* b_conv = (const float*)d_in[11];  // [2][4][128]
    const float* W_lg = (const float*)d_in[12];
    const float* b_lg = (const float*)d_in[13];
    const float* W_lr = (const float*)d_in[14];
    const float* b_lr = (const float*)d_in[15];

    float* out_gen  = (float*)d_out;
    float* out_rain = out_gen + (size_t)NNODE * DOUT;

    char* p = (char*)d_ws;
    auto alloc = [&](size_t bytes) -> void* {
        void* r = (void*)p;
        p += (bytes + 255) & ~(size_t)255;
        return r;
    };

    // deg layout: [gr_s | rg_s | gg | gr_d | rg_d | rr] so the 2 atomic-built
    // src-degree arrays are contiguous at the front (to_dinv over them only).
    float* deg = (float*)alloc(6 * (size_t)NNODE * sizeof(float));
    float* dinv_gr_s = deg + 0 * NNODE;
    float* dinv_rg_s = deg + 1 * NNODE;
    float* dinv_gg   = deg + 2 * NNODE;
    float* dinv_gr_d = deg + 3 * NNODE;
    float* dinv_rg_d = deg + 4 * NNODE;
    float* dinv_rr   = deg + 5 * NNODE;
    int*   cnt_all  = (int*)alloc(4 * (size_t)NNODE * sizeof(int));  // contiguous after deg

    int*  rowptr_all = (int*)alloc(4 * (size_t)(NNODE + 1) * sizeof(int));
    int2* edges_all  = (int2*)alloc(4 * (size_t)NE * sizeof(int2));

    float* agg_all = (float*)alloc(4 * (size_t)NNODE * DF * sizeof(float));
    float* agg_gg = agg_all + 0 * (size_t)NNODE * DF;
    float* agg_gr = agg_all + 1 * (size_t)NNODE * DF;
    float* agg_rg = agg_all + 2 * (size_t)NNODE * DF;
    float* agg_rr = agg_all + 3 * (size_t)NNODE * DF;
    __half* xh_gen  = (__half*)alloc((size_t)NNODE * DF * sizeof(__half));
    __half* xh_rain = (__half*)alloc((size_t)NNODE * DF * sizeof(__half));

    // eoff aliases agg_all (dead by the time spmm writes agg)
    int* eoff_all = (int*)agg_all;

    int* cnt[4]; int* rowptr[4]; int2* edges[4]; int* eoff[4];
    for (int r = 0; r < 4; ++r) {
        cnt[r]    = cnt_all + (size_t)r * NNODE;
        rowptr[r] = rowptr_all + (size_t)r * (NNODE + 1);
        edges[r]  = edges_all + (size_t)r * NE;
        eoff[r]   = eoff_all + (size_t)r * NE;
    }

    const int* rows_[4]  = {ei[0], ei[1], ei[2], ei[3]};
    const int* cols_[4]  = {ei[0] + NE, ei[1] + NE, ei[2] + NE, ei[3] + NE};

    int ge = ceil_div(NE, 256);
    int nwb = ceil_div(NNODE, 4);  // wave-per-node blocks (4 waves/block)

    // zero deg (6N f32) + cnt (4N i32) in one contiguous shot
    hipMemsetAsync(deg, 0, 6 * (size_t)NNODE * sizeof(float) + 4 * (size_t)NNODE * sizeof(int), stream);

    // ---- fp16 conversion of layer-0 features (independent of CSR build) ----
    CvtP CV;
    CV.in[0] = x_gen;  CV.out[0] = xh_gen;
    CV.in[1] = x_rain; CV.out[1] = xh_rain;
    cvt_k<<<dim3(NNODE * DF / 4 / 256, 2), 256, 0, stream>>>(CV);

    // ---- phase A: counts (slot-returning) + source degrees ----
    PassAP PA;
    for (int r = 0; r < 4; ++r) {
        PA.row[r] = rows_[r]; PA.col[r] = cols_[r]; PA.w[r] = w[r];
        PA.cnt[r] = cnt[r]; PA.eoff[r] = eoff[r];
    }
    PA.degS[0] = nullptr; PA.degS[1] = dinv_gr_s; PA.degS[2] = dinv_rg_s; PA.degS[3] = nullptr;
    passA_k<<<dim3(ge, 4), 256, 0, stream>>>(PA);

    exscan4_k<<<4, 1024, 0, stream>>>(cnt_all, rowptr_all);

    // ---- scatter (atomic-free) ----
    ScatP SC;
    for (int r = 0; r < 4; ++r) {
        SC.row[r] = rows_[r]; SC.col[r] = cols_[r]; SC.w[r] = w[r];
        SC.rowptr[r] = rowptr[r]; SC.eoff[r] = eoff[r];
        SC.edges[r] = edges[r];
    }
    scatterP_k<<<dim3(ge, 4), 256, 0, stream>>>(SC);

    // ---- dst degrees -> dinv (rsqrt folded) ----
    DegDP DD;
    for (int r = 0; r < 4; ++r) { DD.rowptr[r] = rowptr[r]; DD.edges[r] = edges[r]; }
    DD.dinvD[0] = dinv_gg; DD.dinvD[1] = dinv_gr_d; DD.dinvD[2] = dinv_rg_d; DD.dinvD[3] = dinv_rr;
    DD.selfw[0] = 1.f; DD.selfw[1] = 0.f; DD.selfw[2] = 0.f; DD.selfw[3] = 1.f;
    degD_k<<<dim3(nwb, 4), 256, 0, stream>>>(DD);

    // src-degree arrays (atomic-built raw sums) -> dinv
    to_dinv_k<<<ceil_div(2 * NNODE, 256), 256, 0, stream>>>(deg, 2 * NNODE);

    // ---- layers ----
    for (int l = 0; l < 2; ++l) {
        SpmmP SP;
        for (int r = 0; r < 4; ++r) { SP.rowptr[r] = rowptr[r]; SP.edges[r] = edges[r]; }
        SP.x[0] = xh_gen; SP.x[1] = xh_gen; SP.x[2] = xh_rain; SP.x[3] = xh_rain;
        SP.dinvS[0] = dinv_gg;   SP.dinvD[0] = dinv_gg;
        SP.dinvS[1] = dinv_gr_s; SP.dinvD[1] = dinv_gr_d;
        SP.dinvS[2] = dinv_rg_s; SP.dinvD[2] = dinv_rg_d;
        SP.dinvS[3] = dinv_rr;   SP.dinvD[3] = dinv_rr;
        SP.self[0] = 1; SP.self[1] = 0; SP.self[2] = 0; SP.self[3] = 1;
        SP.out[0] = agg_gg; SP.out[1] = agg_gr; SP.out[2] = agg_rg; SP.out[3] = agg_rr;
        spmm4_k<<<dim3(nwb, 4), 256, 0, stream>>>(SP);

        const float* Wl = W_conv + (size_t)l * 4 * DF * DF;
        const float* bl = b_conv + (size_t)l * 4 * DF;
        Gemm2P GP;
        GP.A1[0] = agg_gg; GP.A2[0] = agg_rg;
        GP.Wa[0] = Wl + 0 * DF * DF; GP.Wb[0] = Wl + 2 * DF * DF;
        GP.ba[0] = bl + 0 * DF; GP.bb[0] = bl + 2 * DF;
        GP.out[0] = xh_gen;
        GP.A1[1] = agg_gr; GP.A2[1] = agg_rr;
        GP.Wa[1] = Wl + 1 * DF * DF; GP.Wb[1] = Wl + 3 * DF * DF;
        GP.ba[1] = bl + 1 * DF; GP.bb[1] = bl + 3 * DF;
        GP.out[1] = xh_rain;
        gemm2_k<<<dim3(ceil_div(NNODE, 16), 2), 256, 0, stream>>>(GP);
    }

    // ---- output heads ----
    Lin16P LP;
    LP.x[0] = xh_gen;  LP.W[0] = W_lg; LP.b[0] = b_lg; LP.out[0] = out_gen;
    LP.x[1] = xh_rain; LP.W[1] = W_lr; LP.b[1] = b_lr; LP.out[1] = out_rain;
    lin16_k<<<dim3(ceil_div(NNODE * DOUT, 256), 2), 256, 0, stream>>>(LP);
}

// Round 5
// 570.567 us; speedup vs baseline: 4.8364x; 1.1612x over previous
//
#include <hip/hip_runtime.h>
#include <hip/hip_fp16.h>

#define NNODE 20000
#define NE    600000
#define DF    128
#define DOUT  16
#define NB    64          // hist blocks per relation
#define CE    (NE/NB)     // 9375 edges per hist block (exact)
#define NWORD 10000       // packed 16-bit pairs covering 20000 nodes
#define SB    32          // degS chunks per relation
#define CS    (NE/SB)     // 18750 edges per degS chunk (exact)

static inline int ceil_div(int a, int b) { return (a + b - 1) / b; }

// ---------------- fp32 -> fp16 conversion (4 floats/thread) ----------------
struct CvtP { const float* in[2]; __half* out[2]; };
__global__ __launch_bounds__(256) void cvt_k(CvtP P) {
    int g = blockIdx.y;
    int i = blockIdx.x * 256 + threadIdx.x;           // float4 index
    const float4* in = (const float4*)P.in[g];
    __half2* out = (__half2*)P.out[g];
    float4 v = in[i];
    out[2 * i + 0] = __floats2half2_rn(v.x, v.y);
    out[2 * i + 1] = __floats2half2_rn(v.z, v.w);
}

// ---------------- phase H: per-chunk packed histogram + local slots (LDS atomics only) ----------------
struct HistP { const int* col[4]; unsigned int* hist; unsigned short* loc[4]; };
__global__ __launch_bounds__(256) void hist_k(HistP P) {
    __shared__ unsigned int h[NWORD];   // 40 KB, 2x16-bit counts per word
    int b = blockIdx.x, r = blockIdx.y;
    for (int i = threadIdx.x; i < NWORD; i += 256) h[i] = 0u;
    __syncthreads();
    const int* col = P.col[r];
    unsigned short* loc = P.loc[r];
    int e0 = b * CE;
    for (int e = e0 + threadIdx.x; e < e0 + CE; e += 256) {
        int c = col[e];
        unsigned int sh = (unsigned)(c & 1) << 4;
        unsigned int old = atomicAdd(&h[c >> 1], 1u << sh);
        loc[e] = (unsigned short)((old >> sh) & 0xffffu);
    }
    __syncthreads();
    unsigned int* hg = P.hist + (size_t)(r * NB + b) * NWORD;
    for (int i = threadIdx.x; i < NWORD; i += 256) hg[i] = h[i];
}

// ---------------- per-node totals from histograms ----------------
__global__ __launch_bounds__(256) void sumcnt_k(const unsigned int* __restrict__ hist,
                                                int* __restrict__ cnt_all) {
    int r = blockIdx.y;
    int w = blockIdx.x * 256 + threadIdx.x;
    if (w >= NWORD) return;
    unsigned int lo = 0, hi = 0;
    const unsigned int* hp = hist + (size_t)r * NB * NWORD + w;
    for (int b = 0; b < NB; ++b) {
        unsigned int v = hp[(size_t)b * NWORD];
        lo += v & 0xffffu; hi += v >> 16;
    }
    int* cnt = cnt_all + (size_t)r * NNODE;
    cnt[2 * w] = (int)lo;
    cnt[2 * w + 1] = (int)hi;
}

// exclusive scan over NNODE counts per relation; blockIdx.x = relation
__global__ void exscan4_k(const int* __restrict__ cnt_all, int* __restrict__ rowptr_all) {
    __shared__ int sums[1024];
    const int* cnt = cnt_all + (size_t)blockIdx.x * NNODE;
    int* rowptr = rowptr_all + (size_t)blockIdx.x * (NNODE + 1);
    int t = threadIdx.x;
    int chunk = (NNODE + 1023) >> 10;
    int b = t * chunk; if (b > NNODE) b = NNODE;
    int e = b + chunk; if (e > NNODE) e = NNODE;
    int s = 0;
    for (int i = b; i < e; ++i) s += cnt[i];
    sums[t] = s;
    __syncthreads();
    for (int off = 1; off < 1024; off <<= 1) {
        int v = (t >= off) ? sums[t - off] : 0;
        __syncthreads();
        sums[t] += v;
        __syncthreads();
    }
    int run = (t == 0) ? 0 : sums[t - 1];
    for (int i = b; i < e; ++i) { rowptr[i] = run; run += cnt[i]; }
    if (t == 1023) rowptr[NNODE] = run;
}

// ---------------- per-(block,node) global bases: prefix along block axis ----------------
__global__ __launch_bounds__(256) void mkbase_k(const unsigned int* __restrict__ hist,
                                               const int* __restrict__ rowptr_all,
                                               int* __restrict__ base) {
    int r = blockIdx.y;
    int w = blockIdx.x * 256 + threadIdx.x;
    if (w >= NWORD) return;
    const int* rowptr = rowptr_all + (size_t)r * (NNODE + 1);
    int lo = rowptr[2 * w], hi = rowptr[2 * w + 1];
    const unsigned int* hp = hist + (size_t)r * NB * NWORD + w;
    int* bp = base + (size_t)r * NB * NNODE;
    for (int b = 0; b < NB; ++b) {
        bp[(size_t)b * NNODE + 2 * w]     = lo;
        bp[(size_t)b * NNODE + 2 * w + 1] = hi;
        unsigned int v = hp[(size_t)b * NNODE / 2 * 0 + (size_t)b * NWORD];
        lo += (int)(v & 0xffffu);
        hi += (int)(v >> 16);
    }
}

// ---------------- scatter: fully atomic-free ----------------
struct Scat3P {
    const int* row[4]; const int* col[4]; const float* w[4];
    const unsigned short* loc[4]; const int* base; int2* edges[4];
};
__global__ __launch_bounds__(256) void scat3_k(Scat3P P) {
    int b = blockIdx.x, r = blockIdx.y;
    const int* bp = P.base + ((size_t)r * NB + b) * NNODE;
    const int* row = P.row[r];
    const int* col = P.col[r];
    const float* w = P.w[r];
    const unsigned short* loc = P.loc[r];
    int2* ed = P.edges[r];
    int e0 = b * CE;
    for (int e = e0 + threadIdx.x; e < e0 + CE; e += 256) {
        int c = col[e];
        int pos = bp[c] + (int)loc[e];
        int2 v;
        v.x = row[e];
        v.y = __float_as_int(w[e]);
        ed[pos] = v;
    }
}

// ---------------- src weighted degrees via LDS float partials ----------------
struct DegSP { const int* row[2]; const float* w[2]; float* part; };
__global__ __launch_bounds__(256) void degS_part_k(DegSP P) {
    __shared__ float t[NWORD];   // 40 KB, covers 10000 nodes
    int r = blockIdx.y;
    int chunk = blockIdx.x >> 1, half = blockIdx.x & 1;
    int nbase = half * NWORD;
    for (int i = threadIdx.x; i < NWORD; i += 256) t[i] = 0.f;
    __syncthreads();
    const int* row = P.row[r];
    const float* w = P.w[r];
    int e0 = chunk * CS;
    for (int e = e0 + threadIdx.x; e < e0 + CS; e += 256) {
        int rr = row[e] - nbase;
        if ((unsigned)rr < (unsigned)NWORD) atomicAdd(&t[rr], w[e]);
    }
    __syncthreads();
    float* pp = P.part + ((size_t)r * SB + chunk) * NNODE + nbase;
    for (int i = threadIdx.x; i < NWORD; i += 256) pp[i] = t[i];
}

__global__ __launch_bounds__(256) void degS_sum_k(const float* __restrict__ part,
                                                 float* dinv0, float* dinv1) {
    int r = blockIdx.y;
    int n = blockIdx.x * 256 + threadIdx.x;
    if (n >= NNODE) return;
    const float* pp = part + (size_t)r * SB * NNODE + n;
    float s = 0.f;
    for (int c = 0; c < SB; ++c) s += pp[(size_t)c * NNODE];
    float* d = (r == 0) ? dinv0 : dinv1;
    d[n] = s > 0.f ? rsqrtf(s) : 0.f;
}

// ---------------- dst degrees from CSR -> dinv directly (rsqrt folded) ----------------
struct DegDP { const int* rowptr[4]; const int2* edges[4]; float* dinvD[4]; float selfw[4]; };
__global__ __launch_bounds__(256) void degD_k(DegDP P) {
    int r = blockIdx.y;
    int node = (blockIdx.x * 256 + threadIdx.x) >> 6;
    int lane = threadIdx.x & 63;
    if (node >= NNODE) return;
    int b = P.rowptr[r][node], e = P.rowptr[r][node + 1];
    const int2* ed = P.edges[r];
    float s = 0.f;
    for (int i = b + lane; i < e; i += 64) s += __int_as_float(ed[i].y);
#pragma unroll
    for (int off = 32; off > 0; off >>= 1) s += __shfl_xor(s, off, 64);
    if (lane == 0) {
        float d = s + P.selfw[r];
        P.dinvD[r][node] = d > 0.f ? rsqrtf(d) : 0.f;
    }
}

// ---------------- pull-SpMM, fp16 gather, XCD-partitioned by source table ----------------
struct SpmmP {
    const __half* x[4]; const int* rowptr[4]; const int2* edges[4];
    const float* dinvS[4]; const float* dinvD[4]; float* out[4]; int self[4];
};
__global__ __launch_bounds__(256) void spmm4_k(SpmmP P) {
    // grid = 20000 blocks, 4 waves/block, 1 node/wave.
    // blockIdx&7 ~ XCD (dispatch round-robin heuristic): XCDs 0-3 take the
    // gen-sourced relations (0,1), XCDs 4-7 the rain-sourced (2,3) so each
    // XCD's L2 only caches one 5 MB fp16 feature table.
    int b = blockIdx.x;
    int xcd = b & 7;
    int j = b >> 3;                               // 0..2499
    int r = ((xcd >> 2) << 1) + (j >= 1250 ? 1 : 0);
    int nodeblk = (xcd & 3) * 1250 + (j >= 1250 ? j - 1250 : j);
    int wid = nodeblk * 4 + (threadIdx.x >> 6);
    int lane = threadIdx.x & 63;
    const __half2* x = (const __half2*)P.x[r];    // row stride = 64 half2
    float dd = P.dinvD[r][wid];
    float a0 = 0.f, a1 = 0.f;
    if (P.self[r]) {
        float sc = dd * dd;
        float2 f = __half22float2(x[(size_t)wid * 64 + lane]);
        a0 = f.x * sc;
        a1 = f.y * sc;
    }
    const float* dS = P.dinvS[r];
    const int* rp = P.rowptr[r];
    int bb = rp[wid], ee = rp[wid + 1];
    const int2* ed = P.edges[r];
    int i = bb;
    for (; i + 1 < ee; i += 2) {
        int2 m0 = ed[i], m1 = ed[i + 1];
        float n0 = dS[m0.x] * __int_as_float(m0.y) * dd;
        float n1 = dS[m1.x] * __int_as_float(m1.y) * dd;
        float2 f0 = __half22float2(x[(size_t)m0.x * 64 + lane]);
        float2 f1 = __half22float2(x[(size_t)m1.x * 64 + lane]);
        a0 += f0.x * n0; a1 += f0.y * n0;
        a0 += f1.x * n1; a1 += f1.y * n1;
    }
    if (i < ee) {
        int2 m0 = ed[i];
        float n0 = dS[m0.x] * __int_as_float(m0.y) * dd;
        float2 f0 = __half22float2(x[(size_t)m0.x * 64 + lane]);
        a0 += f0.x * n0; a1 += f0.y * n0;
    }
    float2* o = (float2*)(P.out[r] + (size_t)wid * DF);
    o[lane] = make_float2(a0, a1);
}

// ---------------- fused 2-GEMM epilogue -> fp16 out, 2 dst types batched ----------------
struct Gemm2P {
    const float* A1[2]; const float* A2[2];
    const float* Wa[2]; const float* Wb[2];
    const float* ba[2]; const float* bb[2];
    __half* out[2];
};
__global__ __launch_bounds__(256) void gemm2_k(Gemm2P P) {
    __shared__ float As[16][256];
    int g = blockIdx.y;
    const float* A1 = P.A1[g]; const float* A2 = P.A2[g];
    int r0 = blockIdx.x * 16;
    int t = threadIdx.x;
    for (int idx = t; idx < 16 * 256; idx += 256) {
        int r = idx >> 8, k = idx & 255;
        int row = r0 + r;
        float v = 0.f;
        if (row < NNODE) v = (k < 128) ? A1[(size_t)row * 128 + k] : A2[(size_t)row * 128 + (k - 128)];
        As[r][k] = v;
    }
    __syncthreads();
    int col = t & 127;
    int rb = (t >> 7) * 8;  // 0 or 8
    const float* Wa = P.Wa[g]; const float* Wb = P.Wb[g];
    float acc[8] = {0.f, 0.f, 0.f, 0.f, 0.f, 0.f, 0.f, 0.f};
    for (int k = 0; k < 128; ++k) {
        float wv = Wa[k * 128 + col];
#pragma unroll
        for (int r = 0; r < 8; ++r) acc[r] += As[rb + r][k] * wv;
    }
    for (int k = 0; k < 128; ++k) {
        float wv = Wb[k * 128 + col];
#pragma unroll
        for (int r = 0; r < 8; ++r) acc[r] += As[rb + r][k + 128] * wv;
    }
    float bias = P.ba[g][col] + P.bb[g][col];
    __half* out = P.out[g];
#pragma unroll
    for (int r = 0; r < 8; ++r) {
        int row = r0 + rb + r;
        if (row < NNODE) {
            float v = 0.5f * (acc[r] + bias);
            out[(size_t)row * 128 + col] = __float2half(v > 0.f ? v : 0.f);
        }
    }
}

struct Lin16P { const __half* x[2]; const float* W[2]; const float* b[2]; float* out[2]; };
__global__ __launch_bounds__(256) void lin16_k(Lin16P P) {
    int g = blockIdx.y;
    int idx = blockIdx.x * 256 + threadIdx.x;
    int row = idx >> 4, c = idx & 15;
    if (row >= NNODE) return;
    const __half* xr = P.x[g] + (size_t)row * 128;
    const float* W = P.W[g];
    float acc = P.b[g][c];
    for (int k = 0; k < 128; ++k) acc += __half2float(xr[k]) * W[k * 16 + c];
    P.out[g][(size_t)row * 16 + c] = acc;
}

extern "C" void kernel_launch(void* const* d_in, const int* in_sizes, int n_in,
                              void* d_out, int out_size, void* d_ws, size_t ws_size,
                              hipStream_t stream) {
    (void)in_sizes; (void)n_in; (void)out_size; (void)ws_size;

    const float* x_gen  = (const float*)d_in[0];
    const float* x_rain = (const float*)d_in[1];
    const int* ei[4] = {(const int*)d_in[2], (const int*)d_in[3], (const int*)d_in[4], (const int*)d_in[5]};
    const float* w[4] = {(const float*)d_in[6], (const float*)d_in[7], (const float*)d_in[8], (const float*)d_in[9]};
    const float* W_conv = (const float*)d_in[10];  // [2][4][128][128]
    const float* b_conv = (const float*)d_in[11];  // [2][4][128]
    const float* W_lg = (const float*)d_in[12];
    const float* b_lg = (const float*)d_in[13];
    const float* W_lr = (const float*)d_in[14];
    const float* b_lr = (const float*)d_in[15];

    float* out_gen  = (float*)d_out;
    float* out_rain = out_gen + (size_t)NNODE * DOUT;

    char* p = (char*)d_ws;
    auto alloc = [&](size_t bytes) -> void* {
        void* r = (void*)p;
        p += (bytes + 255) & ~(size_t)255;
        return r;
    };

    // dinv layout: [gr_s | rg_s | gg | gr_d | rg_d | rr]
    float* deg = (float*)alloc(6 * (size_t)NNODE * sizeof(float));
    float* dinv_gr_s = deg + 0 * NNODE;
    float* dinv_rg_s = deg + 1 * NNODE;
    float* dinv_gg   = deg + 2 * NNODE;
    float* dinv_gr_d = deg + 3 * NNODE;
    float* dinv_rg_d = deg + 4 * NNODE;
    float* dinv_rr   = deg + 5 * NNODE;

    int*  cnt_all    = (int*)alloc(4 * (size_t)NNODE * sizeof(int));
    int*  rowptr_all = (int*)alloc(4 * (size_t)(NNODE + 1) * sizeof(int));
    int2* edges_all  = (int2*)alloc(4 * (size_t)NE * sizeof(int2));

    float* agg_all = (float*)alloc(4 * (size_t)NNODE * DF * sizeof(float));  // 40.96 MB
    float* agg_gg = agg_all + 0 * (size_t)NNODE * DF;
    float* agg_gr = agg_all + 1 * (size_t)NNODE * DF;
    float* agg_rg = agg_all + 2 * (size_t)NNODE * DF;
    float* agg_rr = agg_all + 3 * (size_t)NNODE * DF;
    __half* xh_gen  = (__half*)alloc((size_t)NNODE * DF * sizeof(__half));   // 5.12 MB
    __half* xh_rain = (__half*)alloc((size_t)NNODE * DF * sizeof(__half));

    // Build-phase scratch aliased into agg_all (dead before spmm writes agg):
    //   base_all 20.48 MB | hist_all 10.24 MB | loc_all 4.8 MB  = 35.52 MB
    int*            base_all = (int*)agg_all;
    unsigned int*   hist_all = (unsigned int*)((char*)agg_all + (size_t)4 * NB * NNODE * sizeof(int));
    unsigned short* loc_all  = (unsigned short*)((char*)hist_all + (size_t)4 * NB * NWORD * sizeof(unsigned int));
    // degS partials aliased into xh_gen (5.12 MB exactly); cvt_k runs after degS_sum_k.
    float* part_degS = (float*)xh_gen;

    int* rowptr[4]; int2* edges[4]; unsigned short* loc[4];
    for (int r = 0; r < 4; ++r) {
        rowptr[r] = rowptr_all + (size_t)r * (NNODE + 1);
        edges[r]  = edges_all + (size_t)r * NE;
        loc[r]    = loc_all + (size_t)r * NE;
    }

    const int* rows_[4] = {ei[0], ei[1], ei[2], ei[3]};
    const int* cols_[4] = {ei[0] + NE, ei[1] + NE, ei[2] + NE, ei[3] + NE};

    // ---- build: histogram -> counts -> scan -> bases -> scatter (0 global atomics) ----
    HistP HP;
    for (int r = 0; r < 4; ++r) { HP.col[r] = cols_[r]; HP.loc[r] = loc[r]; }
    HP.hist = hist_all;
    hist_k<<<dim3(NB, 4), 256, 0, stream>>>(HP);

    sumcnt_k<<<dim3(ceil_div(NWORD, 256), 4), 256, 0, stream>>>(hist_all, cnt_all);
    exscan4_k<<<4, 1024, 0, stream>>>(cnt_all, rowptr_all);
    mkbase_k<<<dim3(ceil_div(NWORD, 256), 4), 256, 0, stream>>>(hist_all, rowptr_all, base_all);

    Scat3P SC;
    for (int r = 0; r < 4; ++r) {
        SC.row[r] = rows_[r]; SC.col[r] = cols_[r]; SC.w[r] = w[r];
        SC.loc[r] = loc[r]; SC.edges[r] = edges[r];
    }
    SC.base = base_all;
    scat3_k<<<dim3(NB, 4), 256, 0, stream>>>(SC);

    // ---- src degrees (gr, rg) via LDS partials ----
    DegSP DS;
    DS.row[0] = rows_[1]; DS.w[0] = w[1];   // gr: src = gen
    DS.row[1] = rows_[2]; DS.w[1] = w[2];   // rg: src = rain
    DS.part = part_degS;
    degS_part_k<<<dim3(SB * 2, 2), 256, 0, stream>>>(DS);
    degS_sum_k<<<dim3(ceil_div(NNODE, 256), 2), 256, 0, stream>>>(part_degS, dinv_gr_s, dinv_rg_s);

    // ---- dst degrees -> dinv ----
    DegDP DD;
    for (int r = 0; r < 4; ++r) { DD.rowptr[r] = rowptr[r]; DD.edges[r] = edges[r]; }
    DD.dinvD[0] = dinv_gg; DD.dinvD[1] = dinv_gr_d; DD.dinvD[2] = dinv_rg_d; DD.dinvD[3] = dinv_rr;
    DD.selfw[0] = 1.f; DD.selfw[1] = 0.f; DD.selfw[2] = 0.f; DD.selfw[3] = 1.f;
    degD_k<<<dim3(ceil_div(NNODE, 4), 4), 256, 0, stream>>>(DD);

    // ---- fp16 conversion of layer-0 features (after degS partials are dead) ----
    CvtP CV;
    CV.in[0] = x_gen;  CV.out[0] = xh_gen;
    CV.in[1] = x_rain; CV.out[1] = xh_rain;
    cvt_k<<<dim3(NNODE * DF / 4 / 256, 2), 256, 0, stream>>>(CV);

    // ---- layers ----
    for (int l = 0; l < 2; ++l) {
        SpmmP SP;
        for (int r = 0; r < 4; ++r) { SP.rowptr[r] = rowptr[r]; SP.edges[r] = edges[r]; }
        SP.x[0] = xh_gen; SP.x[1] = xh_gen; SP.x[2] = xh_rain; SP.x[3] = xh_rain;
        SP.dinvS[0] = dinv_gg;   SP.dinvD[0] = dinv_gg;
        SP.dinvS[1] = dinv_gr_s; SP.dinvD[1] = dinv_gr_d;
        SP.dinvS[2] = dinv_rg_s; SP.dinvD[2] = dinv_rg_d;
        SP.dinvS[3] = dinv_rr;   SP.dinvD[3] = dinv_rr;
        SP.self[0] = 1; SP.self[1] = 0; SP.self[2] = 0; SP.self[3] = 1;
        SP.out[0] = agg_gg; SP.out[1] = agg_gr; SP.out[2] = agg_rg; SP.out[3] = agg_rr;
        spmm4_k<<<20000, 256, 0, stream>>>(SP);

        const float* Wl = W_conv + (size_t)l * 4 * DF * DF;
        const float* bl = b_conv + (size_t)l * 4 * DF;
        Gemm2P GP;
        GP.A1[0] = agg_gg; GP.A2[0] = agg_rg;
        GP.Wa[0] = Wl + 0 * DF * DF; GP.Wb[0] = Wl + 2 * DF * DF;
        GP.ba[0] = bl + 0 * DF; GP.bb[0] = bl + 2 * DF;
        GP.out[0] = xh_gen;
        GP.A1[1] = agg_gr; GP.A2[1] = agg_rr;
        GP.Wa[1] = Wl + 1 * DF * DF; GP.Wb[1] = Wl + 3 * DF * DF;
        GP.ba[1] = bl + 1 * DF; GP.bb[1] = bl + 3 * DF;
        GP.out[1] = xh_rain;
        gemm2_k<<<dim3(ceil_div(NNODE, 16), 2), 256, 0, stream>>>(GP);
    }

    // ---- output heads ----
    Lin16P LP;
    LP.x[0] = xh_gen;  LP.W[0] = W_lg; LP.b[0] = b_lg; LP.out[0] = out_gen;
    LP.x[1] = xh_rain; LP.W[1] = W_lr; LP.b[1] = b_lr; LP.out[1] = out_rain;
    lin16_k<<<dim3(ceil_div(NNODE * DOUT, 256), 2), 256, 0, stream>>>(LP);
}

// Round 6
// 490.716 us; speedup vs baseline: 5.6234x; 1.1627x over previous
//
#include <hip/hip_runtime.h>
#include <hip/hip_fp16.h>

#define NNODE 20000
#define NE    600000
#define NES   (NE + NNODE)   // edges incl. self slots (relations gg, rr)
#define DF    128
#define DOUT  16
#define NB    64          // hist blocks per relation
#define CE    (NE/NB)     // 9375 edges per hist block (exact)
#define NWORD 10000       // packed 16-bit pairs covering 20000 nodes
#define SB    32          // degS chunks per relation
#define CS    (NE/SB)     // 18750 edges per degS chunk (exact)

static inline int ceil_div(int a, int b) { return (a + b - 1) / b; }

// ---------------- fp32 -> fp16 conversion (4 floats/thread) ----------------
struct CvtP { const float* in[2]; __half* out[2]; };
__global__ __launch_bounds__(256) void cvt_k(CvtP P) {
    int g = blockIdx.y;
    int i = blockIdx.x * 256 + threadIdx.x;           // float4 index
    const float4* in = (const float4*)P.in[g];
    __half2* out = (__half2*)P.out[g];
    float4 v = in[i];
    out[2 * i + 0] = __floats2half2_rn(v.x, v.y);
    out[2 * i + 1] = __floats2half2_rn(v.z, v.w);
}

// ---------------- phase H: per-chunk packed histogram + local slots (LDS atomics only) ----------------
struct HistP { const int* col[4]; unsigned int* hist; unsigned short* loc[4]; };
__global__ __launch_bounds__(256) void hist_k(HistP P) {
    __shared__ unsigned int h[NWORD];   // 40 KB, 2x16-bit counts per word
    int b = blockIdx.x, r = blockIdx.y;
    for (int i = threadIdx.x; i < NWORD; i += 256) h[i] = 0u;
    __syncthreads();
    const int* col = P.col[r];
    unsigned short* loc = P.loc[r];
    int e0 = b * CE;
    for (int e = e0 + threadIdx.x; e < e0 + CE; e += 256) {
        int c = col[e];
        unsigned int sh = (unsigned)(c & 1) << 4;
        unsigned int old = atomicAdd(&h[c >> 1], 1u << sh);
        loc[e] = (unsigned short)((old >> sh) & 0xffffu);
    }
    __syncthreads();
    unsigned int* hg = P.hist + (size_t)(r * NB + b) * NWORD;
    for (int i = threadIdx.x; i < NWORD; i += 256) hg[i] = h[i];
}

// ---------------- per-node totals (+1 self slot for gg/rr) ----------------
__global__ __launch_bounds__(256) void sumcnt_k(const unsigned int* __restrict__ hist,
                                                int* __restrict__ cnt_all) {
    int r = blockIdx.y;
    int w = blockIdx.x * 256 + threadIdx.x;
    if (w >= NWORD) return;
    unsigned int lo = 0, hi = 0;
    const unsigned int* hp = hist + (size_t)r * NB * NWORD + w;
    for (int b = 0; b < NB; ++b) {
        unsigned int v = hp[(size_t)b * NWORD];
        lo += v & 0xffffu; hi += v >> 16;
    }
    int s = (r == 0 || r == 3) ? 1 : 0;   // self slot
    int* cnt = cnt_all + (size_t)r * NNODE;
    cnt[2 * w] = (int)lo + s;
    cnt[2 * w + 1] = (int)hi + s;
}

// exclusive scan over NNODE counts per relation; blockIdx.x = relation
__global__ void exscan4_k(const int* __restrict__ cnt_all, int* __restrict__ rowptr_all) {
    __shared__ int sums[1024];
    const int* cnt = cnt_all + (size_t)blockIdx.x * NNODE;
    int* rowptr = rowptr_all + (size_t)blockIdx.x * (NNODE + 1);
    int t = threadIdx.x;
    int chunk = (NNODE + 1023) >> 10;
    int b = t * chunk; if (b > NNODE) b = NNODE;
    int e = b + chunk; if (e > NNODE) e = NNODE;
    int s = 0;
    for (int i = b; i < e; ++i) s += cnt[i];
    sums[t] = s;
    __syncthreads();
    for (int off = 1; off < 1024; off <<= 1) {
        int v = (t >= off) ? sums[t - off] : 0;
        __syncthreads();
        sums[t] += v;
        __syncthreads();
    }
    int run = (t == 0) ? 0 : sums[t - 1];
    for (int i = b; i < e; ++i) { rowptr[i] = run; run += cnt[i]; }
    if (t == 1023) rowptr[NNODE] = run;
}

// ---------------- per-(block,node) global bases: prefix along block axis ----------------
__global__ __launch_bounds__(256) void mkbase_k(const unsigned int* __restrict__ hist,
                                               const int* __restrict__ rowptr_all,
                                               int* __restrict__ base) {
    int r = blockIdx.y;
    int w = blockIdx.x * 256 + threadIdx.x;
    if (w >= NWORD) return;
    const int* rowptr = rowptr_all + (size_t)r * (NNODE + 1);
    int s = (r == 0 || r == 3) ? 1 : 0;   // skip reserved self slot
    int lo = rowptr[2 * w] + s, hi = rowptr[2 * w + 1] + s;
    const unsigned int* hp = hist + (size_t)r * NB * NWORD + w;
    int* bp = base + (size_t)r * NB * NNODE;
    for (int b = 0; b < NB; ++b) {
        bp[(size_t)b * NNODE + 2 * w]     = lo;
        bp[(size_t)b * NNODE + 2 * w + 1] = hi;
        unsigned int v = hp[(size_t)b * NWORD];
        lo += (int)(v & 0xffffu);
        hi += (int)(v >> 16);
    }
}

// ---------------- self edges into reserved slot 0 (gg, rr) ----------------
__global__ __launch_bounds__(256) void selfscat_k(const int* __restrict__ rp0, int2* ed0,
                                                  const int* __restrict__ rp3, int2* ed3) {
    int n = blockIdx.x * 256 + threadIdx.x;
    if (n >= NNODE) return;
    int2 v; v.x = n; v.y = __float_as_int(1.0f);
    ed0[rp0[n]] = v;
    ed3[rp3[n]] = v;
}

// ---------------- scatter: fully atomic-free ----------------
struct Scat3P {
    const int* row[4]; const int* col[4]; const float* w[4];
    const unsigned short* loc[4]; const int* base; int2* edges[4];
};
__global__ __launch_bounds__(256) void scat3_k(Scat3P P) {
    int b = blockIdx.x, r = blockIdx.y;
    const int* bp = P.base + ((size_t)r * NB + b) * NNODE;
    const int* row = P.row[r];
    const int* col = P.col[r];
    const float* w = P.w[r];
    const unsigned short* loc = P.loc[r];
    int2* ed = P.edges[r];
    int e0 = b * CE;
    for (int e = e0 + threadIdx.x; e < e0 + CE; e += 256) {
        int c = col[e];
        int pos = bp[c] + (int)loc[e];
        int2 v;
        v.x = row[e];
        v.y = __float_as_int(w[e]);
        ed[pos] = v;
    }
}

// ---------------- src weighted degrees via LDS float partials ----------------
struct DegSP { const int* row[2]; const float* w[2]; float* part; };
__global__ __launch_bounds__(256) void degS_part_k(DegSP P) {
    __shared__ float t[NWORD];   // 40 KB, covers 10000 nodes
    int r = blockIdx.y;
    int chunk = blockIdx.x >> 1, half = blockIdx.x & 1;
    int nbase = half * NWORD;
    for (int i = threadIdx.x; i < NWORD; i += 256) t[i] = 0.f;
    __syncthreads();
    const int* row = P.row[r];
    const float* w = P.w[r];
    int e0 = chunk * CS;
    for (int e = e0 + threadIdx.x; e < e0 + CS; e += 256) {
        int rr = row[e] - nbase;
        if ((unsigned)rr < (unsigned)NWORD) atomicAdd(&t[rr], w[e]);
    }
    __syncthreads();
    float* pp = P.part + ((size_t)r * SB + chunk) * NNODE + nbase;
    for (int i = threadIdx.x; i < NWORD; i += 256) pp[i] = t[i];
}

__global__ __launch_bounds__(256) void degS_sum_k(const float* __restrict__ part,
                                                 float* dinv0, float* dinv1) {
    int r = blockIdx.y;
    int n = blockIdx.x * 256 + threadIdx.x;
    if (n >= NNODE) return;
    const float* pp = part + (size_t)r * SB * NNODE + n;
    float s = 0.f;
    for (int c = 0; c < SB; ++c) s += pp[(size_t)c * NNODE];
    float* d = (r == 0) ? dinv0 : dinv1;
    d[n] = s > 0.f ? rsqrtf(s) : 0.f;
}

// ---------------- dst degrees from CSR (self edge included) -> dinv ----------------
struct DegDP { const int* rowptr[4]; const int2* edges[4]; float* dinvD[4]; };
__global__ __launch_bounds__(256) void degD_k(DegDP P) {
    int r = blockIdx.y;
    int node = (blockIdx.x * 256 + threadIdx.x) >> 6;
    int lane = threadIdx.x & 63;
    if (node >= NNODE) return;
    int b = P.rowptr[r][node], e = P.rowptr[r][node + 1];
    const int2* ed = P.edges[r];
    float s = 0.f;
    for (int i = b + lane; i < e; i += 64) s += __int_as_float(ed[i].y);
#pragma unroll
    for (int off = 32; off > 0; off >>= 1) s += __shfl_xor(s, off, 64);
    if (lane == 0) P.dinvD[r][node] = s > 0.f ? rsqrtf(s) : 0.f;
}

// ---------------- edge norms in place: ed.y = dS[src] * w * dD[dst] ----------------
struct NormP { const int* rowptr[4]; const float* dinvS[4]; const float* dinvD[4]; int2* edges[4]; };
__global__ __launch_bounds__(256) void enorm_k(NormP P) {
    int r = blockIdx.y;
    int node = (blockIdx.x * 256 + threadIdx.x) >> 6;
    int lane = threadIdx.x & 63;
    if (node >= NNODE) return;
    int b = P.rowptr[r][node], e = P.rowptr[r][node + 1];
    float dd = P.dinvD[r][node];
    const float* dS = P.dinvS[r];
    int2* ed = P.edges[r];
    for (int i = b + lane; i < e; i += 64) {
        int2 m = ed[i];
        m.y = __float_as_int(dS[m.x] * __int_as_float(m.y) * dd);
        ed[i] = m;
    }
}

// ---------------- pull-SpMM: half-wave row gather, precomputed norms ----------------
struct SpmmP {
    const __half* x[4]; const int* rowptr[4]; const int2* edges[4]; float* out[4];
};
__global__ __launch_bounds__(256) void spmm4_k(SpmmP P) {
    // grid = 20000 blocks, 4 waves/block, 1 node/wave.
    // blockIdx&7 ~ XCD: XCDs 0-3 take gen-sourced relations (0,1),
    // XCDs 4-7 the rain-sourced (2,3) -> one 5 MB fp16 table per XCD L2.
    int b = blockIdx.x;
    int xcd = b & 7;
    int j = b >> 3;                               // 0..2499
    int r = ((xcd >> 2) << 1) + (j >= 1250 ? 1 : 0);
    int nodeblk = (xcd & 3) * 1250 + (j >= 1250 ? j - 1250 : j);
    int wid = nodeblk * 4 + (threadIdx.x >> 6);
    int lane = threadIdx.x & 63;
    int h = lane >> 5, l = lane & 31;             // half-wave id, lane-in-half
    const uint2* x = (const uint2*)P.x[r];        // row = 32 x uint2 (4 fp16 each)
    const int* rp = P.rowptr[r];
    int bb = rp[wid], ee = rp[wid + 1];
    const int2* ed = P.edges[r];
    float4 acc = make_float4(0.f, 0.f, 0.f, 0.f);
    int i = bb + h;
    for (; i + 2 < ee; i += 4) {                  // 2 edges per half in flight
        int2 m0 = ed[i], m1 = ed[i + 2];
        float n0 = __int_as_float(m0.y), n1 = __int_as_float(m1.y);
        uint2 p0 = x[(size_t)m0.x * 32 + l];
        uint2 p1 = x[(size_t)m1.x * 32 + l];
        float2 a0 = __half22float2(*(const __half2*)&p0.x);
        float2 a1 = __half22float2(*(const __half2*)&p0.y);
        float2 c0 = __half22float2(*(const __half2*)&p1.x);
        float2 c1 = __half22float2(*(const __half2*)&p1.y);
        acc.x += a0.x * n0; acc.y += a0.y * n0; acc.z += a1.x * n0; acc.w += a1.y * n0;
        acc.x += c0.x * n1; acc.y += c0.y * n1; acc.z += c1.x * n1; acc.w += c1.y * n1;
    }
    if (i < ee) {
        int2 m0 = ed[i];
        float n0 = __int_as_float(m0.y);
        uint2 p0 = x[(size_t)m0.x * 32 + l];
        float2 a0 = __half22float2(*(const __half2*)&p0.x);
        float2 a1 = __half22float2(*(const __half2*)&p0.y);
        acc.x += a0.x * n0; acc.y += a0.y * n0; acc.z += a1.x * n0; acc.w += a1.y * n0;
    }
    // merge the two half-wave partial sums (lane l <-> lane l+32)
    acc.x += __shfl_xor(acc.x, 32, 64);
    acc.y += __shfl_xor(acc.y, 32, 64);
    acc.z += __shfl_xor(acc.z, 32, 64);
    acc.w += __shfl_xor(acc.w, 32, 64);
    if (h == 0) {
        float4* o = (float4*)P.out[r];
        o[(size_t)wid * 32 + l] = acc;
    }
}

// ---------------- fused 2-GEMM epilogue -> fp16 out, 2 dst types batched ----------------
struct Gemm2P {
    const float* A1[2]; const float* A2[2];
    const float* Wa[2]; const float* Wb[2];
    const float* ba[2]; const float* bb[2];
    __half* out[2];
};
__global__ __launch_bounds__(256) void gemm2_k(Gemm2P P) {
    __shared__ float As[16][256];
    int g = blockIdx.y;
    const float* A1 = P.A1[g]; const float* A2 = P.A2[g];
    int r0 = blockIdx.x * 16;
    int t = threadIdx.x;
    for (int idx = t; idx < 16 * 256; idx += 256) {
        int r = idx >> 8, k = idx & 255;
        int row = r0 + r;
        float v = 0.f;
        if (row < NNODE) v = (k < 128) ? A1[(size_t)row * 128 + k] : A2[(size_t)row * 128 + (k - 128)];
        As[r][k] = v;
    }
    __syncthreads();
    int col = t & 127;
    int rb = (t >> 7) * 8;  // 0 or 8
    const float* Wa = P.Wa[g]; const float* Wb = P.Wb[g];
    float acc[8] = {0.f, 0.f, 0.f, 0.f, 0.f, 0.f, 0.f, 0.f};
    for (int k = 0; k < 128; ++k) {
        float wv = Wa[k * 128 + col];
#pragma unroll
        for (int r = 0; r < 8; ++r) acc[r] += As[rb + r][k] * wv;
    }
    for (int k = 0; k < 128; ++k) {
        float wv = Wb[k * 128 + col];
#pragma unroll
        for (int r = 0; r < 8; ++r) acc[r] += As[rb + r][k + 128] * wv;
    }
    float bias = P.ba[g][col] + P.bb[g][col];
    __half* out = P.out[g];
#pragma unroll
    for (int r = 0; r < 8; ++r) {
        int row = r0 + rb + r;
        if (row < NNODE) {
            float v = 0.5f * (acc[r] + bias);
            out[(size_t)row * 128 + col] = __float2half(v > 0.f ? v : 0.f);
        }
    }
}

struct Lin16P { const __half* x[2]; const float* W[2]; const float* b[2]; float* out[2]; };
__global__ __launch_bounds__(256) void lin16_k(Lin16P P) {
    int g = blockIdx.y;
    int idx = blockIdx.x * 256 + threadIdx.x;
    int row = idx >> 4, c = idx & 15;
    if (row >= NNODE) return;
    const __half* xr = P.x[g] + (size_t)row * 128;
    const float* W = P.W[g];
    float acc = P.b[g][c];
    for (int k = 0; k < 128; ++k) acc += __half2float(xr[k]) * W[k * 16 + c];
    P.out[g][(size_t)row * 16 + c] = acc;
}

extern "C" void kernel_launch(void* const* d_in, const int* in_sizes, int n_in,
                              void* d_out, int out_size, void* d_ws, size_t ws_size,
                              hipStream_t stream) {
    (void)in_sizes; (void)n_in; (void)out_size; (void)ws_size;

    const float* x_gen  = (const float*)d_in[0];
    const float* x_rain = (const float*)d_in[1];
    const int* ei[4] = {(const int*)d_in[2], (const int*)d_in[3], (const int*)d_in[4], (const int*)d_in[5]};
    const float* w[4] = {(const float*)d_in[6], (const float*)d_in[7], (const float*)d_in[8], (const float*)d_in[9]};
    const float* W_conv = (const float*)d_in[10];  // [2][4][128][128]
    const float* b_conv = (const float*)d_in[11];  // [2][4][128]
    const float* W_lg = (const float*)d_in[12];
    const float* b_lg = (const float*)d_in[13];
    const float* W_lr = (const float*)d_in[14];
    const float* b_lr = (const float*)d_in[15];

    float* out_gen  = (float*)d_out;
    float* out_rain = out_gen + (size_t)NNODE * DOUT;

    char* p = (char*)d_ws;
    auto alloc = [&](size_t bytes) -> void* {
        void* r = (void*)p;
        p += (bytes + 255) & ~(size_t)255;
        return r;
    };

    // dinv layout: [gr_s | rg_s | gg | gr_d | rg_d | rr]
    float* deg = (float*)alloc(6 * (size_t)NNODE * sizeof(float));
    float* dinv_gr_s = deg + 0 * NNODE;
    float* dinv_rg_s = deg + 1 * NNODE;
    float* dinv_gg   = deg + 2 * NNODE;
    float* dinv_gr_d = deg + 3 * NNODE;
    float* dinv_rg_d = deg + 4 * NNODE;
    float* dinv_rr   = deg + 5 * NNODE;

    int*  cnt_all    = (int*)alloc(4 * (size_t)NNODE * sizeof(int));
    int*  rowptr_all = (int*)alloc(4 * (size_t)(NNODE + 1) * sizeof(int));
    int2* edges_all  = (int2*)alloc(4 * (size_t)NES * sizeof(int2));

    float* agg_all = (float*)alloc(4 * (size_t)NNODE * DF * sizeof(float));  // 40.96 MB
    float* agg_gg = agg_all + 0 * (size_t)NNODE * DF;
    float* agg_gr = agg_all + 1 * (size_t)NNODE * DF;
    float* agg_rg = agg_all + 2 * (size_t)NNODE * DF;
    float* agg_rr = agg_all + 3 * (size_t)NNODE * DF;
    __half* xh_gen  = (__half*)alloc((size_t)NNODE * DF * sizeof(__half));   // 5.12 MB
    __half* xh_rain = (__half*)alloc((size_t)NNODE * DF * sizeof(__half));

    // Build-phase scratch aliased into agg_all (dead before spmm writes agg):
    //   base_all 20.48 MB | hist_all 10.24 MB | loc_all 4.8 MB  = 35.52 MB
    int*            base_all = (int*)agg_all;
    unsigned int*   hist_all = (unsigned int*)((char*)agg_all + (size_t)4 * NB * NNODE * sizeof(int));
    unsigned short* loc_all  = (unsigned short*)((char*)hist_all + (size_t)4 * NB * NWORD * sizeof(unsigned int));
    // degS partials aliased into xh_gen (5.12 MB exactly); cvt_k runs after degS_sum_k.
    float* part_degS = (float*)xh_gen;

    int* rowptr[4]; int2* edges[4]; unsigned short* loc[4];
    for (int r = 0; r < 4; ++r) {
        rowptr[r] = rowptr_all + (size_t)r * (NNODE + 1);
        edges[r]  = edges_all + (size_t)r * NES;
        loc[r]    = loc_all + (size_t)r * NE;
    }

    const int* rows_[4] = {ei[0], ei[1], ei[2], ei[3]};
    const int* cols_[4] = {ei[0] + NE, ei[1] + NE, ei[2] + NE, ei[3] + NE};

    // ---- build: histogram -> counts -> scan -> bases -> scatter (0 global atomics) ----
    HistP HP;
    for (int r = 0; r < 4; ++r) { HP.col[r] = cols_[r]; HP.loc[r] = loc[r]; }
    HP.hist = hist_all;
    hist_k<<<dim3(NB, 4), 256, 0, stream>>>(HP);

    sumcnt_k<<<dim3(ceil_div(NWORD, 256), 4), 256, 0, stream>>>(hist_all, cnt_all);
    exscan4_k<<<4, 1024, 0, stream>>>(cnt_all, rowptr_all);
    mkbase_k<<<dim3(ceil_div(NWORD, 256), 4), 256, 0, stream>>>(hist_all, rowptr_all, base_all);

    selfscat_k<<<ceil_div(NNODE, 256), 256, 0, stream>>>(rowptr[0], edges[0], rowptr[3], edges[3]);

    Scat3P SC;
    for (int r = 0; r < 4; ++r) {
        SC.row[r] = rows_[r]; SC.col[r] = cols_[r]; SC.w[r] = w[r];
        SC.loc[r] = loc[r]; SC.edges[r] = edges[r];
    }
    SC.base = base_all;
    scat3_k<<<dim3(NB, 4), 256, 0, stream>>>(SC);

    // ---- src degrees (gr, rg) via LDS partials ----
    DegSP DS;
    DS.row[0] = rows_[1]; DS.w[0] = w[1];   // gr: src = gen
    DS.row[1] = rows_[2]; DS.w[1] = w[2];   // rg: src = rain
    DS.part = part_degS;
    degS_part_k<<<dim3(SB * 2, 2), 256, 0, stream>>>(DS);
    degS_sum_k<<<dim3(ceil_div(NNODE, 256), 2), 256, 0, stream>>>(part_degS, dinv_gr_s, dinv_rg_s);

    // ---- dst degrees -> dinv (self edge already in CSR) ----
    DegDP DD;
    for (int r = 0; r < 4; ++r) { DD.rowptr[r] = rowptr[r]; DD.edges[r] = edges[r]; }
    DD.dinvD[0] = dinv_gg; DD.dinvD[1] = dinv_gr_d; DD.dinvD[2] = dinv_rg_d; DD.dinvD[3] = dinv_rr;
    degD_k<<<dim3(ceil_div(NNODE, 4), 4), 256, 0, stream>>>(DD);

    // ---- edge norms in place ----
    NormP NP;
    for (int r = 0; r < 4; ++r) { NP.rowptr[r] = rowptr[r]; NP.edges[r] = edges[r]; }
    NP.dinvS[0] = dinv_gg;   NP.dinvD[0] = dinv_gg;
    NP.dinvS[1] = dinv_gr_s; NP.dinvD[1] = dinv_gr_d;
    NP.dinvS[2] = dinv_rg_s; NP.dinvD[2] = dinv_rg_d;
    NP.dinvS[3] = dinv_rr;   NP.dinvD[3] = dinv_rr;
    enorm_k<<<dim3(ceil_div(NNODE, 4), 4), 256, 0, stream>>>(NP);

    // ---- fp16 conversion of layer-0 features (after degS partials are dead) ----
    CvtP CV;
    CV.in[0] = x_gen;  CV.out[0] = xh_gen;
    CV.in[1] = x_rain; CV.out[1] = xh_rain;
    cvt_k<<<dim3(NNODE * DF / 4 / 256, 2), 256, 0, stream>>>(CV);

    // ---- layers ----
    for (int l = 0; l < 2; ++l) {
        SpmmP SP;
        for (int r = 0; r < 4; ++r) { SP.rowptr[r] = rowptr[r]; SP.edges[r] = edges[r]; }
        SP.x[0] = xh_gen; SP.x[1] = xh_gen; SP.x[2] = xh_rain; SP.x[3] = xh_rain;
        SP.out[0] = agg_gg; SP.out[1] = agg_gr; SP.out[2] = agg_rg; SP.out[3] = agg_rr;
        spmm4_k<<<20000, 256, 0, stream>>>(SP);

        const float* Wl = W_conv + (size_t)l * 4 * DF * DF;
        const float* bl = b_conv + (size_t)l * 4 * DF;
        Gemm2P GP;
        GP.A1[0] = agg_gg; GP.A2[0] = agg_rg;
        GP.Wa[0] = Wl + 0 * DF * DF; GP.Wb[0] = Wl + 2 * DF * DF;
        GP.ba[0] = bl + 0 * DF; GP.bb[0] = bl + 2 * DF;
        GP.out[0] = xh_gen;
        GP.A1[1] = agg_gr; GP.A2[1] = agg_rr;
        GP.Wa[1] = Wl + 1 * DF * DF; GP.Wb[1] = Wl + 3 * DF * DF;
        GP.ba[1] = bl + 1 * DF; GP.bb[1] = bl + 3 * DF;
        GP.out[1] = xh_rain;
        gemm2_k<<<dim3(ceil_div(NNODE, 16), 2), 256, 0, stream>>>(GP);
    }

    // ---- output heads ----
    Lin16P LP;
    LP.x[0] = xh_gen;  LP.W[0] = W_lg; LP.b[0] = b_lg; LP.out[0] = out_gen;
    LP.x[1] = xh_rain; LP.W[1] = W_lr; LP.b[1] = b_lr; LP.out[1] = out_rain;
    lin16_k<<<dim3(ceil_div(NNODE * DOUT, 256), 2), 256, 0, stream>>>(LP);
}

// Round 7
// 347.204 us; speedup vs baseline: 7.9477x; 1.4133x over previous
//
#include <hip/hip_runtime.h>
#include <hip/hip_fp16.h>

#define NNODE 20000
#define NE    600000
#define NES   (NE + NNODE)   // edges incl. self slots (relations gg, rr)
#define DF    128
#define DOUT  16
#define NB    64          // hist blocks per relation
#define CE    (NE/NB)     // 9375 edges per hist block (exact)
#define NWORD 10000       // packed 16-bit pairs covering 20000 nodes
#define SB    32          // degS chunks per relation
#define CS    (NE/SB)     // 18750 edges per degS chunk (exact)

typedef _Float16 f16x8 __attribute__((ext_vector_type(8)));
typedef float f32x4 __attribute__((ext_vector_type(4)));

static inline int ceil_div(int a, int b) { return (a + b - 1) / b; }

// ---------------- fp32 -> fp16 conversion (4 floats/thread) ----------------
struct CvtP { const float* in[2]; __half* out[2]; };
__global__ __launch_bounds__(256) void cvt_k(CvtP P) {
    int g = blockIdx.y;
    int i = blockIdx.x * 256 + threadIdx.x;           // float4 index
    const float4* in = (const float4*)P.in[g];
    __half2* out = (__half2*)P.out[g];
    float4 v = in[i];
    out[2 * i + 0] = __floats2half2_rn(v.x, v.y);
    out[2 * i + 1] = __floats2half2_rn(v.z, v.w);
}

// ---------------- W prep: combined, transposed, fp16 + folded bias ----------------
// WtH[lg][col][k]: k<128 -> Wa[k][col], k>=128 -> Wb[k-128][col]; lg = l*2+g
__global__ __launch_bounds__(256) void prepW_k(const float* __restrict__ W_conv,
                                               const float* __restrict__ b_conv,
                                               __half* __restrict__ WtH,
                                               float* __restrict__ bsum) {
    int lg = blockIdx.y;
    int l = lg >> 1, g = lg & 1;
    int ra = (g == 0) ? 0 : 1;
    int rb = (g == 0) ? 2 : 3;
    int idx = blockIdx.x * 256 + threadIdx.x;    // 0..32767
    int col = idx >> 8, k = idx & 255;
    const float* Wa = W_conv + (size_t)(l * 4 + ra) * 128 * 128;
    const float* Wb = W_conv + (size_t)(l * 4 + rb) * 128 * 128;
    float v = (k < 128) ? Wa[k * 128 + col] : Wb[(k - 128) * 128 + col];
    WtH[((size_t)lg * 128 + col) * 256 + k] = __float2half(v);
    if (idx < 128)
        bsum[lg * 128 + idx] = 0.5f * (b_conv[(l * 4 + ra) * 128 + idx] +
                                       b_conv[(l * 4 + rb) * 128 + idx]);
}

// ---------------- phase H: per-chunk packed histogram + local slots ----------------
struct HistP { const int* col[4]; unsigned int* hist; unsigned short* loc[4]; };
__global__ __launch_bounds__(256) void hist_k(HistP P) {
    __shared__ unsigned int h[NWORD];   // 40 KB, 2x16-bit counts per word
    int b = blockIdx.x, r = blockIdx.y;
    for (int i = threadIdx.x; i < NWORD; i += 256) h[i] = 0u;
    __syncthreads();
    const int* col = P.col[r];
    unsigned short* loc = P.loc[r];
    int e0 = b * CE;
    for (int e = e0 + threadIdx.x; e < e0 + CE; e += 256) {
        int c = col[e];
        unsigned int sh = (unsigned)(c & 1) << 4;
        unsigned int old = atomicAdd(&h[c >> 1], 1u << sh);
        loc[e] = (unsigned short)((old >> sh) & 0xffffu);
    }
    __syncthreads();
    unsigned int* hg = P.hist + (size_t)(r * NB + b) * NWORD;
    for (int i = threadIdx.x; i < NWORD; i += 256) hg[i] = h[i];
}

// ---------------- per-node totals (+1 self slot for gg/rr) ----------------
__global__ __launch_bounds__(256) void sumcnt_k(const unsigned int* __restrict__ hist,
                                                int* __restrict__ cnt_all) {
    int r = blockIdx.y;
    int w = blockIdx.x * 256 + threadIdx.x;
    if (w >= NWORD) return;
    unsigned int lo = 0, hi = 0;
    const unsigned int* hp = hist + (size_t)r * NB * NWORD + w;
    for (int b = 0; b < NB; ++b) {
        unsigned int v = hp[(size_t)b * NWORD];
        lo += v & 0xffffu; hi += v >> 16;
    }
    int s = (r == 0 || r == 3) ? 1 : 0;   // self slot
    int* cnt = cnt_all + (size_t)r * NNODE;
    cnt[2 * w] = (int)lo + s;
    cnt[2 * w + 1] = (int)hi + s;
}

// exclusive scan over NNODE counts per relation; blockIdx.x = relation
__global__ void exscan4_k(const int* __restrict__ cnt_all, int* __restrict__ rowptr_all) {
    __shared__ int sums[1024];
    const int* cnt = cnt_all + (size_t)blockIdx.x * NNODE;
    int* rowptr = rowptr_all + (size_t)blockIdx.x * (NNODE + 1);
    int t = threadIdx.x;
    int chunk = (NNODE + 1023) >> 10;
    int b = t * chunk; if (b > NNODE) b = NNODE;
    int e = b + chunk; if (e > NNODE) e = NNODE;
    int s = 0;
    for (int i = b; i < e; ++i) s += cnt[i];
    sums[t] = s;
    __syncthreads();
    for (int off = 1; off < 1024; off <<= 1) {
        int v = (t >= off) ? sums[t - off] : 0;
        __syncthreads();
        sums[t] += v;
        __syncthreads();
    }
    int run = (t == 0) ? 0 : sums[t - 1];
    for (int i = b; i < e; ++i) { rowptr[i] = run; run += cnt[i]; }
    if (t == 1023) rowptr[NNODE] = run;
}

// ---------------- per-(block,node) global bases ----------------
__global__ __launch_bounds__(256) void mkbase_k(const unsigned int* __restrict__ hist,
                                               const int* __restrict__ rowptr_all,
                                               int* __restrict__ base) {
    int r = blockIdx.y;
    int w = blockIdx.x * 256 + threadIdx.x;
    if (w >= NWORD) return;
    const int* rowptr = rowptr_all + (size_t)r * (NNODE + 1);
    int s = (r == 0 || r == 3) ? 1 : 0;   // skip reserved self slot
    int lo = rowptr[2 * w] + s, hi = rowptr[2 * w + 1] + s;
    const unsigned int* hp = hist + (size_t)r * NB * NWORD + w;
    int* bp = base + (size_t)r * NB * NNODE;
    for (int b = 0; b < NB; ++b) {
        bp[(size_t)b * NNODE + 2 * w]     = lo;
        bp[(size_t)b * NNODE + 2 * w + 1] = hi;
        unsigned int v = hp[(size_t)b * NWORD];
        lo += (int)(v & 0xffffu);
        hi += (int)(v >> 16);
    }
}

// ---------------- self edges into reserved slot 0 (gg, rr) ----------------
__global__ __launch_bounds__(256) void selfscat_k(const int* __restrict__ rp0, int2* ed0,
                                                  const int* __restrict__ rp3, int2* ed3) {
    int n = blockIdx.x * 256 + threadIdx.x;
    if (n >= NNODE) return;
    int2 v; v.x = n; v.y = __float_as_int(1.0f);
    ed0[rp0[n]] = v;
    ed3[rp3[n]] = v;
}

// ---------------- scatter: fully atomic-free ----------------
struct Scat3P {
    const int* row[4]; const int* col[4]; const float* w[4];
    const unsigned short* loc[4]; const int* base; int2* edges[4];
};
__global__ __launch_bounds__(256) void scat3_k(Scat3P P) {
    int b = blockIdx.x, r = blockIdx.y;
    const int* bp = P.base + ((size_t)r * NB + b) * NNODE;
    const int* row = P.row[r];
    const int* col = P.col[r];
    const float* w = P.w[r];
    const unsigned short* loc = P.loc[r];
    int2* ed = P.edges[r];
    int e0 = b * CE;
    for (int e = e0 + threadIdx.x; e < e0 + CE; e += 256) {
        int c = col[e];
        int pos = bp[c] + (int)loc[e];
        int2 v;
        v.x = row[e];
        v.y = __float_as_int(w[e]);
        ed[pos] = v;
    }
}

// ---------------- src weighted degrees via LDS float partials ----------------
struct DegSP { const int* row[2]; const float* w[2]; float* part; };
__global__ __launch_bounds__(256) void degS_part_k(DegSP P) {
    __shared__ float t[NWORD];
    int r = blockIdx.y;
    int chunk = blockIdx.x >> 1, half = blockIdx.x & 1;
    int nbase = half * NWORD;
    for (int i = threadIdx.x; i < NWORD; i += 256) t[i] = 0.f;
    __syncthreads();
    const int* row = P.row[r];
    const float* w = P.w[r];
    int e0 = chunk * CS;
    for (int e = e0 + threadIdx.x; e < e0 + CS; e += 256) {
        int rr = row[e] - nbase;
        if ((unsigned)rr < (unsigned)NWORD) atomicAdd(&t[rr], w[e]);
    }
    __syncthreads();
    float* pp = P.part + ((size_t)r * SB + chunk) * NNODE + nbase;
    for (int i = threadIdx.x; i < NWORD; i += 256) pp[i] = t[i];
}

__global__ __launch_bounds__(256) void degS_sum_k(const float* __restrict__ part,
                                                 float* dinv0, float* dinv1) {
    int r = blockIdx.y;
    int n = blockIdx.x * 256 + threadIdx.x;
    if (n >= NNODE) return;
    const float* pp = part + (size_t)r * SB * NNODE + n;
    float s = 0.f;
    for (int c = 0; c < SB; ++c) s += pp[(size_t)c * NNODE];
    float* d = (r == 0) ? dinv0 : dinv1;
    d[n] = s > 0.f ? rsqrtf(s) : 0.f;
}

// ---------------- dst degrees from CSR -> dinv ----------------
struct DegDP { const int* rowptr[4]; const int2* edges[4]; float* dinvD[4]; };
__global__ __launch_bounds__(256) void degD_k(DegDP P) {
    int r = blockIdx.y;
    int node = (blockIdx.x * 256 + threadIdx.x) >> 6;
    int lane = threadIdx.x & 63;
    if (node >= NNODE) return;
    int b = P.rowptr[r][node], e = P.rowptr[r][node + 1];
    const int2* ed = P.edges[r];
    float s = 0.f;
    for (int i = b + lane; i < e; i += 64) s += __int_as_float(ed[i].y);
#pragma unroll
    for (int off = 32; off > 0; off >>= 1) s += __shfl_xor(s, off, 64);
    if (lane == 0) P.dinvD[r][node] = s > 0.f ? rsqrtf(s) : 0.f;
}

// ---------------- edge norms -> packed (src<<16 | fp16(norm)) ----------------
struct NormP {
    const int* rowptr[4]; const float* dinvS[4]; const float* dinvD[4];
    const int2* edges[4]; unsigned int* ep[4];
};
__global__ __launch_bounds__(256) void enorm_k(NormP P) {
    int r = blockIdx.y;
    int node = (blockIdx.x * 256 + threadIdx.x) >> 6;
    int lane = threadIdx.x & 63;
    if (node >= NNODE) return;
    int b = P.rowptr[r][node], e = P.rowptr[r][node + 1];
    float dd = P.dinvD[r][node];
    const float* dS = P.dinvS[r];
    const int2* ed = P.edges[r];
    unsigned int* ep = P.ep[r];
    for (int i = b + lane; i < e; i += 64) {
        int2 m = ed[i];
        float nm = dS[m.x] * __int_as_float(m.y) * dd;
        __half hh = __float2half(nm);
        unsigned short us = *reinterpret_cast<unsigned short*>(&hh);
        ep[i] = ((unsigned int)m.x << 16) | us;
    }
}

// ---------------- pull-SpMM: quarter-wave row gather, packed edges, fp16 out ----------------
struct SpmmP {
    const __half* x[4]; const int* rowptr[4]; const unsigned int* ep[4]; __half* out[4];
};
__global__ __launch_bounds__(256) void spmm4_k(SpmmP P) {
    // grid = 20000 blocks, 4 waves/block, 1 node/wave; XCD-partitioned by src table.
    int b = blockIdx.x;
    int xcd = b & 7;
    int j = b >> 3;                               // 0..2499
    int r = ((xcd >> 2) << 1) + (j >= 1250 ? 1 : 0);
    int nodeblk = (xcd & 3) * 1250 + (j >= 1250 ? j - 1250 : j);
    int wid = nodeblk * 4 + (threadIdx.x >> 6);
    int lane = threadIdx.x & 63;
    int q = lane >> 4, c = lane & 15;             // quarter id, lane-in-quarter
    const uint4* x4 = (const uint4*)P.x[r];       // row = 16 x uint4 (8 fp16 each)
    const int* rp = P.rowptr[r];
    int bb = rp[wid], ee = rp[wid + 1];
    const unsigned int* ep = P.ep[r];
    float a[8];
#pragma unroll
    for (int t = 0; t < 8; ++t) a[t] = 0.f;

    auto decn = [](unsigned int v) -> float {
        unsigned short us = (unsigned short)(v & 0xffffu);
        __half h = *reinterpret_cast<__half*>(&us);
        return __half2float(h);
    };
    auto accum = [&](uint4 p, float n) {
        const __half2* ph = (const __half2*)&p;
#pragma unroll
        for (int t = 0; t < 4; ++t) {
            float2 f = __half22float2(ph[t]);
            a[2 * t]     = fmaf(f.x, n, a[2 * t]);
            a[2 * t + 1] = fmaf(f.y, n, a[2 * t + 1]);
        }
    };

    int i = bb + q;
    for (; i + 4 < ee; i += 8) {                  // 2 edges per quarter in flight
        unsigned int v0 = ep[i], v1 = ep[i + 4];
        uint4 p0 = x4[(size_t)(v0 >> 16) * 16 + c];
        uint4 p1 = x4[(size_t)(v1 >> 16) * 16 + c];
        accum(p0, decn(v0));
        accum(p1, decn(v1));
    }
    if (i < ee) {
        unsigned int v0 = ep[i];
        uint4 p0 = x4[(size_t)(v0 >> 16) * 16 + c];
        accum(p0, decn(v0));
    }
    // merge quarters: lanes c, c+16, c+32, c+48 hold partials of chunk c
#pragma unroll
    for (int t = 0; t < 8; ++t) {
        a[t] += __shfl_xor(a[t], 16, 64);
        a[t] += __shfl_xor(a[t], 32, 64);
    }
    if (q == 0) {
        __half2 h[4];
#pragma unroll
        for (int t = 0; t < 4; ++t) h[t] = __floats2half2_rn(a[2 * t], a[2 * t + 1]);
        ((uint4*)P.out[r])[(size_t)wid * 16 + c] = *(uint4*)h;
    }
}

// ---------------- MFMA gemm2: relu(0.5*(A1@Wa + A2@Wb) + bsum) -> fp16 ----------------
struct Gemm2P {
    const __half* A1[2]; const __half* A2[2];
    const __half* Wt[2];   // [128 col][256 k] fp16 (k<128: Wa, else Wb)
    const float* bs[2];    // 0.5*(ba+bb)
    __half* out[2];
};
__global__ __launch_bounds__(256) void gemm2_k(Gemm2P P) {
    __shared__ __half sW[128 * 136];   // one 128-K slab, padded stride
    int g = blockIdx.y;
    int w = threadIdx.x >> 6, l = threadIdx.x & 63;
    int r0 = blockIdx.x * 64 + w * 16;
    int lm = l & 15, lh = l >> 4;
    f32x4 acc[8];
    f32x4 zero = {0.f, 0.f, 0.f, 0.f};
#pragma unroll
    for (int n = 0; n < 8; ++n) acc[n] = zero;
    const __half* As[2] = { P.A1[g], P.A2[g] };
    const uint4* wg = (const uint4*)P.Wt[g];
    int arow = r0 + lm;
    bool rok = arow < NNODE;
    for (int s = 0; s < 2; ++s) {
        __syncthreads();
        for (int u = threadIdx.x; u < 2048; u += 256) {   // stage 32 KB slab
            int col = u >> 4, kb8 = u & 15;               // kb = kb8*8
            uint4 vv = wg[col * 32 + s * 16 + kb8];
            *(uint4*)&sW[col * 136 + kb8 * 8] = vv;
        }
        __syncthreads();
        const uint4* a4 = (const uint4*)As[s];
#pragma unroll
        for (int kk = 0; kk < 4; ++kk) {
            uint4 av = make_uint4(0, 0, 0, 0);
            if (rok) av = a4[(size_t)arow * 16 + kk * 4 + lh];
            f16x8 af = *(f16x8*)&av;
#pragma unroll
            for (int n = 0; n < 8; ++n) {
                uint4 bv = *(uint4*)&sW[(n * 16 + lm) * 136 + kk * 32 + lh * 8];
                f16x8 bf = *(f16x8*)&bv;
                acc[n] = __builtin_amdgcn_mfma_f32_16x16x32_f16(af, bf, acc[n], 0, 0, 0);
            }
        }
    }
    __half* out = P.out[g];
    const float* bs = P.bs[g];
#pragma unroll
    for (int n = 0; n < 8; ++n) {
        int colg = n * 16 + lm;
        float bb = bs[colg];
#pragma unroll
        for (int qq = 0; qq < 4; ++qq) {
            int rowg = r0 + lh * 4 + qq;
            if (rowg < NNODE) {
                float v = fmaf(acc[n][qq], 0.5f, bb);
                out[(size_t)rowg * 128 + colg] = __float2half(v > 0.f ? v : 0.f);
            }
        }
    }
}

struct Lin16P { const __half* x[2]; const float* W[2]; const float* b[2]; float* out[2]; };
__global__ __launch_bounds__(256) void lin16_k(Lin16P P) {
    int g = blockIdx.y;
    int idx = blockIdx.x * 256 + threadIdx.x;
    int row = idx >> 4, c = idx & 15;
    if (row >= NNODE) return;
    const __half* xr = P.x[g] + (size_t)row * 128;
    const float* W = P.W[g];
    float acc = P.b[g][c];
    for (int k = 0; k < 128; ++k) acc += __half2float(xr[k]) * W[k * 16 + c];
    P.out[g][(size_t)row * 16 + c] = acc;
}

extern "C" void kernel_launch(void* const* d_in, const int* in_sizes, int n_in,
                              void* d_out, int out_size, void* d_ws, size_t ws_size,
                              hipStream_t stream) {
    (void)in_sizes; (void)n_in; (void)out_size; (void)ws_size;

    const float* x_gen  = (const float*)d_in[0];
    const float* x_rain = (const float*)d_in[1];
    const int* ei[4] = {(const int*)d_in[2], (const int*)d_in[3], (const int*)d_in[4], (const int*)d_in[5]};
    const float* w[4] = {(const float*)d_in[6], (const float*)d_in[7], (const float*)d_in[8], (const float*)d_in[9]};
    const float* W_conv = (const float*)d_in[10];  // [2][4][128][128]
    const float* b_conv = (const float*)d_in[11];  // [2][4][128]
    const float* W_lg = (const float*)d_in[12];
    const float* b_lg = (const float*)d_in[13];
    const float* W_lr = (const float*)d_in[14];
    const float* b_lr = (const float*)d_in[15];

    float* out_gen  = (float*)d_out;
    float* out_rain = out_gen + (size_t)NNODE * DOUT;

    char* p = (char*)d_ws;
    auto alloc = [&](size_t bytes) -> void* {
        void* r = (void*)p;
        p += (bytes + 255) & ~(size_t)255;
        return r;
    };

    // dinv layout: [gr_s | rg_s | gg | gr_d | rg_d | rr]
    float* deg = (float*)alloc(6 * (size_t)NNODE * sizeof(float));
    float* dinv_gr_s = deg + 0 * NNODE;
    float* dinv_rg_s = deg + 1 * NNODE;
    float* dinv_gg   = deg + 2 * NNODE;
    float* dinv_gr_d = deg + 3 * NNODE;
    float* dinv_rg_d = deg + 4 * NNODE;
    float* dinv_rr   = deg + 5 * NNODE;

    int*  cnt_all    = (int*)alloc(4 * (size_t)NNODE * sizeof(int));
    int*  rowptr_all = (int*)alloc(4 * (size_t)(NNODE + 1) * sizeof(int));
    int2* edges_all  = (int2*)alloc(4 * (size_t)NES * sizeof(int2));     // 19.84 MB

    // epack (9.92 MB) shares a 10.24 MB block with hist_all (dead after mkbase)
    size_t epack_bytes = 4 * (size_t)NES * sizeof(unsigned int);
    size_t hist_bytes  = 4 * (size_t)NB * NWORD * sizeof(unsigned int);
    unsigned int* epack_all = (unsigned int*)alloc(epack_bytes > hist_bytes ? epack_bytes : hist_bytes);
    unsigned int* hist_all  = epack_all;

    __half* agg_all = (__half*)alloc(4 * (size_t)NNODE * DF * sizeof(__half));  // 20.48 MB
    __half* aggh_gg = agg_all + 0 * (size_t)NNODE * DF;
    __half* aggh_gr = agg_all + 1 * (size_t)NNODE * DF;
    __half* aggh_rg = agg_all + 2 * (size_t)NNODE * DF;
    __half* aggh_rr = agg_all + 3 * (size_t)NNODE * DF;
    __half* xh_gen  = (__half*)alloc((size_t)NNODE * DF * sizeof(__half));   // 5.12 MB
    __half* xh_rain = (__half*)alloc((size_t)NNODE * DF * sizeof(__half));

    __half* WtH  = (__half*)alloc(4 * (size_t)128 * 256 * sizeof(__half));   // 256 KB
    float*  bsum = (float*)alloc(4 * 128 * sizeof(float));

    // aliases (dead-by-then regions):
    int* base_all = (int*)agg_all;                       // 20.48 MB, dead after scat3
    unsigned short* loc_all = (unsigned short*)xh_rain;  // 4.8 MB in 5.12, dead after scat3
    float* part_degS = (float*)xh_gen;                   // 5.12 MB exact, dead after degS_sum

    int* rowptr[4]; int2* edges[4]; unsigned short* loc[4]; unsigned int* ep[4];
    for (int r = 0; r < 4; ++r) {
        rowptr[r] = rowptr_all + (size_t)r * (NNODE + 1);
        edges[r]  = edges_all + (size_t)r * NES;
        loc[r]    = loc_all + (size_t)r * NE;
        ep[r]     = epack_all + (size_t)r * NES;
    }

    const int* rows_[4] = {ei[0], ei[1], ei[2], ei[3]};
    const int* cols_[4] = {ei[0] + NE, ei[1] + NE, ei[2] + NE, ei[3] + NE};

    // ---- W prep (independent) ----
    prepW_k<<<dim3(128, 4), 256, 0, stream>>>(W_conv, b_conv, WtH, bsum);

    // ---- build: histogram -> counts -> scan -> bases -> scatter (0 global atomics) ----
    HistP HP;
    for (int r = 0; r < 4; ++r) { HP.col[r] = cols_[r]; HP.loc[r] = loc[r]; }
    HP.hist = hist_all;
    hist_k<<<dim3(NB, 4), 256, 0, stream>>>(HP);

    sumcnt_k<<<dim3(ceil_div(NWORD, 256), 4), 256, 0, stream>>>(hist_all, cnt_all);
    exscan4_k<<<4, 1024, 0, stream>>>(cnt_all, rowptr_all);
    mkbase_k<<<dim3(ceil_div(NWORD, 256), 4), 256, 0, stream>>>(hist_all, rowptr_all, base_all);

    selfscat_k<<<ceil_div(NNODE, 256), 256, 0, stream>>>(rowptr[0], edges[0], rowptr[3], edges[3]);

    Scat3P SC;
    for (int r = 0; r < 4; ++r) {
        SC.row[r] = rows_[r]; SC.col[r] = cols_[r]; SC.w[r] = w[r];
        SC.loc[r] = loc[r]; SC.edges[r] = edges[r];
    }
    SC.base = base_all;
    scat3_k<<<dim3(NB, 4), 256, 0, stream>>>(SC);

    // ---- src degrees (gr, rg) via LDS partials ----
    DegSP DS;
    DS.row[0] = rows_[1]; DS.w[0] = w[1];   // gr: src = gen
    DS.row[1] = rows_[2]; DS.w[1] = w[2];   // rg: src = rain
    DS.part = part_degS;
    degS_part_k<<<dim3(SB * 2, 2), 256, 0, stream>>>(DS);
    degS_sum_k<<<dim3(ceil_div(NNODE, 256), 2), 256, 0, stream>>>(part_degS, dinv_gr_s, dinv_rg_s);

    // ---- dst degrees -> dinv ----
    DegDP DD;
    for (int r = 0; r < 4; ++r) { DD.rowptr[r] = rowptr[r]; DD.edges[r] = edges[r]; }
    DD.dinvD[0] = dinv_gg; DD.dinvD[1] = dinv_gr_d; DD.dinvD[2] = dinv_rg_d; DD.dinvD[3] = dinv_rr;
    degD_k<<<dim3(ceil_div(NNODE, 4), 4), 256, 0, stream>>>(DD);

    // ---- edge norms -> packed records (overwrites hist region; hist is dead) ----
    NormP NP;
    for (int r = 0; r < 4; ++r) { NP.rowptr[r] = rowptr[r]; NP.edges[r] = edges[r]; NP.ep[r] = ep[r]; }
    NP.dinvS[0] = dinv_gg;   NP.dinvD[0] = dinv_gg;
    NP.dinvS[1] = dinv_gr_s; NP.dinvD[1] = dinv_gr_d;
    NP.dinvS[2] = dinv_rg_s; NP.dinvD[2] = dinv_rg_d;
    NP.dinvS[3] = dinv_rr;   NP.dinvD[3] = dinv_rr;
    enorm_k<<<dim3(ceil_div(NNODE, 4), 4), 256, 0, stream>>>(NP);

    // ---- fp16 features (part_degS and loc dead now) ----
    CvtP CV;
    CV.in[0] = x_gen;  CV.out[0] = xh_gen;
    CV.in[1] = x_rain; CV.out[1] = xh_rain;
    cvt_k<<<dim3(NNODE * DF / 4 / 256, 2), 256, 0, stream>>>(CV);

    // ---- layers ----
    for (int l = 0; l < 2; ++l) {
        SpmmP SP;
        for (int r = 0; r < 4; ++r) { SP.rowptr[r] = rowptr[r]; SP.ep[r] = ep[r]; }
        SP.x[0] = xh_gen; SP.x[1] = xh_gen; SP.x[2] = xh_rain; SP.x[3] = xh_rain;
        SP.out[0] = aggh_gg; SP.out[1] = aggh_gr; SP.out[2] = aggh_rg; SP.out[3] = aggh_rr;
        spmm4_k<<<20000, 256, 0, stream>>>(SP);

        Gemm2P GP;
        GP.A1[0] = aggh_gg; GP.A2[0] = aggh_rg;
        GP.A1[1] = aggh_gr; GP.A2[1] = aggh_rr;
        GP.Wt[0] = WtH + (size_t)(l * 2 + 0) * 128 * 256;
        GP.Wt[1] = WtH + (size_t)(l * 2 + 1) * 128 * 256;
        GP.bs[0] = bsum + (l * 2 + 0) * 128;
        GP.bs[1] = bsum + (l * 2 + 1) * 128;
        GP.out[0] = xh_gen;
        GP.out[1] = xh_rain;
        gemm2_k<<<dim3(ceil_div(NNODE, 64), 2), 256, 0, stream>>>(GP);
    }

    // ---- output heads ----
    Lin16P LP;
    LP.x[0] = xh_gen;  LP.W[0] = W_lg; LP.b[0] = b_lg; LP.out[0] = out_gen;
    LP.x[1] = xh_rain; LP.W[1] = W_lr; LP.b[1] = b_lr; LP.out[1] = out_rain;
    lin16_k<<<dim3(ceil_div(NNODE * DOUT, 256), 2), 256, 0, stream>>>(LP);
}

// Round 8
// 332.508 us; speedup vs baseline: 8.2990x; 1.0442x over previous
//
#include <hip/hip_runtime.h>
#include <hip/hip_fp16.h>

#define NNODE 20000
#define NE    600000
#define NES   (NE + NNODE)   // edges incl. self slots (relations gg, rr)
#define DF    128
#define DOUT  16
#define NB    64          // hist blocks per relation
#define CE    (NE/NB)     // 9375 edges per hist block (exact)
#define SUB   4           // scatter sub-blocks per chunk
#define CES   ((CE + SUB - 1) / SUB)   // 2344
#define NWORD 10000       // packed 16-bit pairs covering 20000 nodes
#define SB    32          // degree chunks per stream
#define CS    (NE/SB)     // 18750 edges per chunk (exact)

typedef _Float16 f16x8 __attribute__((ext_vector_type(8)));
typedef float f32x4 __attribute__((ext_vector_type(4)));

static inline int ceil_div(int a, int b) { return (a + b - 1) / b; }

// ---------------- fp32 -> fp16 conversion (4 floats/thread) ----------------
struct CvtP { const float* in[2]; __half* out[2]; };
__global__ __launch_bounds__(256) void cvt_k(CvtP P) {
    int g = blockIdx.y;
    int i = blockIdx.x * 256 + threadIdx.x;           // float4 index
    const float4* in = (const float4*)P.in[g];
    __half2* out = (__half2*)P.out[g];
    float4 v = in[i];
    out[2 * i + 0] = __floats2half2_rn(v.x, v.y);
    out[2 * i + 1] = __floats2half2_rn(v.z, v.w);
}

// ---------------- W prep: combined, transposed, fp16 + folded bias ----------------
__global__ __launch_bounds__(256) void prepW_k(const float* __restrict__ W_conv,
                                               const float* __restrict__ b_conv,
                                               __half* __restrict__ WtH,
                                               float* __restrict__ bsum) {
    int lg = blockIdx.y;
    int l = lg >> 1, g = lg & 1;
    int ra = (g == 0) ? 0 : 1;
    int rb = (g == 0) ? 2 : 3;
    int idx = blockIdx.x * 256 + threadIdx.x;    // 0..32767
    int col = idx >> 8, k = idx & 255;
    const float* Wa = W_conv + (size_t)(l * 4 + ra) * 128 * 128;
    const float* Wb = W_conv + (size_t)(l * 4 + rb) * 128 * 128;
    float v = (k < 128) ? Wa[k * 128 + col] : Wb[(k - 128) * 128 + col];
    WtH[((size_t)lg * 128 + col) * 256 + k] = __float2half(v);
    if (idx < 128)
        bsum[lg * 128 + idx] = 0.5f * (b_conv[(l * 4 + ra) * 128 + idx] +
                                       b_conv[(l * 4 + rb) * 128 + idx]);
}

// ---------------- phase H: per-chunk packed histogram + local slots ----------------
struct HistP { const int* col[4]; unsigned int* hist; unsigned short* loc[4]; };
__global__ __launch_bounds__(512) void hist_k(HistP P) {
    __shared__ unsigned int h[NWORD];   // 40 KB, 2x16-bit counts per word
    int b = blockIdx.x, r = blockIdx.y;
    for (int i = threadIdx.x; i < NWORD; i += 512) h[i] = 0u;
    __syncthreads();
    const int* col = P.col[r];
    unsigned short* loc = P.loc[r];
    int e0 = b * CE;
    for (int e = e0 + threadIdx.x; e < e0 + CE; e += 512) {
        int c = col[e];
        unsigned int sh = (unsigned)(c & 1) << 4;
        unsigned int old = atomicAdd(&h[c >> 1], 1u << sh);
        loc[e] = (unsigned short)((old >> sh) & 0xffffu);
    }
    __syncthreads();
    unsigned int* hg = P.hist + (size_t)(r * NB + b) * NWORD;
    for (int i = threadIdx.x; i < NWORD; i += 512) hg[i] = h[i];
}

// ---------------- per-node totals (+1 self slot for gg/rr) ----------------
__global__ __launch_bounds__(256) void sumcnt_k(const unsigned int* __restrict__ hist,
                                                int* __restrict__ cnt_all) {
    int r = blockIdx.y;
    int w = blockIdx.x * 256 + threadIdx.x;
    if (w >= NWORD) return;
    unsigned int lo = 0, hi = 0;
    const unsigned int* hp = hist + (size_t)r * NB * NWORD + w;
    for (int b = 0; b < NB; ++b) {
        unsigned int v = hp[(size_t)b * NWORD];
        lo += v & 0xffffu; hi += v >> 16;
    }
    int s = (r == 0 || r == 3) ? 1 : 0;   // self slot
    int* cnt = cnt_all + (size_t)r * NNODE;
    cnt[2 * w] = (int)lo + s;
    cnt[2 * w + 1] = (int)hi + s;
}

// exclusive scan over NNODE counts per relation; blockIdx.x = relation
__global__ void exscan4_k(const int* __restrict__ cnt_all, int* __restrict__ rowptr_all) {
    __shared__ int sums[1024];
    const int* cnt = cnt_all + (size_t)blockIdx.x * NNODE;
    int* rowptr = rowptr_all + (size_t)blockIdx.x * (NNODE + 1);
    int t = threadIdx.x;
    int chunk = (NNODE + 1023) >> 10;
    int b = t * chunk; if (b > NNODE) b = NNODE;
    int e = b + chunk; if (e > NNODE) e = NNODE;
    int s = 0;
    for (int i = b; i < e; ++i) s += cnt[i];
    sums[t] = s;
    __syncthreads();
    for (int off = 1; off < 1024; off <<= 1) {
        int v = (t >= off) ? sums[t - off] : 0;
        __syncthreads();
        sums[t] += v;
        __syncthreads();
    }
    int run = (t == 0) ? 0 : sums[t - 1];
    for (int i = b; i < e; ++i) { rowptr[i] = run; run += cnt[i]; }
    if (t == 1023) rowptr[NNODE] = run;
}

// ---------------- per-(block,node) global bases ----------------
__global__ __launch_bounds__(256) void mkbase_k(const unsigned int* __restrict__ hist,
                                               const int* __restrict__ rowptr_all,
                                               int* __restrict__ base) {
    int r = blockIdx.y;
    int w = blockIdx.x * 256 + threadIdx.x;
    if (w >= NWORD) return;
    const int* rowptr = rowptr_all + (size_t)r * (NNODE + 1);
    int s = (r == 0 || r == 3) ? 1 : 0;   // skip reserved self slot
    int lo = rowptr[2 * w] + s, hi = rowptr[2 * w + 1] + s;
    const unsigned int* hp = hist + (size_t)r * NB * NWORD + w;
    int* bp = base + (size_t)r * NB * NNODE;
    for (int b = 0; b < NB; ++b) {
        bp[(size_t)b * NNODE + 2 * w]     = lo;
        bp[(size_t)b * NNODE + 2 * w + 1] = hi;
        unsigned int v = hp[(size_t)b * NWORD];
        lo += (int)(v & 0xffffu);
        hi += (int)(v >> 16);
    }
}

// ---------------- all 6 weighted degrees via LDS partials over raw streams ----------------
struct DegAP { const int* idx[6]; const float* wgt[6]; float* part; };
__global__ __launch_bounds__(256) void degAll_part_k(DegAP P) {
    __shared__ float t[NWORD];   // 40 KB, covers 10000 nodes
    int s = blockIdx.y;
    int chunk = blockIdx.x >> 1, half = blockIdx.x & 1;
    int nbase = half * NWORD;
    for (int i = threadIdx.x; i < NWORD; i += 256) t[i] = 0.f;
    __syncthreads();
    const int* idx = P.idx[s];
    const float* w = P.wgt[s];
    int e0 = chunk * CS;
    for (int e = e0 + threadIdx.x; e < e0 + CS; e += 256) {
        int rr = idx[e] - nbase;
        if ((unsigned)rr < (unsigned)NWORD) atomicAdd(&t[rr], w[e]);
    }
    __syncthreads();
    float* pp = P.part + ((size_t)s * SB + chunk) * NNODE + nbase;
    for (int i = threadIdx.x; i < NWORD; i += 256) pp[i] = t[i];
}

struct DegAS { const float* part; float* dinv[6]; float selfw[6]; };
__global__ __launch_bounds__(256) void degAll_sum_k(DegAS P) {
    int s = blockIdx.y;
    int n = blockIdx.x * 256 + threadIdx.x;
    if (n >= NNODE) return;
    const float* pp = P.part + (size_t)s * SB * NNODE + n;
    float acc = P.selfw[s];
    for (int c = 0; c < SB; ++c) acc += pp[(size_t)c * NNODE];
    P.dinv[s][n] = acc > 0.f ? rsqrtf(acc) : 0.f;
}

// ---------------- self edges (packed) into reserved slot 0 (gg, rr) ----------------
__global__ __launch_bounds__(256) void selfscat_k(const int* __restrict__ rp0, unsigned int* ep0,
                                                  const float* __restrict__ dgg,
                                                  const int* __restrict__ rp3, unsigned int* ep3,
                                                  const float* __restrict__ drr) {
    int n = blockIdx.x * 256 + threadIdx.x;
    if (n >= NNODE) return;
    float d0 = dgg[n], d3 = drr[n];
    __half h0 = __float2half(d0 * d0);
    __half h3 = __float2half(d3 * d3);
    ep0[rp0[n]] = ((unsigned)n << 16) | *reinterpret_cast<unsigned short*>(&h0);
    ep3[rp3[n]] = ((unsigned)n << 16) | *reinterpret_cast<unsigned short*>(&h3);
}

// ---------------- scatter: atomic-free, packed 4B records with norm folded ----------------
struct Scat4P {
    const int* row[4]; const int* col[4]; const float* w[4];
    const unsigned short* loc[4]; const int* base;
    const float* dS[4]; const float* dD[4];
    unsigned int* ep[4];
};
__global__ __launch_bounds__(256) void scat4_k(Scat4P P) {
    int bs = blockIdx.x;                 // 0..NB*SUB-1
    int b = bs >> 2, s = bs & 3;         // SUB = 4
    int r = blockIdx.y;
    const int* bp = P.base + ((size_t)r * NB + b) * NNODE;
    const int* row = P.row[r];
    const int* col = P.col[r];
    const float* w = P.w[r];
    const float* dS = P.dS[r];
    const float* dD = P.dD[r];
    const unsigned short* loc = P.loc[r];
    unsigned int* ep = P.ep[r];
    int e0 = b * CE + s * CES;
    int e1 = e0 + CES;
    int cap = b * CE + CE;
    if (e1 > cap) e1 = cap;
    for (int e = e0 + threadIdx.x; e < e1; e += 256) {
        int c = col[e];
        int src = row[e];
        float nm = dS[src] * w[e] * dD[c];
        int pos = bp[c] + (int)loc[e];
        __half hh = __float2half(nm);
        ep[pos] = ((unsigned)src << 16) | *reinterpret_cast<unsigned short*>(&hh);
    }
}

// ---------------- pull-SpMM: quarter-wave row gather, packed edges, fp16 out ----------------
struct SpmmP {
    const __half* x[4]; const int* rowptr[4]; const unsigned int* ep[4]; __half* out[4];
};
__global__ __launch_bounds__(256) void spmm4_k(SpmmP P) {
    // grid = 20000 blocks, 4 waves/block, 1 node/wave; XCD-partitioned by src table.
    int b = blockIdx.x;
    int xcd = b & 7;
    int j = b >> 3;                               // 0..2499
    int r = ((xcd >> 2) << 1) + (j >= 1250 ? 1 : 0);
    int nodeblk = (xcd & 3) * 1250 + (j >= 1250 ? j - 1250 : j);
    int wid = nodeblk * 4 + (threadIdx.x >> 6);
    int lane = threadIdx.x & 63;
    int q = lane >> 4, c = lane & 15;             // quarter id, lane-in-quarter
    const uint4* x4 = (const uint4*)P.x[r];       // row = 16 x uint4 (8 fp16 each)
    const int* rp = P.rowptr[r];
    int bb = rp[wid], ee = rp[wid + 1];
    const unsigned int* ep = P.ep[r];
    float a[8];
#pragma unroll
    for (int t = 0; t < 8; ++t) a[t] = 0.f;

    auto decn = [](unsigned int v) -> float {
        unsigned short us = (unsigned short)(v & 0xffffu);
        __half h = *reinterpret_cast<__half*>(&us);
        return __half2float(h);
    };
    auto accum = [&](uint4 p, float n) {
        const __half2* ph = (const __half2*)&p;
#pragma unroll
        for (int t = 0; t < 4; ++t) {
            float2 f = __half22float2(ph[t]);
            a[2 * t]     = fmaf(f.x, n, a[2 * t]);
            a[2 * t + 1] = fmaf(f.y, n, a[2 * t + 1]);
        }
    };

    int i = bb + q;
    for (; i + 4 < ee; i += 8) {                  // 2 edges per quarter in flight
        unsigned int v0 = ep[i], v1 = ep[i + 4];
        uint4 p0 = x4[(size_t)(v0 >> 16) * 16 + c];
        uint4 p1 = x4[(size_t)(v1 >> 16) * 16 + c];
        accum(p0, decn(v0));
        accum(p1, decn(v1));
    }
    if (i < ee) {
        unsigned int v0 = ep[i];
        uint4 p0 = x4[(size_t)(v0 >> 16) * 16 + c];
        accum(p0, decn(v0));
    }
#pragma unroll
    for (int t = 0; t < 8; ++t) {
        a[t] += __shfl_xor(a[t], 16, 64);
        a[t] += __shfl_xor(a[t], 32, 64);
    }
    if (q == 0) {
        __half2 h[4];
#pragma unroll
        for (int t = 0; t < 4; ++t) h[t] = __floats2half2_rn(a[2 * t], a[2 * t + 1]);
        ((uint4*)P.out[r])[(size_t)wid * 16 + c] = *(uint4*)h;
    }
}

// ---------------- MFMA gemm2: relu(0.5*(A1@Wa + A2@Wb) + bsum) -> fp16 ----------------
struct Gemm2P {
    const __half* A1[2]; const __half* A2[2];
    const __half* Wt[2];   // [128 col][256 k] fp16 (k<128: Wa, else Wb)
    const float* bs[2];    // 0.5*(ba+bb)
    __half* out[2];
};
__global__ __launch_bounds__(256) void gemm2_k(Gemm2P P) {
    __shared__ __half sW[128 * 136];   // one 128-K slab, padded stride
    int g = blockIdx.y;
    int w = threadIdx.x >> 6, l = threadIdx.x & 63;
    int r0 = blockIdx.x * 64 + w * 16;
    int lm = l & 15, lh = l >> 4;
    f32x4 acc[8];
    f32x4 zero = {0.f, 0.f, 0.f, 0.f};
#pragma unroll
    for (int n = 0; n < 8; ++n) acc[n] = zero;
    const __half* As[2] = { P.A1[g], P.A2[g] };
    const uint4* wg = (const uint4*)P.Wt[g];
    int arow = r0 + lm;
    bool rok = arow < NNODE;
    for (int s = 0; s < 2; ++s) {
        __syncthreads();
        for (int u = threadIdx.x; u < 2048; u += 256) {   // stage 32 KB slab
            int col = u >> 4, kb8 = u & 15;               // kb = kb8*8
            uint4 vv = wg[col * 32 + s * 16 + kb8];
            *(uint4*)&sW[col * 136 + kb8 * 8] = vv;
        }
        __syncthreads();
        const uint4* a4 = (const uint4*)As[s];
#pragma unroll
        for (int kk = 0; kk < 4; ++kk) {
            uint4 av = make_uint4(0, 0, 0, 0);
            if (rok) av = a4[(size_t)arow * 16 + kk * 4 + lh];
            f16x8 af = *(f16x8*)&av;
#pragma unroll
            for (int n = 0; n < 8; ++n) {
                uint4 bv = *(uint4*)&sW[(n * 16 + lm) * 136 + kk * 32 + lh * 8];
                f16x8 bf = *(f16x8*)&bv;
                acc[n] = __builtin_amdgcn_mfma_f32_16x16x32_f16(af, bf, acc[n], 0, 0, 0);
            }
        }
    }
    __half* out = P.out[g];
    const float* bs = P.bs[g];
#pragma unroll
    for (int n = 0; n < 8; ++n) {
        int colg = n * 16 + lm;
        float bb = bs[colg];
#pragma unroll
        for (int qq = 0; qq < 4; ++qq) {
            int rowg = r0 + lh * 4 + qq;
            if (rowg < NNODE) {
                float v = fmaf(acc[n][qq], 0.5f, bb);
                out[(size_t)rowg * 128 + colg] = __float2half(v > 0.f ? v : 0.f);
            }
        }
    }
}

struct Lin16P { const __half* x[2]; const float* W[2]; const float* b[2]; float* out[2]; };
__global__ __launch_bounds__(256) void lin16_k(Lin16P P) {
    int g = blockIdx.y;
    int idx = blockIdx.x * 256 + threadIdx.x;
    int row = idx >> 4, c = idx & 15;
    if (row >= NNODE) return;
    const __half* xr = P.x[g] + (size_t)row * 128;
    const float* W = P.W[g];
    float acc = P.b[g][c];
    for (int k = 0; k < 128; ++k) acc += __half2float(xr[k]) * W[k * 16 + c];
    P.out[g][(size_t)row * 16 + c] = acc;
}

extern "C" void kernel_launch(void* const* d_in, const int* in_sizes, int n_in,
                              void* d_out, int out_size, void* d_ws, size_t ws_size,
                              hipStream_t stream) {
    (void)in_sizes; (void)n_in; (void)out_size; (void)ws_size;

    const float* x_gen  = (const float*)d_in[0];
    const float* x_rain = (const float*)d_in[1];
    const int* ei[4] = {(const int*)d_in[2], (const int*)d_in[3], (const int*)d_in[4], (const int*)d_in[5]};
    const float* w[4] = {(const float*)d_in[6], (const float*)d_in[7], (const float*)d_in[8], (const float*)d_in[9]};
    const float* W_conv = (const float*)d_in[10];  // [2][4][128][128]
    const float* b_conv = (const float*)d_in[11];  // [2][4][128]
    const float* W_lg = (const float*)d_in[12];
    const float* b_lg = (const float*)d_in[13];
    const float* W_lr = (const float*)d_in[14];
    const float* b_lr = (const float*)d_in[15];

    float* out_gen  = (float*)d_out;
    float* out_rain = out_gen + (size_t)NNODE * DOUT;

    char* p = (char*)d_ws;
    auto alloc = [&](size_t bytes) -> void* {
        void* r = (void*)p;
        p += (bytes + 255) & ~(size_t)255;
        return r;
    };

    // dinv layout: [gr_s | rg_s | gg | gr_d | rg_d | rr]
    float* deg = (float*)alloc(6 * (size_t)NNODE * sizeof(float));
    float* dinv_gr_s = deg + 0 * NNODE;
    float* dinv_rg_s = deg + 1 * NNODE;
    float* dinv_gg   = deg + 2 * NNODE;
    float* dinv_gr_d = deg + 3 * NNODE;
    float* dinv_rg_d = deg + 4 * NNODE;
    float* dinv_rr   = deg + 5 * NNODE;

    int*  cnt_all    = (int*)alloc(4 * (size_t)NNODE * sizeof(int));
    int*  rowptr_all = (int*)alloc(4 * (size_t)(NNODE + 1) * sizeof(int));

    // epack (9.92 MB) shares a 10.24 MB block with hist_all (dead after mkbase)
    size_t epack_bytes = 4 * (size_t)NES * sizeof(unsigned int);
    size_t hist_bytes  = 4 * (size_t)NB * NWORD * sizeof(unsigned int);
    unsigned int* epack_all = (unsigned int*)alloc(epack_bytes > hist_bytes ? epack_bytes : hist_bytes);
    unsigned int* hist_all  = epack_all;

    // agg region (20.48 MB) also hosts, sequentially: degAll partials (15.36 MB,
    // dead after degAll_sum) then base (20.48 MB, dead after scat4)
    __half* agg_all = (__half*)alloc(4 * (size_t)NNODE * DF * sizeof(__half));
    __half* aggh_gg = agg_all + 0 * (size_t)NNODE * DF;
    __half* aggh_gr = agg_all + 1 * (size_t)NNODE * DF;
    __half* aggh_rg = agg_all + 2 * (size_t)NNODE * DF;
    __half* aggh_rr = agg_all + 3 * (size_t)NNODE * DF;
    __half* xh_gen  = (__half*)alloc((size_t)NNODE * DF * sizeof(__half));
    __half* xh_rain = (__half*)alloc((size_t)NNODE * DF * sizeof(__half));

    __half* WtH  = (__half*)alloc(4 * (size_t)128 * 256 * sizeof(__half));   // 256 KB
    float*  bsum = (float*)alloc(4 * 128 * sizeof(float));

    float* part_all = (float*)agg_all;                   // 15.36 MB, dead after degAll_sum
    int*   base_all = (int*)agg_all;                     // 20.48 MB, dead after scat4
    unsigned short* loc_all = (unsigned short*)xh_rain;  // 4.8 MB in 5.12, dead after scat4

    int* rowptr[4]; unsigned short* loc[4]; unsigned int* ep[4];
    for (int r = 0; r < 4; ++r) {
        rowptr[r] = rowptr_all + (size_t)r * (NNODE + 1);
        loc[r]    = loc_all + (size_t)r * NE;
        ep[r]     = epack_all + (size_t)r * NES;
    }

    const int* rows_[4] = {ei[0], ei[1], ei[2], ei[3]};
    const int* cols_[4] = {ei[0] + NE, ei[1] + NE, ei[2] + NE, ei[3] + NE};

    // ---- W prep (independent) ----
    prepW_k<<<dim3(128, 4), 256, 0, stream>>>(W_conv, b_conv, WtH, bsum);

    // ---- histogram + local slots ----
    HistP HP;
    for (int r = 0; r < 4; ++r) { HP.col[r] = cols_[r]; HP.loc[r] = loc[r]; }
    HP.hist = hist_all;
    hist_k<<<dim3(NB, 4), 512, 0, stream>>>(HP);

    sumcnt_k<<<dim3(ceil_div(NWORD, 256), 4), 256, 0, stream>>>(hist_all, cnt_all);

    // ---- all 6 degree vectors from raw streams (partials live in agg region) ----
    DegAP DA;
    DA.idx[0] = cols_[0]; DA.wgt[0] = w[0];   // gg dst (= both sides)
    DA.idx[1] = rows_[1]; DA.wgt[1] = w[1];   // gr src
    DA.idx[2] = cols_[1]; DA.wgt[2] = w[1];   // gr dst
    DA.idx[3] = rows_[2]; DA.wgt[3] = w[2];   // rg src
    DA.idx[4] = cols_[2]; DA.wgt[4] = w[2];   // rg dst
    DA.idx[5] = cols_[3]; DA.wgt[5] = w[3];   // rr dst
    DA.part = part_all;
    degAll_part_k<<<dim3(SB * 2, 6), 256, 0, stream>>>(DA);

    DegAS DAS;
    DAS.part = part_all;
    DAS.dinv[0] = dinv_gg;   DAS.selfw[0] = 1.f;
    DAS.dinv[1] = dinv_gr_s; DAS.selfw[1] = 0.f;
    DAS.dinv[2] = dinv_gr_d; DAS.selfw[2] = 0.f;
    DAS.dinv[3] = dinv_rg_s; DAS.selfw[3] = 0.f;
    DAS.dinv[4] = dinv_rg_d; DAS.selfw[4] = 0.f;
    DAS.dinv[5] = dinv_rr;   DAS.selfw[5] = 1.f;
    degAll_sum_k<<<dim3(ceil_div(NNODE, 256), 6), 256, 0, stream>>>(DAS);

    // ---- scan + bases (base overwrites partials; they are dead) ----
    exscan4_k<<<4, 1024, 0, stream>>>(cnt_all, rowptr_all);
    mkbase_k<<<dim3(ceil_div(NWORD, 256), 4), 256, 0, stream>>>(hist_all, rowptr_all, base_all);

    // ---- scatter packed records (norm folded); self edges ----
    selfscat_k<<<ceil_div(NNODE, 256), 256, 0, stream>>>(rowptr[0], ep[0], dinv_gg,
                                                         rowptr[3], ep[3], dinv_rr);
    Scat4P SC;
    for (int r = 0; r < 4; ++r) {
        SC.row[r] = rows_[r]; SC.col[r] = cols_[r]; SC.w[r] = w[r];
        SC.loc[r] = loc[r]; SC.ep[r] = ep[r];
    }
    SC.base = base_all;
    SC.dS[0] = dinv_gg;   SC.dD[0] = dinv_gg;
    SC.dS[1] = dinv_gr_s; SC.dD[1] = dinv_gr_d;
    SC.dS[2] = dinv_rg_s; SC.dD[2] = dinv_rg_d;
    SC.dS[3] = dinv_rr;   SC.dD[3] = dinv_rr;
    scat4_k<<<dim3(NB * SUB, 4), 256, 0, stream>>>(SC);

    // ---- fp16 features (loc region dead now) ----
    CvtP CV;
    CV.in[0] = x_gen;  CV.out[0] = xh_gen;
    CV.in[1] = x_rain; CV.out[1] = xh_rain;
    cvt_k<<<dim3(NNODE * DF / 4 / 256, 2), 256, 0, stream>>>(CV);

    // ---- layers ----
    for (int l = 0; l < 2; ++l) {
        SpmmP SP;
        for (int r = 0; r < 4; ++r) { SP.rowptr[r] = rowptr[r]; SP.ep[r] = ep[r]; }
        SP.x[0] = xh_gen; SP.x[1] = xh_gen; SP.x[2] = xh_rain; SP.x[3] = xh_rain;
        SP.out[0] = aggh_gg; SP.out[1] = aggh_gr; SP.out[2] = aggh_rg; SP.out[3] = aggh_rr;
        spmm4_k<<<20000, 256, 0, stream>>>(SP);

        Gemm2P GP;
        GP.A1[0] = aggh_gg; GP.A2[0] = aggh_rg;
        GP.A1[1] = aggh_gr; GP.A2[1] = aggh_rr;
        GP.Wt[0] = WtH + (size_t)(l * 2 + 0) * 128 * 256;
        GP.Wt[1] = WtH + (size_t)(l * 2 + 1) * 128 * 256;
        GP.bs[0] = bsum + (l * 2 + 0) * 128;
        GP.bs[1] = bsum + (l * 2 + 1) * 128;
        GP.out[0] = xh_gen;
        GP.out[1] = xh_rain;
        gemm2_k<<<dim3(ceil_div(NNODE, 64), 2), 256, 0, stream>>>(GP);
    }

    // ---- output heads ----
    Lin16P LP;
    LP.x[0] = xh_gen;  LP.W[0] = W_lg; LP.b[0] = b_lg; LP.out[0] = out_gen;
    LP.x[1] = xh_rain; LP.W[1] = W_lr; LP.b[1] = b_lr; LP.out[1] = out_rain;
    lin16_k<<<dim3(ceil_div(NNODE * DOUT, 256), 2), 256, 0, stream>>>(LP);
}

// Round 9
// 314.086 us; speedup vs baseline: 8.7857x; 1.0587x over previous
//
#include <hip/hip_runtime.h>
#include <hip/hip_fp16.h>

#define NNODE 20000
#define NE    600000
#define NES   (NE + NNODE)   // edges incl. self slots (relations gg, rr)
#define DF    128
#define DOUT  16
#define NB    64          // hist blocks per relation
#define CE    (NE/NB)     // 9375 edges per hist block (exact)
#define SUB   4           // scatter sub-blocks per chunk
#define CES   ((CE + SUB - 1) / SUB)   // 2344
#define NWORD 10000       // packed 16-bit pairs covering 20000 nodes
#define SB    32          // degree chunks per stream
#define CS    (NE/SB)     // 18750 edges per chunk (exact)

typedef _Float16 f16x8 __attribute__((ext_vector_type(8)));
typedef float f32x4 __attribute__((ext_vector_type(4)));

static inline int ceil_div(int a, int b) { return (a + b - 1) / b; }

// ---------------- fp32 -> fp16 conversion (4 floats/thread) ----------------
struct CvtP { const float* in[2]; __half* out[2]; };
__global__ __launch_bounds__(256) void cvt_k(CvtP P) {
    int g = blockIdx.y;
    int i = blockIdx.x * 256 + threadIdx.x;           // float4 index
    const float4* in = (const float4*)P.in[g];
    __half2* out = (__half2*)P.out[g];
    float4 v = in[i];
    out[2 * i + 0] = __floats2half2_rn(v.x, v.y);
    out[2 * i + 1] = __floats2half2_rn(v.z, v.w);
}

// ---------------- W prep: combined, transposed, fp16 + folded bias ----------------
__global__ __launch_bounds__(256) void prepW_k(const float* __restrict__ W_conv,
                                               const float* __restrict__ b_conv,
                                               __half* __restrict__ WtH,
                                               float* __restrict__ bsum) {
    int lg = blockIdx.y;
    int l = lg >> 1, g = lg & 1;
    int ra = (g == 0) ? 0 : 1;
    int rb = (g == 0) ? 2 : 3;
    int idx = blockIdx.x * 256 + threadIdx.x;    // 0..32767
    int col = idx >> 8, k = idx & 255;
    const float* Wa = W_conv + (size_t)(l * 4 + ra) * 128 * 128;
    const float* Wb = W_conv + (size_t)(l * 4 + rb) * 128 * 128;
    float v = (k < 128) ? Wa[k * 128 + col] : Wb[(k - 128) * 128 + col];
    WtH[((size_t)lg * 128 + col) * 256 + k] = __float2half(v);
    if (idx < 128)
        bsum[lg * 128 + idx] = 0.5f * (b_conv[(l * 4 + ra) * 128 + idx] +
                                       b_conv[(l * 4 + rb) * 128 + idx]);
}

// ---------------- phase H: per-chunk packed histogram + local slots ----------------
struct HistP { const int* col[4]; unsigned int* hist; unsigned short* loc[4]; };
__global__ __launch_bounds__(512) void hist_k(HistP P) {
    __shared__ unsigned int h[NWORD];   // 40 KB, 2x16-bit counts per word
    int b = blockIdx.x, r = blockIdx.y;
    for (int i = threadIdx.x; i < NWORD; i += 512) h[i] = 0u;
    __syncthreads();
    const int* col = P.col[r];
    unsigned short* loc = P.loc[r];
    int e0 = b * CE;
    for (int e = e0 + threadIdx.x; e < e0 + CE; e += 512) {
        int c = col[e];
        unsigned int sh = (unsigned)(c & 1) << 4;
        unsigned int old = atomicAdd(&h[c >> 1], 1u << sh);
        loc[e] = (unsigned short)((old >> sh) & 0xffffu);
    }
    __syncthreads();
    unsigned int* hg = P.hist + (size_t)(r * NB + b) * NWORD;
    for (int i = threadIdx.x; i < NWORD; i += 512) hg[i] = h[i];
}

// ---------------- per-node totals (+1 self slot for gg/rr) ----------------
__global__ __launch_bounds__(256) void sumcnt_k(const unsigned int* __restrict__ hist,
                                                int* __restrict__ cnt_all) {
    int r = blockIdx.y;
    int w = blockIdx.x * 256 + threadIdx.x;
    if (w >= NWORD) return;
    unsigned int lo = 0, hi = 0;
    const unsigned int* hp = hist + (size_t)r * NB * NWORD + w;
    for (int b = 0; b < NB; ++b) {
        unsigned int v = hp[(size_t)b * NWORD];
        lo += v & 0xffffu; hi += v >> 16;
    }
    int s = (r == 0 || r == 3) ? 1 : 0;   // self slot
    int* cnt = cnt_all + (size_t)r * NNODE;
    cnt[2 * w] = (int)lo + s;
    cnt[2 * w + 1] = (int)hi + s;
}

// exclusive scan over NNODE counts per relation; blockIdx.x = relation
__global__ void exscan4_k(const int* __restrict__ cnt_all, int* __restrict__ rowptr_all) {
    __shared__ int sums[1024];
    const int* cnt = cnt_all + (size_t)blockIdx.x * NNODE;
    int* rowptr = rowptr_all + (size_t)blockIdx.x * (NNODE + 1);
    int t = threadIdx.x;
    int chunk = (NNODE + 1023) >> 10;
    int b = t * chunk; if (b > NNODE) b = NNODE;
    int e = b + chunk; if (e > NNODE) e = NNODE;
    int s = 0;
    for (int i = b; i < e; ++i) s += cnt[i];
    sums[t] = s;
    __syncthreads();
    for (int off = 1; off < 1024; off <<= 1) {
        int v = (t >= off) ? sums[t - off] : 0;
        __syncthreads();
        sums[t] += v;
        __syncthreads();
    }
    int run = (t == 0) ? 0 : sums[t - 1];
    for (int i = b; i < e; ++i) { rowptr[i] = run; run += cnt[i]; }
    if (t == 1023) rowptr[NNODE] = run;
}

// ---------------- per-(block,node) global bases ----------------
__global__ __launch_bounds__(256) void mkbase_k(const unsigned int* __restrict__ hist,
                                               const int* __restrict__ rowptr_all,
                                               int* __restrict__ base) {
    int r = blockIdx.y;
    int w = blockIdx.x * 256 + threadIdx.x;
    if (w >= NWORD) return;
    const int* rowptr = rowptr_all + (size_t)r * (NNODE + 1);
    int s = (r == 0 || r == 3) ? 1 : 0;   // skip reserved self slot
    int lo = rowptr[2 * w] + s, hi = rowptr[2 * w + 1] + s;
    const unsigned int* hp = hist + (size_t)r * NB * NWORD + w;
    int* bp = base + (size_t)r * NB * NNODE;
    for (int b = 0; b < NB; ++b) {
        bp[(size_t)b * NNODE + 2 * w]     = lo;
        bp[(size_t)b * NNODE + 2 * w + 1] = hi;
        unsigned int v = hp[(size_t)b * NWORD];
        lo += (int)(v & 0xffffu);
        hi += (int)(v >> 16);
    }
}

// ---------------- all 6 weighted degrees via LDS partials over raw streams ----------------
struct DegAP { const int* idx[6]; const float* wgt[6]; float* part; };
__global__ __launch_bounds__(256) void degAll_part_k(DegAP P) {
    __shared__ float t[NWORD];   // 40 KB, covers 10000 nodes
    int s = blockIdx.y;
    int chunk = blockIdx.x >> 1, half = blockIdx.x & 1;
    int nbase = half * NWORD;
    for (int i = threadIdx.x; i < NWORD; i += 256) t[i] = 0.f;
    __syncthreads();
    const int* idx = P.idx[s];
    const float* w = P.wgt[s];
    int e0 = chunk * CS;
    for (int e = e0 + threadIdx.x; e < e0 + CS; e += 256) {
        int rr = idx[e] - nbase;
        if ((unsigned)rr < (unsigned)NWORD) atomicAdd(&t[rr], w[e]);
    }
    __syncthreads();
    float* pp = P.part + ((size_t)s * SB + chunk) * NNODE + nbase;
    for (int i = threadIdx.x; i < NWORD; i += 256) pp[i] = t[i];
}

struct DegAS { const float* part; float* dinv[6]; float selfw[6]; };
__global__ __launch_bounds__(256) void degAll_sum_k(DegAS P) {
    int s = blockIdx.y;
    int n = blockIdx.x * 256 + threadIdx.x;
    if (n >= NNODE) return;
    const float* pp = P.part + (size_t)s * SB * NNODE + n;
    float acc = P.selfw[s];
    for (int c = 0; c < SB; ++c) acc += pp[(size_t)c * NNODE];
    P.dinv[s][n] = acc > 0.f ? rsqrtf(acc) : 0.f;
}

// ---------------- self edges (packed) into reserved slot 0 (gg, rr) ----------------
__global__ __launch_bounds__(256) void selfscat_k(const int* __restrict__ rp0, unsigned int* ep0,
                                                  const float* __restrict__ dgg,
                                                  const int* __restrict__ rp3, unsigned int* ep3,
                                                  const float* __restrict__ drr) {
    int n = blockIdx.x * 256 + threadIdx.x;
    if (n >= NNODE) return;
    float d0 = dgg[n], d3 = drr[n];
    __half h0 = __float2half(d0 * d0);
    __half h3 = __float2half(d3 * d3);
    ep0[rp0[n]] = ((unsigned)n << 16) | *reinterpret_cast<unsigned short*>(&h0);
    ep3[rp3[n]] = ((unsigned)n << 16) | *reinterpret_cast<unsigned short*>(&h3);
}

// ---------------- scatter: atomic-free, packed 4B records, XCD-pinned per relation ----------------
// grid = 1024 blocks 1D. xcd = bid&7 (dispatch round-robin); r = xcd>>1 so each
// relation's ep region (2.48 MB) accumulates dirty lines in only 2 XCD L2s ->
// partial-line RMW fragments merge in L2 instead of thrashing to HBM.
struct Scat4P {
    const int* row[4]; const int* col[4]; const float* w[4];
    const unsigned short* loc[4]; const int* base;
    const float* dS[4]; const float* dD[4];
    unsigned int* ep[4];
};
__global__ __launch_bounds__(256) void scat4_k(Scat4P P) {
    int bid = blockIdx.x;
    int xcd = bid & 7;
    int r = xcd >> 1;
    int j = bid >> 3;                    // 0..127 within-XCD
    int cs = (xcd & 1) * 128 + j;        // chunk-sub 0..255 for this relation
    int b = cs >> 2, s = cs & 3;         // SUB = 4; chunk's 4 subs share one XCD
    const int* bp = P.base + ((size_t)r * NB + b) * NNODE;
    const int* row = P.row[r];
    const int* col = P.col[r];
    const float* w = P.w[r];
    const float* dS = P.dS[r];
    const float* dD = P.dD[r];
    const unsigned short* loc = P.loc[r];
    unsigned int* ep = P.ep[r];
    int e0 = b * CE + s * CES;
    int e1 = e0 + CES;
    int cap = b * CE + CE;
    if (e1 > cap) e1 = cap;
    for (int e = e0 + threadIdx.x; e < e1; e += 256) {
        int c = col[e];
        int src = row[e];
        float nm = dS[src] * w[e] * dD[c];
        int pos = bp[c] + (int)loc[e];
        __half hh = __float2half(nm);
        ep[pos] = ((unsigned)src << 16) | *reinterpret_cast<unsigned short*>(&hh);
    }
}

// ---------------- pull-SpMM: quarter-wave row gather, packed edges, fp16 out ----------------
struct SpmmP {
    const __half* x[4]; const int* rowptr[4]; const unsigned int* ep[4]; __half* out[4];
};
__global__ __launch_bounds__(256) void spmm4_k(SpmmP P) {
    // grid = 20000 blocks, 4 waves/block, 1 node/wave; XCD-partitioned by src table.
    int b = blockIdx.x;
    int xcd = b & 7;
    int j = b >> 3;                               // 0..2499
    int r = ((xcd >> 2) << 1) + (j >= 1250 ? 1 : 0);
    int nodeblk = (xcd & 3) * 1250 + (j >= 1250 ? j - 1250 : j);
    int wid = nodeblk * 4 + (threadIdx.x >> 6);
    int lane = threadIdx.x & 63;
    int q = lane >> 4, c = lane & 15;             // quarter id, lane-in-quarter
    const uint4* x4 = (const uint4*)P.x[r];       // row = 16 x uint4 (8 fp16 each)
    const int* rp = P.rowptr[r];
    int bb = rp[wid], ee = rp[wid + 1];
    const unsigned int* ep = P.ep[r];
    float a[8];
#pragma unroll
    for (int t = 0; t < 8; ++t) a[t] = 0.f;

    auto decn = [](unsigned int v) -> float {
        unsigned short us = (unsigned short)(v & 0xffffu);
        __half h = *reinterpret_cast<__half*>(&us);
        return __half2float(h);
    };
    auto accum = [&](uint4 p, float n) {
        const __half2* ph = (const __half2*)&p;
#pragma unroll
        for (int t = 0; t < 4; ++t) {
            float2 f = __half22float2(ph[t]);
            a[2 * t]     = fmaf(f.x, n, a[2 * t]);
            a[2 * t + 1] = fmaf(f.y, n, a[2 * t + 1]);
        }
    };

    int i = bb + q;
    for (; i + 4 < ee; i += 8) {                  // 2 edges per quarter in flight
        unsigned int v0 = ep[i], v1 = ep[i + 4];
        uint4 p0 = x4[(size_t)(v0 >> 16) * 16 + c];
        uint4 p1 = x4[(size_t)(v1 >> 16) * 16 + c];
        accum(p0, decn(v0));
        accum(p1, decn(v1));
    }
    if (i < ee) {
        unsigned int v0 = ep[i];
        uint4 p0 = x4[(size_t)(v0 >> 16) * 16 + c];
        accum(p0, decn(v0));
    }
#pragma unroll
    for (int t = 0; t < 8; ++t) {
        a[t] += __shfl_xor(a[t], 16, 64);
        a[t] += __shfl_xor(a[t], 32, 64);
    }
    if (q == 0) {
        __half2 h[4];
#pragma unroll
        for (int t = 0; t < 4; ++t) h[t] = __floats2half2_rn(a[2 * t], a[2 * t + 1]);
        ((uint4*)P.out[r])[(size_t)wid * 16 + c] = *(uint4*)h;
    }
}

// ---------------- MFMA gemm2: relu(0.5*(A1@Wa + A2@Wb) + bsum) -> fp16 ----------------
struct Gemm2P {
    const __half* A1[2]; const __half* A2[2];
    const __half* Wt[2];   // [128 col][256 k] fp16 (k<128: Wa, else Wb)
    const float* bs[2];    // 0.5*(ba+bb)
    __half* out[2];
};
__global__ __launch_bounds__(256) void gemm2_k(Gemm2P P) {
    __shared__ __half sW[128 * 136];   // one 128-K slab, padded stride
    int g = blockIdx.y;
    int w = threadIdx.x >> 6, l = threadIdx.x & 63;
    int r0 = blockIdx.x * 64 + w * 16;
    int lm = l & 15, lh = l >> 4;
    f32x4 acc[8];
    f32x4 zero = {0.f, 0.f, 0.f, 0.f};
#pragma unroll
    for (int n = 0; n < 8; ++n) acc[n] = zero;
    const __half* As[2] = { P.A1[g], P.A2[g] };
    const uint4* wg = (const uint4*)P.Wt[g];
    int arow = r0 + lm;
    bool rok = arow < NNODE;
    for (int s = 0; s < 2; ++s) {
        __syncthreads();
        for (int u = threadIdx.x; u < 2048; u += 256) {   // stage 32 KB slab
            int col = u >> 4, kb8 = u & 15;               // kb = kb8*8
            uint4 vv = wg[col * 32 + s * 16 + kb8];
            *(uint4*)&sW[col * 136 + kb8 * 8] = vv;
        }
        __syncthreads();
        const uint4* a4 = (const uint4*)As[s];
#pragma unroll
        for (int kk = 0; kk < 4; ++kk) {
            uint4 av = make_uint4(0, 0, 0, 0);
            if (rok) av = a4[(size_t)arow * 16 + kk * 4 + lh];
            f16x8 af = *(f16x8*)&av;
#pragma unroll
            for (int n = 0; n < 8; ++n) {
                uint4 bv = *(uint4*)&sW[(n * 16 + lm) * 136 + kk * 32 + lh * 8];
                f16x8 bf = *(f16x8*)&bv;
                acc[n] = __builtin_amdgcn_mfma_f32_16x16x32_f16(af, bf, acc[n], 0, 0, 0);
            }
        }
    }
    __half* out = P.out[g];
    const float* bs = P.bs[g];
#pragma unroll
    for (int n = 0; n < 8; ++n) {
        int colg = n * 16 + lm;
        float bb = bs[colg];
#pragma unroll
        for (int qq = 0; qq < 4; ++qq) {
            int rowg = r0 + lh * 4 + qq;
            if (rowg < NNODE) {
                float v = fmaf(acc[n][qq], 0.5f, bb);
                out[(size_t)rowg * 128 + colg] = __float2half(v > 0.f ? v : 0.f);
            }
        }
    }
}

struct Lin16P { const __half* x[2]; const float* W[2]; const float* b[2]; float* out[2]; };
__global__ __launch_bounds__(256) void lin16_k(Lin16P P) {
    int g = blockIdx.y;
    int idx = blockIdx.x * 256 + threadIdx.x;
    int row = idx >> 4, c = idx & 15;
    if (row >= NNODE) return;
    const __half* xr = P.x[g] + (size_t)row * 128;
    const float* W = P.W[g];
    float acc = P.b[g][c];
    for (int k = 0; k < 128; ++k) acc += __half2float(xr[k]) * W[k * 16 + c];
    P.out[g][(size_t)row * 16 + c] = acc;
}

extern "C" void kernel_launch(void* const* d_in, const int* in_sizes, int n_in,
                              void* d_out, int out_size, void* d_ws, size_t ws_size,
                              hipStream_t stream) {
    (void)in_sizes; (void)n_in; (void)out_size; (void)ws_size;

    const float* x_gen  = (const float*)d_in[0];
    const float* x_rain = (const float*)d_in[1];
    const int* ei[4] = {(const int*)d_in[2], (const int*)d_in[3], (const int*)d_in[4], (const int*)d_in[5]};
    const float* w[4] = {(const float*)d_in[6], (const float*)d_in[7], (const float*)d_in[8], (const float*)d_in[9]};
    const float* W_conv = (const float*)d_in[10];  // [2][4][128][128]
    const float* b_conv = (const float*)d_in[11];  // [2][4][128]
    const float* W_lg = (const float*)d_in[12];
    const float* b_lg = (const float*)d_in[13];
    const float* W_lr = (const float*)d_in[14];
    const float* b_lr = (const float*)d_in[15];

    float* out_gen  = (float*)d_out;
    float* out_rain = out_gen + (size_t)NNODE * DOUT;

    char* p = (char*)d_ws;
    auto alloc = [&](size_t bytes) -> void* {
        void* r = (void*)p;
        p += (bytes + 255) & ~(size_t)255;
        return r;
    };

    // dinv layout: [gr_s | rg_s | gg | gr_d | rg_d | rr]
    float* deg = (float*)alloc(6 * (size_t)NNODE * sizeof(float));
    float* dinv_gr_s = deg + 0 * NNODE;
    float* dinv_rg_s = deg + 1 * NNODE;
    float* dinv_gg   = deg + 2 * NNODE;
    float* dinv_gr_d = deg + 3 * NNODE;
    float* dinv_rg_d = deg + 4 * NNODE;
    float* dinv_rr   = deg + 5 * NNODE;

    int*  cnt_all    = (int*)alloc(4 * (size_t)NNODE * sizeof(int));
    int*  rowptr_all = (int*)alloc(4 * (size_t)(NNODE + 1) * sizeof(int));

    // epack (9.92 MB) shares a 10.24 MB block with hist_all (dead after mkbase)
    size_t epack_bytes = 4 * (size_t)NES * sizeof(unsigned int);
    size_t hist_bytes  = 4 * (size_t)NB * NWORD * sizeof(unsigned int);
    unsigned int* epack_all = (unsigned int*)alloc(epack_bytes > hist_bytes ? epack_bytes : hist_bytes);
    unsigned int* hist_all  = epack_all;

    // agg region (20.48 MB) also hosts, sequentially: degAll partials (15.36 MB,
    // dead after degAll_sum) then base (20.48 MB, dead after scat4)
    __half* agg_all = (__half*)alloc(4 * (size_t)NNODE * DF * sizeof(__half));
    __half* aggh_gg = agg_all + 0 * (size_t)NNODE * DF;
    __half* aggh_gr = agg_all + 1 * (size_t)NNODE * DF;
    __half* aggh_rg = agg_all + 2 * (size_t)NNODE * DF;
    __half* aggh_rr = agg_all + 3 * (size_t)NNODE * DF;
    __half* xh_gen  = (__half*)alloc((size_t)NNODE * DF * sizeof(__half));
    __half* xh_rain = (__half*)alloc((size_t)NNODE * DF * sizeof(__half));

    __half* WtH  = (__half*)alloc(4 * (size_t)128 * 256 * sizeof(__half));   // 256 KB
    float*  bsum = (float*)alloc(4 * 128 * sizeof(float));

    float* part_all = (float*)agg_all;                   // 15.36 MB, dead after degAll_sum
    int*   base_all = (int*)agg_all;                     // 20.48 MB, dead after scat4
    unsigned short* loc_all = (unsigned short*)xh_rain;  // 4.8 MB in 5.12, dead after scat4

    int* rowptr[4]; unsigned short* loc[4]; unsigned int* ep[4];
    for (int r = 0; r < 4; ++r) {
        rowptr[r] = rowptr_all + (size_t)r * (NNODE + 1);
        loc[r]    = loc_all + (size_t)r * NE;
        ep[r]     = epack_all + (size_t)r * NES;
    }

    const int* rows_[4] = {ei[0], ei[1], ei[2], ei[3]};
    const int* cols_[4] = {ei[0] + NE, ei[1] + NE, ei[2] + NE, ei[3] + NE};

    // ---- W prep (independent) ----
    prepW_k<<<dim3(128, 4), 256, 0, stream>>>(W_conv, b_conv, WtH, bsum);

    // ---- histogram + local slots ----
    HistP HP;
    for (int r = 0; r < 4; ++r) { HP.col[r] = cols_[r]; HP.loc[r] = loc[r]; }
    HP.hist = hist_all;
    hist_k<<<dim3(NB, 4), 512, 0, stream>>>(HP);

    sumcnt_k<<<dim3(ceil_div(NWORD, 256), 4), 256, 0, stream>>>(hist_all, cnt_all);

    // ---- all 6 degree vectors from raw streams (partials live in agg region) ----
    DegAP DA;
    DA.idx[0] = cols_[0]; DA.wgt[0] = w[0];   // gg dst (= both sides)
    DA.idx[1] = rows_[1]; DA.wgt[1] = w[1];   // gr src
    DA.idx[2] = cols_[1]; DA.wgt[2] = w[1];   // gr dst
    DA.idx[3] = rows_[2]; DA.wgt[3] = w[2];   // rg src
    DA.idx[4] = cols_[2]; DA.wgt[4] = w[2];   // rg dst
    DA.idx[5] = cols_[3]; DA.wgt[5] = w[3];   // rr dst
    DA.part = part_all;
    degAll_part_k<<<dim3(SB * 2, 6), 256, 0, stream>>>(DA);

    DegAS DAS;
    DAS.part = part_all;
    DAS.dinv[0] = dinv_gg;   DAS.selfw[0] = 1.f;
    DAS.dinv[1] = dinv_gr_s; DAS.selfw[1] = 0.f;
    DAS.dinv[2] = dinv_gr_d; DAS.selfw[2] = 0.f;
    DAS.dinv[3] = dinv_rg_s; DAS.selfw[3] = 0.f;
    DAS.dinv[4] = dinv_rg_d; DAS.selfw[4] = 0.f;
    DAS.dinv[5] = dinv_rr;   DAS.selfw[5] = 1.f;
    degAll_sum_k<<<dim3(ceil_div(NNODE, 256), 6), 256, 0, stream>>>(DAS);

    // ---- scan + bases (base overwrites partials; they are dead) ----
    exscan4_k<<<4, 1024, 0, stream>>>(cnt_all, rowptr_all);
    mkbase_k<<<dim3(ceil_div(NWORD, 256), 4), 256, 0, stream>>>(hist_all, rowptr_all, base_all);

    // ---- scatter packed records (norm folded, XCD-pinned); self edges ----
    selfscat_k<<<ceil_div(NNODE, 256), 256, 0, stream>>>(rowptr[0], ep[0], dinv_gg,
                                                         rowptr[3], ep[3], dinv_rr);
    Scat4P SC;
    for (int r = 0; r < 4; ++r) {
        SC.row[r] = rows_[r]; SC.col[r] = cols_[r]; SC.w[r] = w[r];
        SC.loc[r] = loc[r]; SC.ep[r] = ep[r];
    }
    SC.base = base_all;
    SC.dS[0] = dinv_gg;   SC.dD[0] = dinv_gg;
    SC.dS[1] = dinv_gr_s; SC.dD[1] = dinv_gr_d;
    SC.dS[2] = dinv_rg_s; SC.dD[2] = dinv_rg_d;
    SC.dS[3] = dinv_rr;   SC.dD[3] = dinv_rr;
    scat4_k<<<1024, 256, 0, stream>>>(SC);

    // ---- fp16 features (loc region dead now) ----
    CvtP CV;
    CV.in[0] = x_gen;  CV.out[0] = xh_gen;
    CV.in[1] = x_rain; CV.out[1] = xh_rain;
    cvt_k<<<dim3(NNODE * DF / 4 / 256, 2), 256, 0, stream>>>(CV);

    // ---- layers ----
    for (int l = 0; l < 2; ++l) {
        SpmmP SP;
        for (int r = 0; r < 4; ++r) { SP.rowptr[r] = rowptr[r]; SP.ep[r] = ep[r]; }
        SP.x[0] = xh_gen; SP.x[1] = xh_gen; SP.x[2] = xh_rain; SP.x[3] = xh_rain;
        SP.out[0] = aggh_gg; SP.out[1] = aggh_gr; SP.out[2] = aggh_rg; SP.out[3] = aggh_rr;
        spmm4_k<<<20000, 256, 0, stream>>>(SP);

        Gemm2P GP;
        GP.A1[0] = aggh_gg; GP.A2[0] = aggh_rg;
        GP.A1[1] = aggh_gr; GP.A2[1] = aggh_rr;
        GP.Wt[0] = WtH + (size_t)(l * 2 + 0) * 128 * 256;
        GP.Wt[1] = WtH + (size_t)(l * 2 + 1) * 128 * 256;
        GP.bs[0] = bsum + (l * 2 + 0) * 128;
        GP.bs[1] = bsum + (l * 2 + 1) * 128;
        GP.out[0] = xh_gen;
        GP.out[1] = xh_rain;
        gemm2_k<<<dim3(ceil_div(NNODE, 64), 2), 256, 0, stream>>>(GP);
    }

    // ---- output heads ----
    Lin16P LP;
    LP.x[0] = xh_gen;  LP.W[0] = W_lg; LP.b[0] = b_lg; LP.out[0] = out_gen;
    LP.x[1] = xh_rain; LP.W[1] = W_lr; LP.b[1] = b_lr; LP.out[1] = out_rain;
    lin16_k<<<dim3(ceil_div(NNODE * DOUT, 256), 2), 256, 0, stream>>>(LP);
}

// Round 10
// 305.015 us; speedup vs baseline: 9.0470x; 1.0297x over previous
//
#include <hip/hip_runtime.h>
#include <hip/hip_fp16.h>

#define NNODE 20000
#define NE    600000
#define NES   (NE + NNODE)   // edges incl. self slots (relations gg, rr)
#define DF    128
#define DOUT  16
#define NB    64          // hist blocks per relation
#define CE    (NE/NB)     // 9375 edges per hist block (exact)
#define SUB   4           // scatter sub-blocks per chunk
#define CES   ((CE + SUB - 1) / SUB)   // 2344
#define NWORD 10000       // packed 16-bit pairs covering 20000 nodes
#define SB    32          // degree chunks per stream
#define CS    (NE/SB)     // 18750 edges per chunk (exact)

typedef _Float16 f16x8 __attribute__((ext_vector_type(8)));
typedef float f32x4 __attribute__((ext_vector_type(4)));

static inline int ceil_div(int a, int b) { return (a + b - 1) / b; }

// ---------------- fp32 -> fp16 conversion (4 floats/thread) ----------------
struct CvtP { const float* in[2]; __half* out[2]; };
__global__ __launch_bounds__(256) void cvt_k(CvtP P) {
    int g = blockIdx.y;
    int i = blockIdx.x * 256 + threadIdx.x;           // float4 index
    const float4* in = (const float4*)P.in[g];
    __half2* out = (__half2*)P.out[g];
    float4 v = in[i];
    out[2 * i + 0] = __floats2half2_rn(v.x, v.y);
    out[2 * i + 1] = __floats2half2_rn(v.z, v.w);
}

// ---------------- W prep: combined, transposed, fp16 + folded bias ----------------
__global__ __launch_bounds__(256) void prepW_k(const float* __restrict__ W_conv,
                                               const float* __restrict__ b_conv,
                                               __half* __restrict__ WtH,
                                               float* __restrict__ bsum) {
    int lg = blockIdx.y;
    int l = lg >> 1, g = lg & 1;
    int ra = (g == 0) ? 0 : 1;
    int rb = (g == 0) ? 2 : 3;
    int idx = blockIdx.x * 256 + threadIdx.x;    // 0..32767
    int col = idx >> 8, k = idx & 255;
    const float* Wa = W_conv + (size_t)(l * 4 + ra) * 128 * 128;
    const float* Wb = W_conv + (size_t)(l * 4 + rb) * 128 * 128;
    float v = (k < 128) ? Wa[k * 128 + col] : Wb[(k - 128) * 128 + col];
    WtH[((size_t)lg * 128 + col) * 256 + k] = __float2half(v);
    if (idx < 128)
        bsum[lg * 128 + idx] = 0.5f * (b_conv[(l * 4 + ra) * 128 + idx] +
                                       b_conv[(l * 4 + rb) * 128 + idx]);
}

// ---------------- phase H: per-chunk packed histogram + local slots ----------------
struct HistP { const int* col[4]; unsigned int* hist; unsigned short* loc[4]; };
__global__ __launch_bounds__(512) void hist_k(HistP P) {
    __shared__ unsigned int h[NWORD];   // 40 KB, 2x16-bit counts per word
    int b = blockIdx.x, r = blockIdx.y;
    for (int i = threadIdx.x; i < NWORD; i += 512) h[i] = 0u;
    __syncthreads();
    const int* col = P.col[r];
    unsigned short* loc = P.loc[r];
    int e0 = b * CE;
    for (int e = e0 + threadIdx.x; e < e0 + CE; e += 512) {
        int c = col[e];
        unsigned int sh = (unsigned)(c & 1) << 4;
        unsigned int old = atomicAdd(&h[c >> 1], 1u << sh);
        loc[e] = (unsigned short)((old >> sh) & 0xffffu);
    }
    __syncthreads();
    unsigned int* hg = P.hist + (size_t)(r * NB + b) * NWORD;
    for (int i = threadIdx.x; i < NWORD; i += 512) hg[i] = h[i];
}

// ---------------- per-node totals (+1 self slot for gg/rr) ----------------
__global__ __launch_bounds__(256) void sumcnt_k(const unsigned int* __restrict__ hist,
                                                int* __restrict__ cnt_all) {
    int r = blockIdx.y;
    int w = blockIdx.x * 256 + threadIdx.x;
    if (w >= NWORD) return;
    unsigned int lo = 0, hi = 0;
    const unsigned int* hp = hist + (size_t)r * NB * NWORD + w;
    for (int b = 0; b < NB; ++b) {
        unsigned int v = hp[(size_t)b * NWORD];
        lo += v & 0xffffu; hi += v >> 16;
    }
    int s = (r == 0 || r == 3) ? 1 : 0;   // self slot
    int* cnt = cnt_all + (size_t)r * NNODE;
    cnt[2 * w] = (int)lo + s;
    cnt[2 * w + 1] = (int)hi + s;
}

// exclusive scan over NNODE counts per relation; blockIdx.x = relation
__global__ void exscan4_k(const int* __restrict__ cnt_all, int* __restrict__ rowptr_all) {
    __shared__ int sums[1024];
    const int* cnt = cnt_all + (size_t)blockIdx.x * NNODE;
    int* rowptr = rowptr_all + (size_t)blockIdx.x * (NNODE + 1);
    int t = threadIdx.x;
    int chunk = (NNODE + 1023) >> 10;
    int b = t * chunk; if (b > NNODE) b = NNODE;
    int e = b + chunk; if (e > NNODE) e = NNODE;
    int s = 0;
    for (int i = b; i < e; ++i) s += cnt[i];
    sums[t] = s;
    __syncthreads();
    for (int off = 1; off < 1024; off <<= 1) {
        int v = (t >= off) ? sums[t - off] : 0;
        __syncthreads();
        sums[t] += v;
        __syncthreads();
    }
    int run = (t == 0) ? 0 : sums[t - 1];
    for (int i = b; i < e; ++i) { rowptr[i] = run; run += cnt[i]; }
    if (t == 1023) rowptr[NNODE] = run;
}

// ---------------- per-(block,node) global bases ----------------
__global__ __launch_bounds__(256) void mkbase_k(const unsigned int* __restrict__ hist,
                                               const int* __restrict__ rowptr_all,
                                               int* __restrict__ base) {
    int r = blockIdx.y;
    int w = blockIdx.x * 256 + threadIdx.x;
    if (w >= NWORD) return;
    const int* rowptr = rowptr_all + (size_t)r * (NNODE + 1);
    int s = (r == 0 || r == 3) ? 1 : 0;   // skip reserved self slot
    int lo = rowptr[2 * w] + s, hi = rowptr[2 * w + 1] + s;
    const unsigned int* hp = hist + (size_t)r * NB * NWORD + w;
    int* bp = base + (size_t)r * NB * NNODE;
    for (int b = 0; b < NB; ++b) {
        bp[(size_t)b * NNODE + 2 * w]     = lo;
        bp[(size_t)b * NNODE + 2 * w + 1] = hi;
        unsigned int v = hp[(size_t)b * NWORD];
        lo += (int)(v & 0xffffu);
        hi += (int)(v >> 16);
    }
}

// ---------------- all 6 weighted degrees via LDS partials over raw streams ----------------
struct DegAP { const int* idx[6]; const float* wgt[6]; float* part; };
__global__ __launch_bounds__(256) void degAll_part_k(DegAP P) {
    __shared__ float t[NWORD];   // 40 KB, covers 10000 nodes
    int s = blockIdx.y;
    int chunk = blockIdx.x >> 1, half = blockIdx.x & 1;
    int nbase = half * NWORD;
    for (int i = threadIdx.x; i < NWORD; i += 256) t[i] = 0.f;
    __syncthreads();
    const int* idx = P.idx[s];
    const float* w = P.wgt[s];
    int e0 = chunk * CS;
    for (int e = e0 + threadIdx.x; e < e0 + CS; e += 256) {
        int rr = idx[e] - nbase;
        if ((unsigned)rr < (unsigned)NWORD) atomicAdd(&t[rr], w[e]);
    }
    __syncthreads();
    float* pp = P.part + ((size_t)s * SB + chunk) * NNODE + nbase;
    for (int i = threadIdx.x; i < NWORD; i += 256) pp[i] = t[i];
}

struct DegAS { const float* part; float* dinv[6]; float selfw[6]; };
__global__ __launch_bounds__(256) void degAll_sum_k(DegAS P) {
    int s = blockIdx.y;
    int n = blockIdx.x * 256 + threadIdx.x;
    if (n >= NNODE) return;
    const float* pp = P.part + (size_t)s * SB * NNODE + n;
    float acc = P.selfw[s];
    for (int c = 0; c < SB; ++c) acc += pp[(size_t)c * NNODE];
    P.dinv[s][n] = acc > 0.f ? rsqrtf(acc) : 0.f;
}

// ---------------- self edges (packed) into reserved slot 0 (gg, rr) ----------------
__global__ __launch_bounds__(256) void selfscat_k(const int* __restrict__ rp0, unsigned int* ep0,
                                                  const float* __restrict__ dgg,
                                                  const int* __restrict__ rp3, unsigned int* ep3,
                                                  const float* __restrict__ drr) {
    int n = blockIdx.x * 256 + threadIdx.x;
    if (n >= NNODE) return;
    float d0 = dgg[n], d3 = drr[n];
    __half h0 = __float2half(d0 * d0);
    __half h3 = __float2half(d3 * d3);
    ep0[rp0[n]] = ((unsigned)n << 16) | *reinterpret_cast<unsigned short*>(&h0);
    ep3[rp3[n]] = ((unsigned)n << 16) | *reinterpret_cast<unsigned short*>(&h3);
}

// ---------------- scatter: atomic-free, packed 4B, single-XCD line ownership ----------------
// grid = 2048 blocks 1D. xcd = bid&7; (relation, node-half) = (xcd>>1, xcd&1).
// Each (relation, half) pair is written by exactly ONE XCD, so every ep cache
// line's fragments merge in a single L2 and write back ~once. Each chunk-sub
// is scanned by both halves (filter by dst half); the duplicate stream reads
// are absorbed by L3.
struct Scat4P {
    const int* row[4]; const int* col[4]; const float* w[4];
    const unsigned short* loc[4]; const int* base;
    const float* dS[4]; const float* dD[4];
    unsigned int* ep[4];
};
__global__ __launch_bounds__(256) void scat4_k(Scat4P P) {
    int bid = blockIdx.x;
    int xcd = bid & 7;
    int r = xcd >> 1;
    int half = xcd & 1;
    int nlo = half * NWORD;              // node-half base (10000)
    int cs = bid >> 3;                   // chunk-sub 0..255
    int b = cs >> 2, s = cs & 3;         // SUB = 4
    const int* bp = P.base + ((size_t)r * NB + b) * NNODE;
    const int* row = P.row[r];
    const int* col = P.col[r];
    const float* w = P.w[r];
    const float* dS = P.dS[r];
    const float* dD = P.dD[r];
    const unsigned short* loc = P.loc[r];
    unsigned int* ep = P.ep[r];
    int e0 = b * CE + s * CES;
    int e1 = e0 + CES;
    int cap = b * CE + CE;
    if (e1 > cap) e1 = cap;
    for (int e = e0 + threadIdx.x; e < e1; e += 256) {
        int c = col[e];
        if ((unsigned)(c - nlo) >= (unsigned)NWORD) continue;   // other half
        int src = row[e];
        float nm = dS[src] * w[e] * dD[c];
        int pos = bp[c] + (int)loc[e];
        __half hh = __float2half(nm);
        ep[pos] = ((unsigned)src << 16) | *reinterpret_cast<unsigned short*>(&hh);
    }
}

// ---------------- pull-SpMM: quarter-wave row gather, 4-deep unroll ----------------
struct SpmmP {
    const __half* x[4]; const int* rowptr[4]; const unsigned int* ep[4]; __half* out[4];
};
__global__ __launch_bounds__(256) void spmm4_k(SpmmP P) {
    // grid = 20000 blocks, 4 waves/block, 1 node/wave; XCD-partitioned by src table.
    int b = blockIdx.x;
    int xcd = b & 7;
    int j = b >> 3;                               // 0..2499
    int r = ((xcd >> 2) << 1) + (j >= 1250 ? 1 : 0);
    int nodeblk = (xcd & 3) * 1250 + (j >= 1250 ? j - 1250 : j);
    int wid = nodeblk * 4 + (threadIdx.x >> 6);
    int lane = threadIdx.x & 63;
    int q = lane >> 4, c = lane & 15;             // quarter id, lane-in-quarter
    const uint4* x4 = (const uint4*)P.x[r];       // row = 16 x uint4 (8 fp16 each)
    const int* rp = P.rowptr[r];
    int bb = rp[wid], ee = rp[wid + 1];
    const unsigned int* ep = P.ep[r];
    float a[8];
#pragma unroll
    for (int t = 0; t < 8; ++t) a[t] = 0.f;

    auto decn = [](unsigned int v) -> float {
        unsigned short us = (unsigned short)(v & 0xffffu);
        __half h = *reinterpret_cast<__half*>(&us);
        return __half2float(h);
    };
    auto accum = [&](uint4 p, float n) {
        const __half2* ph = (const __half2*)&p;
#pragma unroll
        for (int t = 0; t < 4; ++t) {
            float2 f = __half22float2(ph[t]);
            a[2 * t]     = fmaf(f.x, n, a[2 * t]);
            a[2 * t + 1] = fmaf(f.y, n, a[2 * t + 1]);
        }
    };

    int i = bb + q;
    for (; i + 12 < ee; i += 16) {                // 4 edges per quarter in flight
        unsigned int v0 = ep[i], v1 = ep[i + 4], v2 = ep[i + 8], v3 = ep[i + 12];
        uint4 p0 = x4[(size_t)(v0 >> 16) * 16 + c];
        uint4 p1 = x4[(size_t)(v1 >> 16) * 16 + c];
        uint4 p2 = x4[(size_t)(v2 >> 16) * 16 + c];
        uint4 p3 = x4[(size_t)(v3 >> 16) * 16 + c];
        accum(p0, decn(v0));
        accum(p1, decn(v1));
        accum(p2, decn(v2));
        accum(p3, decn(v3));
    }
    for (; i + 4 < ee; i += 8) {                  // 2 edges
        unsigned int v0 = ep[i], v1 = ep[i + 4];
        uint4 p0 = x4[(size_t)(v0 >> 16) * 16 + c];
        uint4 p1 = x4[(size_t)(v1 >> 16) * 16 + c];
        accum(p0, decn(v0));
        accum(p1, decn(v1));
    }
    if (i < ee) {
        unsigned int v0 = ep[i];
        uint4 p0 = x4[(size_t)(v0 >> 16) * 16 + c];
        accum(p0, decn(v0));
    }
#pragma unroll
    for (int t = 0; t < 8; ++t) {
        a[t] += __shfl_xor(a[t], 16, 64);
        a[t] += __shfl_xor(a[t], 32, 64);
    }
    if (q == 0) {
        __half2 h[4];
#pragma unroll
        for (int t = 0; t < 4; ++t) h[t] = __floats2half2_rn(a[2 * t], a[2 * t + 1]);
        ((uint4*)P.out[r])[(size_t)wid * 16 + c] = *(uint4*)h;
    }
}

// ---------------- MFMA gemm2: relu(0.5*(A1@Wa + A2@Wb) + bsum) -> fp16 ----------------
struct Gemm2P {
    const __half* A1[2]; const __half* A2[2];
    const __half* Wt[2];   // [128 col][256 k] fp16 (k<128: Wa, else Wb)
    const float* bs[2];    // 0.5*(ba+bb)
    __half* out[2];
};
__global__ __launch_bounds__(256) void gemm2_k(Gemm2P P) {
    __shared__ __half sW[128 * 136];   // one 128-K slab, padded stride
    int g = blockIdx.y;
    int w = threadIdx.x >> 6, l = threadIdx.x & 63;
    int r0 = blockIdx.x * 64 + w * 16;
    int lm = l & 15, lh = l >> 4;
    f32x4 acc[8];
    f32x4 zero = {0.f, 0.f, 0.f, 0.f};
#pragma unroll
    for (int n = 0; n < 8; ++n) acc[n] = zero;
    const __half* As[2] = { P.A1[g], P.A2[g] };
    const uint4* wg = (const uint4*)P.Wt[g];
    int arow = r0 + lm;
    bool rok = arow < NNODE;
    for (int s = 0; s < 2; ++s) {
        __syncthreads();
        for (int u = threadIdx.x; u < 2048; u += 256) {   // stage 32 KB slab
            int col = u >> 4, kb8 = u & 15;               // kb = kb8*8
            uint4 vv = wg[col * 32 + s * 16 + kb8];
            *(uint4*)&sW[col * 136 + kb8 * 8] = vv;
        }
        __syncthreads();
        const uint4* a4 = (const uint4*)As[s];
#pragma unroll
        for (int kk = 0; kk < 4; ++kk) {
            uint4 av = make_uint4(0, 0, 0, 0);
            if (rok) av = a4[(size_t)arow * 16 + kk * 4 + lh];
            f16x8 af = *(f16x8*)&av;
#pragma unroll
            for (int n = 0; n < 8; ++n) {
                uint4 bv = *(uint4*)&sW[(n * 16 + lm) * 136 + kk * 32 + lh * 8];
                f16x8 bf = *(f16x8*)&bv;
                acc[n] = __builtin_amdgcn_mfma_f32_16x16x32_f16(af, bf, acc[n], 0, 0, 0);
            }
        }
    }
    __half* out = P.out[g];
    const float* bs = P.bs[g];
#pragma unroll
    for (int n = 0; n < 8; ++n) {
        int colg = n * 16 + lm;
        float bb = bs[colg];
#pragma unroll
        for (int qq = 0; qq < 4; ++qq) {
            int rowg = r0 + lh * 4 + qq;
            if (rowg < NNODE) {
                float v = fmaf(acc[n][qq], 0.5f, bb);
                out[(size_t)rowg * 128 + colg] = __float2half(v > 0.f ? v : 0.f);
            }
        }
    }
}

struct Lin16P { const __half* x[2]; const float* W[2]; const float* b[2]; float* out[2]; };
__global__ __launch_bounds__(256) void lin16_k(Lin16P P) {
    int g = blockIdx.y;
    int idx = blockIdx.x * 256 + threadIdx.x;
    int row = idx >> 4, c = idx & 15;
    if (row >= NNODE) return;
    const __half* xr = P.x[g] + (size_t)row * 128;
    const float* W = P.W[g];
    float acc = P.b[g][c];
    for (int k = 0; k < 128; ++k) acc += __half2float(xr[k]) * W[k * 16 + c];
    P.out[g][(size_t)row * 16 + c] = acc;
}

extern "C" void kernel_launch(void* const* d_in, const int* in_sizes, int n_in,
                              void* d_out, int out_size, void* d_ws, size_t ws_size,
                              hipStream_t stream) {
    (void)in_sizes; (void)n_in; (void)out_size; (void)ws_size;

    const float* x_gen  = (const float*)d_in[0];
    const float* x_rain = (const float*)d_in[1];
    const int* ei[4] = {(const int*)d_in[2], (const int*)d_in[3], (const int*)d_in[4], (const int*)d_in[5]};
    const float* w[4] = {(const float*)d_in[6], (const float*)d_in[7], (const float*)d_in[8], (const float*)d_in[9]};
    const float* W_conv = (const float*)d_in[10];  // [2][4][128][128]
    const float* b_conv = (const float*)d_in[11];  // [2][4][128]
    const float* W_lg = (const float*)d_in[12];
    const float* b_lg = (const float*)d_in[13];
    const float* W_lr = (const float*)d_in[14];
    const float* b_lr = (const float*)d_in[15];

    float* out_gen  = (float*)d_out;
    float* out_rain = out_gen + (size_t)NNODE * DOUT;

    char* p = (char*)d_ws;
    auto alloc = [&](size_t bytes) -> void* {
        void* r = (void*)p;
        p += (bytes + 255) & ~(size_t)255;
        return r;
    };

    // dinv layout: [gr_s | rg_s | gg | gr_d | rg_d | rr]
    float* deg = (float*)alloc(6 * (size_t)NNODE * sizeof(float));
    float* dinv_gr_s = deg + 0 * NNODE;
    float* dinv_rg_s = deg + 1 * NNODE;
    float* dinv_gg   = deg + 2 * NNODE;
    float* dinv_gr_d = deg + 3 * NNODE;
    float* dinv_rg_d = deg + 4 * NNODE;
    float* dinv_rr   = deg + 5 * NNODE;

    int*  cnt_all    = (int*)alloc(4 * (size_t)NNODE * sizeof(int));
    int*  rowptr_all = (int*)alloc(4 * (size_t)(NNODE + 1) * sizeof(int));

    // epack (9.92 MB) shares a 10.24 MB block with hist_all (dead after mkbase)
    size_t epack_bytes = 4 * (size_t)NES * sizeof(unsigned int);
    size_t hist_bytes  = 4 * (size_t)NB * NWORD * sizeof(unsigned int);
    unsigned int* epack_all = (unsigned int*)alloc(epack_bytes > hist_bytes ? epack_bytes : hist_bytes);
    unsigned int* hist_all  = epack_all;

    // agg region (20.48 MB) also hosts, sequentially: degAll partials (15.36 MB,
    // dead after degAll_sum) then base (20.48 MB, dead after scat4)
    __half* agg_all = (__half*)alloc(4 * (size_t)NNODE * DF * sizeof(__half));
    __half* aggh_gg = agg_all + 0 * (size_t)NNODE * DF;
    __half* aggh_gr = agg_all + 1 * (size_t)NNODE * DF;
    __half* aggh_rg = agg_all + 2 * (size_t)NNODE * DF;
    __half* aggh_rr = agg_all + 3 * (size_t)NNODE * DF;
    __half* xh_gen  = (__half*)alloc((size_t)NNODE * DF * sizeof(__half));
    __half* xh_rain = (__half*)alloc((size_t)NNODE * DF * sizeof(__half));

    __half* WtH  = (__half*)alloc(4 * (size_t)128 * 256 * sizeof(__half));   // 256 KB
    float*  bsum = (float*)alloc(4 * 128 * sizeof(float));

    float* part_all = (float*)agg_all;                   // 15.36 MB, dead after degAll_sum
    int*   base_all = (int*)agg_all;                     // 20.48 MB, dead after scat4
    unsigned short* loc_all = (unsigned short*)xh_rain;  // 4.8 MB in 5.12, dead after scat4

    int* rowptr[4]; unsigned short* loc[4]; unsigned int* ep[4];
    for (int r = 0; r < 4; ++r) {
        rowptr[r] = rowptr_all + (size_t)r * (NNODE + 1);
        loc[r]    = loc_all + (size_t)r * NE;
        ep[r]     = epack_all + (size_t)r * NES;
    }

    const int* rows_[4] = {ei[0], ei[1], ei[2], ei[3]};
    const int* cols_[4] = {ei[0] + NE, ei[1] + NE, ei[2] + NE, ei[3] + NE};

    // ---- W prep (independent) ----
    prepW_k<<<dim3(128, 4), 256, 0, stream>>>(W_conv, b_conv, WtH, bsum);

    // ---- histogram + local slots ----
    HistP HP;
    for (int r = 0; r < 4; ++r) { HP.col[r] = cols_[r]; HP.loc[r] = loc[r]; }
    HP.hist = hist_all;
    hist_k<<<dim3(NB, 4), 512, 0, stream>>>(HP);

    sumcnt_k<<<dim3(ceil_div(NWORD, 256), 4), 256, 0, stream>>>(hist_all, cnt_all);

    // ---- all 6 degree vectors from raw streams (partials live in agg region) ----
    DegAP DA;
    DA.idx[0] = cols_[0]; DA.wgt[0] = w[0];   // gg dst (= both sides)
    DA.idx[1] = rows_[1]; DA.wgt[1] = w[1];   // gr src
    DA.idx[2] = cols_[1]; DA.wgt[2] = w[1];   // gr dst
    DA.idx[3] = rows_[2]; DA.wgt[3] = w[2];   // rg src
    DA.idx[4] = cols_[2]; DA.wgt[4] = w[2];   // rg dst
    DA.idx[5] = cols_[3]; DA.wgt[5] = w[3];   // rr dst
    DA.part = part_all;
    degAll_part_k<<<dim3(SB * 2, 6), 256, 0, stream>>>(DA);

    DegAS DAS;
    DAS.part = part_all;
    DAS.dinv[0] = dinv_gg;   DAS.selfw[0] = 1.f;
    DAS.dinv[1] = dinv_gr_s; DAS.selfw[1] = 0.f;
    DAS.dinv[2] = dinv_gr_d; DAS.selfw[2] = 0.f;
    DAS.dinv[3] = dinv_rg_s; DAS.selfw[3] = 0.f;
    DAS.dinv[4] = dinv_rg_d; DAS.selfw[4] = 0.f;
    DAS.dinv[5] = dinv_rr;   DAS.selfw[5] = 1.f;
    degAll_sum_k<<<dim3(ceil_div(NNODE, 256), 6), 256, 0, stream>>>(DAS);

    // ---- scan + bases (base overwrites partials; they are dead) ----
    exscan4_k<<<4, 1024, 0, stream>>>(cnt_all, rowptr_all);
    mkbase_k<<<dim3(ceil_div(NWORD, 256), 4), 256, 0, stream>>>(hist_all, rowptr_all, base_all);

    // ---- scatter packed records (norm folded, single-XCD ownership); self edges ----
    selfscat_k<<<ceil_div(NNODE, 256), 256, 0, stream>>>(rowptr[0], ep[0], dinv_gg,
                                                         rowptr[3], ep[3], dinv_rr);
    Scat4P SC;
    for (int r = 0; r < 4; ++r) {
        SC.row[r] = rows_[r]; SC.col[r] = cols_[r]; SC.w[r] = w[r];
        SC.loc[r] = loc[r]; SC.ep[r] = ep[r];
    }
    SC.base = base_all;
    SC.dS[0] = dinv_gg;   SC.dD[0] = dinv_gg;
    SC.dS[1] = dinv_gr_s; SC.dD[1] = dinv_gr_d;
    SC.dS[2] = dinv_rg_s; SC.dD[2] = dinv_rg_d;
    SC.dS[3] = dinv_rr;   SC.dD[3] = dinv_rr;
    scat4_k<<<2048, 256, 0, stream>>>(SC);

    // ---- fp16 features (loc region dead now) ----
    CvtP CV;
    CV.in[0] = x_gen;  CV.out[0] = xh_gen;
    CV.in[1] = x_rain; CV.out[1] = xh_rain;
    cvt_k<<<dim3(NNODE * DF / 4 / 256, 2), 256, 0, stream>>>(CV);

    // ---- layers ----
    for (int l = 0; l < 2; ++l) {
        SpmmP SP;
        for (int r = 0; r < 4; ++r) { SP.rowptr[r] = rowptr[r]; SP.ep[r] = ep[r]; }
        SP.x[0] = xh_gen; SP.x[1] = xh_gen; SP.x[2] = xh_rain; SP.x[3] = xh_rain;
        SP.out[0] = aggh_gg; SP.out[1] = aggh_gr; SP.out[2] = aggh_rg; SP.out[3] = aggh_rr;
        spmm4_k<<<20000, 256, 0, stream>>>(SP);

        Gemm2P GP;
        GP.A1[0] = aggh_gg; GP.A2[0] = aggh_rg;
        GP.A1[1] = aggh_gr; GP.A2[1] = aggh_rr;
        GP.Wt[0] = WtH + (size_t)(l * 2 + 0) * 128 * 256;
        GP.Wt[1] = WtH + (size_t)(l * 2 + 1) * 128 * 256;
        GP.bs[0] = bsum + (l * 2 + 0) * 128;
        GP.bs[1] = bsum + (l * 2 + 1) * 128;
        GP.out[0] = xh_gen;
        GP.out[1] = xh_rain;
        gemm2_k<<<dim3(ceil_div(NNODE, 64), 2), 256, 0, stream>>>(GP);
    }

    // ---- output heads ----
    Lin16P LP;
    LP.x[0] = xh_gen;  LP.W[0] = W_lg; LP.b[0] = b_lg; LP.out[0] = out_gen;
    LP.x[1] = xh_rain; LP.W[1] = W_lr; LP.b[1] = b_lr; LP.out[1] = out_rain;
    lin16_k<<<dim3(ceil_div(NNODE * DOUT, 256), 2), 256, 0, stream>>>(LP);
}

// Round 11
// 283.238 us; speedup vs baseline: 9.7426x; 1.0769x over previous
//
#include <hip/hip_runtime.h>
#include <hip/hip_fp16.h>

#define NNODE 20000
#define NE    600000
#define NES   (NE + NNODE)   // ep stride incl. self slots (used by gg, rr)
#define DF    128
#define DOUT  16
#define NBKT  80          // dst buckets
#define RNG   250         // nodes per bucket (80*250 = 20000 exact)
#define NCH   128         // partition chunks
#define CHE   4688        // edges per chunk (128*4688 >= NE)
#define P2CAP 12288       // part2 staging capacity (records; mean 7500+250)
#define SB    32          // degree chunks per stream
#define CS    (NE/SB)     // 18750

typedef _Float16 f16x8 __attribute__((ext_vector_type(8)));
typedef float f32x4 __attribute__((ext_vector_type(4)));

static inline int ceil_div(int a, int b) { return (a + b - 1) / b; }

// ---------------- fp32 -> fp16 conversion ----------------
struct CvtP { const float* in[2]; __half* out[2]; };
__global__ __launch_bounds__(256) void cvt_k(CvtP P) {
    int g = blockIdx.y;
    int i = blockIdx.x * 256 + threadIdx.x;
    const float4* in = (const float4*)P.in[g];
    __half2* out = (__half2*)P.out[g];
    float4 v = in[i];
    out[2 * i + 0] = __floats2half2_rn(v.x, v.y);
    out[2 * i + 1] = __floats2half2_rn(v.z, v.w);
}

// ---------------- W prep: combined, transposed, fp16 + folded bias ----------------
__global__ __launch_bounds__(256) void prepW_k(const float* __restrict__ W_conv,
                                               const float* __restrict__ b_conv,
                                               __half* __restrict__ WtH,
                                               float* __restrict__ bsum) {
    int lg = blockIdx.y;
    int l = lg >> 1, g = lg & 1;
    int ra = (g == 0) ? 0 : 1;
    int rb = (g == 0) ? 2 : 3;
    int idx = blockIdx.x * 256 + threadIdx.x;
    int col = idx >> 8, k = idx & 255;
    const float* Wa = W_conv + (size_t)(l * 4 + ra) * 128 * 128;
    const float* Wb = W_conv + (size_t)(l * 4 + rb) * 128 * 128;
    float v = (k < 128) ? Wa[k * 128 + col] : Wb[(k - 128) * 128 + col];
    WtH[((size_t)lg * 128 + col) * 256 + k] = __float2half(v);
    if (idx < 128)
        bsum[lg * 128 + idx] = 0.5f * (b_conv[(l * 4 + ra) * 128 + idx] +
                                       b_conv[(l * 4 + rb) * 128 + idx]);
}

// ---------------- bucket counts per (relation, chunk) ----------------
struct C1P { const int* col[4]; int* cnt1; };
__global__ __launch_bounds__(256) void count1_k(C1P P) {
    __shared__ int h[NBKT];
    int ch = blockIdx.x, r = blockIdx.y;
    for (int i = threadIdx.x; i < NBKT; i += 256) h[i] = 0;
    __syncthreads();
    const int* col = P.col[r];
    int e0 = ch * CHE, e1 = min(NE, e0 + CHE);
    for (int e = e0 + threadIdx.x; e < e1; e += 256) atomicAdd(&h[col[e] / RNG], 1);
    __syncthreads();
    int* out = P.cnt1 + (size_t)r * NBKT * NCH;
    for (int b = threadIdx.x; b < NBKT; b += 256) out[b * NCH + ch] = h[b];
}

// ---------------- scans: chunk offsets within bucket + bucket bases ----------------
__global__ __launch_bounds__(128) void scan1_k(int* __restrict__ cnt1, int* __restrict__ bktbase) {
    __shared__ int tot[NBKT];
    int r = blockIdx.x;
    int* base = cnt1 + (size_t)r * NBKT * NCH;
    for (int b = threadIdx.x; b < NBKT; b += 128) {
        int run = 0;
        int* pb = base + b * NCH;
        for (int ch = 0; ch < NCH; ++ch) { int v = pb[ch]; pb[ch] = run; run += v; }
        tot[b] = run;
    }
    __syncthreads();
    if (threadIdx.x == 0) {
        int run = 0;
        int* bb = bktbase + r * (NBKT + 1);
        for (int b = 0; b < NBKT; ++b) { bb[b] = run; run += tot[b]; }
        bb[NBKT] = run;
    }
}

// ---------------- part1: sort chunk by bucket in LDS, flush runs coalesced ----------------
struct P1P {
    const int* row[4]; const int* col[4]; const float* w[4];
    const int* choff;   // cnt1 after scan: [r][bkt][ch] exclusive offsets
    const int* bktbase; // [r][NBKT+1]
    uint2* bk[4];       // bucket storage, NE records per relation
};
__global__ __launch_bounds__(256) void part1_k(P1P P) {
    __shared__ uint2 st[CHE];
    __shared__ int h[NBKT];
    __shared__ int hoff[NBKT];
    __shared__ int c2[NBKT];
    int ch = blockIdx.x, r = blockIdx.y;
    for (int i = threadIdx.x; i < NBKT; i += 256) { h[i] = 0; c2[i] = 0; }
    __syncthreads();
    const int* col = P.col[r];
    const int* row = P.row[r];
    const float* w = P.w[r];
    int e0 = ch * CHE, e1 = min(NE, e0 + CHE);
    for (int e = e0 + threadIdx.x; e < e1; e += 256) atomicAdd(&h[col[e] / RNG], 1);
    __syncthreads();
    if (threadIdx.x == 0) {
        int run = 0;
        for (int b = 0; b < NBKT; ++b) { hoff[b] = run; run += h[b]; }
    }
    __syncthreads();
    for (int e = e0 + threadIdx.x; e < e1; e += 256) {
        int c = col[e];
        int b = c / RNG;
        int slot = hoff[b] + atomicAdd(&c2[b], 1);
        uint2 v;
        v.x = ((unsigned)c << 15) | (unsigned)row[e];   // c<2^15, src<2^15
        v.y = (unsigned)__float_as_int(w[e]);
        st[slot] = v;
    }
    __syncthreads();
    const int* choff = P.choff + (size_t)r * NBKT * NCH;
    const int* bb = P.bktbase + r * (NBKT + 1);
    uint2* bk = P.bk[r];
    for (int b = 0; b < NBKT; ++b) {
        int base = bb[b] + choff[b * NCH + ch];
        int m = h[b];
        int lo = hoff[b];
        for (int i = threadIdx.x; i < m; i += 256) bk[base + i] = st[lo + i];
    }
}

// ---------------- 4 global degree streams (gg col, rr col, gr row, rg row) ----------------
struct DegAP { const int* idx[4]; const float* wgt[4]; float* part; };
__global__ __launch_bounds__(256) void degAll_part_k(DegAP P) {
    __shared__ float t[NNODE / 2];   // 40 KB, half the nodes
    int s = blockIdx.y;
    int chunk = blockIdx.x >> 1, half = blockIdx.x & 1;
    int nbase = half * (NNODE / 2);
    for (int i = threadIdx.x; i < NNODE / 2; i += 256) t[i] = 0.f;
    __syncthreads();
    const int* idx = P.idx[s];
    const float* w = P.wgt[s];
    int e0 = chunk * CS;
    for (int e = e0 + threadIdx.x; e < e0 + CS; e += 256) {
        int rr = idx[e] - nbase;
        if ((unsigned)rr < (unsigned)(NNODE / 2)) atomicAdd(&t[rr], w[e]);
    }
    __syncthreads();
    float* pp = P.part + ((size_t)s * SB + chunk) * NNODE + nbase;
    for (int i = threadIdx.x; i < NNODE / 2; i += 256) pp[i] = t[i];
}

struct DegAS { const float* part; float* dinv[4]; float selfw[4]; };
__global__ __launch_bounds__(256) void degAll_sum_k(DegAS P) {
    int s = blockIdx.y;
    int n = blockIdx.x * 256 + threadIdx.x;
    if (n >= NNODE) return;
    const float* pp = P.part + (size_t)s * SB * NNODE + n;
    float acc = P.selfw[s];
    for (int c = 0; c < SB; ++c) acc += pp[(size_t)c * NNODE];
    P.dinv[s][n] = acc > 0.f ? rsqrtf(acc) : 0.f;
}

// ---------------- part2: bucket -> CSR segment (local sort, norms, self, rowptr) ----------------
struct P2P {
    const uint2* bk[4];
    const int* bktbase;     // [r][NBKT+1]
    const float* dS[4];     // per-src dinv vector
    const float* dDg[4];    // global dst dinv (gg/rr) or nullptr
    int self[4];
    int* rowptr[4];
    unsigned int* ep[4];
};
__global__ __launch_bounds__(256) void part2_k(P2P P) {
    __shared__ unsigned int st[P2CAP];   // 48 KB staging
    __shared__ float wsum[RNG];
    __shared__ int cnt[RNG];
    __shared__ int off[RNG + 1];
    __shared__ int cur[RNG];
    int bkt = blockIdx.x, r = blockIdx.y;
    int selfF = P.self[r];
    const int* bb = P.bktbase + r * (NBKT + 1);
    int b0 = bb[bkt], n = bb[bkt + 1] - b0;
    for (int i = threadIdx.x; i < RNG; i += 256) { wsum[i] = 0.f; cnt[i] = 0; cur[i] = 0; }
    __syncthreads();
    const uint2* bk = P.bk[r];
    int nlo = bkt * RNG;
    for (int i = threadIdx.x; i < n; i += 256) {
        uint2 rec = bk[b0 + i];
        int cl = (int)(rec.x >> 15) - nlo;
        atomicAdd(&cnt[cl], 1);
        if (!selfF) atomicAdd(&wsum[cl], __int_as_float((int)rec.y));
    }
    __syncthreads();
    if (threadIdx.x == 0) {
        int run = 0;
        for (int c = 0; c < RNG; ++c) { off[c] = run; run += cnt[c] + selfF; }
        off[RNG] = run;
    }
    __syncthreads();
    int ntot = off[RNG];
    int epseg = b0 + (selfF ? nlo : 0);
    int* rp = P.rowptr[r];
    for (int c = threadIdx.x; c < RNG; c += 256) rp[nlo + c] = epseg + off[c];
    if (bkt == NBKT - 1 && threadIdx.x == 0) rp[NNODE] = epseg + ntot;
    const float* dDg = P.dDg[r];
    if (!selfF) {
        for (int c = threadIdx.x; c < RNG; c += 256) {
            float s = wsum[c];
            wsum[c] = s > 0.f ? rsqrtf(s) : 0.f;
        }
    }
    __syncthreads();
    if (selfF) {
        for (int c = threadIdx.x; c < RNG; c += 256) {
            float d = dDg[nlo + c];
            __half hh = __float2half(d * d);
            st[off[c]] = ((unsigned)(nlo + c) << 16) | *reinterpret_cast<unsigned short*>(&hh);
        }
    }
    const float* dS = P.dS[r];
    for (int i = threadIdx.x; i < n; i += 256) {
        uint2 rec = bk[b0 + i];
        int cg = (int)(rec.x >> 15);
        int cl = cg - nlo;
        int src = (int)(rec.x & 0x7fffu);
        float w = __int_as_float((int)rec.y);
        float dD = selfF ? dDg[cg] : wsum[cl];
        float nm = dS[src] * w * dD;
        int slot = off[cl] + selfF + atomicAdd(&cur[cl], 1);
        __half hh = __float2half(nm);
        st[slot] = ((unsigned)src << 16) | *reinterpret_cast<unsigned short*>(&hh);
    }
    __syncthreads();
    unsigned int* ep = P.ep[r];
    for (int i = threadIdx.x; i < ntot; i += 256) ep[epseg + i] = st[i];
}

// ---------------- pull-SpMM: quarter-wave row gather, 4-deep unroll ----------------
struct SpmmP {
    const __half* x[4]; const int* rowptr[4]; const unsigned int* ep[4]; __half* out[4];
};
__global__ __launch_bounds__(256) void spmm4_k(SpmmP P) {
    int b = blockIdx.x;
    int xcd = b & 7;
    int j = b >> 3;
    int r = ((xcd >> 2) << 1) + (j >= 1250 ? 1 : 0);
    int nodeblk = (xcd & 3) * 1250 + (j >= 1250 ? j - 1250 : j);
    int wid = nodeblk * 4 + (threadIdx.x >> 6);
    int lane = threadIdx.x & 63;
    int q = lane >> 4, c = lane & 15;
    const uint4* x4 = (const uint4*)P.x[r];
    const int* rp = P.rowptr[r];
    int bb = rp[wid], ee = rp[wid + 1];
    const unsigned int* ep = P.ep[r];
    float a[8];
#pragma unroll
    for (int t = 0; t < 8; ++t) a[t] = 0.f;

    auto decn = [](unsigned int v) -> float {
        unsigned short us = (unsigned short)(v & 0xffffu);
        __half h = *reinterpret_cast<__half*>(&us);
        return __half2float(h);
    };
    auto accum = [&](uint4 p, float n) {
        const __half2* ph = (const __half2*)&p;
#pragma unroll
        for (int t = 0; t < 4; ++t) {
            float2 f = __half22float2(ph[t]);
            a[2 * t]     = fmaf(f.x, n, a[2 * t]);
            a[2 * t + 1] = fmaf(f.y, n, a[2 * t + 1]);
        }
    };

    int i = bb + q;
    for (; i + 12 < ee; i += 16) {
        unsigned int v0 = ep[i], v1 = ep[i + 4], v2 = ep[i + 8], v3 = ep[i + 12];
        uint4 p0 = x4[(size_t)(v0 >> 16) * 16 + c];
        uint4 p1 = x4[(size_t)(v1 >> 16) * 16 + c];
        uint4 p2 = x4[(size_t)(v2 >> 16) * 16 + c];
        uint4 p3 = x4[(size_t)(v3 >> 16) * 16 + c];
        accum(p0, decn(v0));
        accum(p1, decn(v1));
        accum(p2, decn(v2));
        accum(p3, decn(v3));
    }
    for (; i + 4 < ee; i += 8) {
        unsigned int v0 = ep[i], v1 = ep[i + 4];
        uint4 p0 = x4[(size_t)(v0 >> 16) * 16 + c];
        uint4 p1 = x4[(size_t)(v1 >> 16) * 16 + c];
        accum(p0, decn(v0));
        accum(p1, decn(v1));
    }
    if (i < ee) {
        unsigned int v0 = ep[i];
        uint4 p0 = x4[(size_t)(v0 >> 16) * 16 + c];
        accum(p0, decn(v0));
    }
#pragma unroll
    for (int t = 0; t < 8; ++t) {
        a[t] += __shfl_xor(a[t], 16, 64);
        a[t] += __shfl_xor(a[t], 32, 64);
    }
    if (q == 0) {
        __half2 h[4];
#pragma unroll
        for (int t = 0; t < 4; ++t) h[t] = __floats2half2_rn(a[2 * t], a[2 * t + 1]);
        ((uint4*)P.out[r])[(size_t)wid * 16 + c] = *(uint4*)h;
    }
}

// ---------------- MFMA gemm2 ----------------
struct Gemm2P {
    const __half* A1[2]; const __half* A2[2];
    const __half* Wt[2];
    const float* bs[2];
    __half* out[2];
};
__global__ __launch_bounds__(256) void gemm2_k(Gemm2P P) {
    __shared__ __half sW[128 * 136];
    int g = blockIdx.y;
    int w = threadIdx.x >> 6, l = threadIdx.x & 63;
    int r0 = blockIdx.x * 64 + w * 16;
    int lm = l & 15, lh = l >> 4;
    f32x4 acc[8];
    f32x4 zero = {0.f, 0.f, 0.f, 0.f};
#pragma unroll
    for (int n = 0; n < 8; ++n) acc[n] = zero;
    const __half* As[2] = { P.A1[g], P.A2[g] };
    const uint4* wg = (const uint4*)P.Wt[g];
    int arow = r0 + lm;
    bool rok = arow < NNODE;
    for (int s = 0; s < 2; ++s) {
        __syncthreads();
        for (int u = threadIdx.x; u < 2048; u += 256) {
            int col = u >> 4, kb8 = u & 15;
            uint4 vv = wg[col * 32 + s * 16 + kb8];
            *(uint4*)&sW[col * 136 + kb8 * 8] = vv;
        }
        __syncthreads();
        const uint4* a4 = (const uint4*)As[s];
#pragma unroll
        for (int kk = 0; kk < 4; ++kk) {
            uint4 av = make_uint4(0, 0, 0, 0);
            if (rok) av = a4[(size_t)arow * 16 + kk * 4 + lh];
            f16x8 af = *(f16x8*)&av;
#pragma unroll
            for (int n = 0; n < 8; ++n) {
                uint4 bv = *(uint4*)&sW[(n * 16 + lm) * 136 + kk * 32 + lh * 8];
                f16x8 bf = *(f16x8*)&bv;
                acc[n] = __builtin_amdgcn_mfma_f32_16x16x32_f16(af, bf, acc[n], 0, 0, 0);
            }
        }
    }
    __half* out = P.out[g];
    const float* bs = P.bs[g];
#pragma unroll
    for (int n = 0; n < 8; ++n) {
        int colg = n * 16 + lm;
        float bb = bs[colg];
#pragma unroll
        for (int qq = 0; qq < 4; ++qq) {
            int rowg = r0 + lh * 4 + qq;
            if (rowg < NNODE) {
                float v = fmaf(acc[n][qq], 0.5f, bb);
                out[(size_t)rowg * 128 + colg] = __float2half(v > 0.f ? v : 0.f);
            }
        }
    }
}

struct Lin16P { const __half* x[2]; const float* W[2]; const float* b[2]; float* out[2]; };
__global__ __launch_bounds__(256) void lin16_k(Lin16P P) {
    int g = blockIdx.y;
    int idx = blockIdx.x * 256 + threadIdx.x;
    int row = idx >> 4, c = idx & 15;
    if (row >= NNODE) return;
    const __half* xr = P.x[g] + (size_t)row * 128;
    const float* W = P.W[g];
    float acc = P.b[g][c];
    for (int k = 0; k < 128; ++k) acc += __half2float(xr[k]) * W[k * 16 + c];
    P.out[g][(size_t)row * 16 + c] = acc;
}

extern "C" void kernel_launch(void* const* d_in, const int* in_sizes, int n_in,
                              void* d_out, int out_size, void* d_ws, size_t ws_size,
                              hipStream_t stream) {
    (void)in_sizes; (void)n_in; (void)out_size; (void)ws_size;

    const float* x_gen  = (const float*)d_in[0];
    const float* x_rain = (const float*)d_in[1];
    const int* ei[4] = {(const int*)d_in[2], (const int*)d_in[3], (const int*)d_in[4], (const int*)d_in[5]};
    const float* w[4] = {(const float*)d_in[6], (const float*)d_in[7], (const float*)d_in[8], (const float*)d_in[9]};
    const float* W_conv = (const float*)d_in[10];
    const float* b_conv = (const float*)d_in[11];
    const float* W_lg = (const float*)d_in[12];
    const float* b_lg = (const float*)d_in[13];
    const float* W_lr = (const float*)d_in[14];
    const float* b_lr = (const float*)d_in[15];

    float* out_gen  = (float*)d_out;
    float* out_rain = out_gen + (size_t)NNODE * DOUT;

    char* p = (char*)d_ws;
    auto alloc = [&](size_t bytes) -> void* {
        void* r = (void*)p;
        p += (bytes + 255) & ~(size_t)255;
        return r;
    };

    // dinv vectors: [gg | rr | gr_s | rg_s]
    float* deg = (float*)alloc(4 * (size_t)NNODE * sizeof(float));
    float* dinv_gg   = deg + 0 * NNODE;
    float* dinv_rr   = deg + 1 * NNODE;
    float* dinv_gr_s = deg + 2 * NNODE;
    float* dinv_rg_s = deg + 3 * NNODE;

    int* rowptr_all = (int*)alloc(4 * (size_t)(NNODE + 1) * sizeof(int));
    int* cnt1       = (int*)alloc(4 * (size_t)NBKT * NCH * sizeof(int));
    int* bktbase    = (int*)alloc(4 * (size_t)(NBKT + 1) * sizeof(int));

    // ep region: max(packed edges 9.92 MB, degAll partials 10.24 MB)
    size_t epack_bytes = 4 * (size_t)NES * sizeof(unsigned int);
    size_t part_bytes  = 4 * (size_t)SB * NNODE * sizeof(float);
    unsigned int* epack_all = (unsigned int*)alloc(epack_bytes > part_bytes ? epack_bytes : part_bytes);
    float* part_all = (float*)epack_all;   // dead before part2 writes ep

    // agg region (20.48 MB) hosts bucket storage (19.2 MB, dead after part2)
    __half* agg_all = (__half*)alloc(4 * (size_t)NNODE * DF * sizeof(__half));
    __half* aggh_gg = agg_all + 0 * (size_t)NNODE * DF;
    __half* aggh_gr = agg_all + 1 * (size_t)NNODE * DF;
    __half* aggh_rg = agg_all + 2 * (size_t)NNODE * DF;
    __half* aggh_rr = agg_all + 3 * (size_t)NNODE * DF;
    uint2* bk_all = (uint2*)agg_all;

    __half* xh_gen  = (__half*)alloc((size_t)NNODE * DF * sizeof(__half));
    __half* xh_rain = (__half*)alloc((size_t)NNODE * DF * sizeof(__half));
    __half* WtH  = (__half*)alloc(4 * (size_t)128 * 256 * sizeof(__half));
    float*  bsum = (float*)alloc(4 * 128 * sizeof(float));

    int* rowptr[4]; unsigned int* ep[4]; uint2* bk[4];
    for (int r = 0; r < 4; ++r) {
        rowptr[r] = rowptr_all + (size_t)r * (NNODE + 1);
        ep[r]     = epack_all + (size_t)r * NES;
        bk[r]     = bk_all + (size_t)r * NE;
    }

    const int* rows_[4] = {ei[0], ei[1], ei[2], ei[3]};
    const int* cols_[4] = {ei[0] + NE, ei[1] + NE, ei[2] + NE, ei[3] + NE};

    // ---- W prep ----
    prepW_k<<<dim3(128, 4), 256, 0, stream>>>(W_conv, b_conv, WtH, bsum);

    // ---- bucket counts -> scans -> partition ----
    C1P C1;
    for (int r = 0; r < 4; ++r) C1.col[r] = cols_[r];
    C1.cnt1 = cnt1;
    count1_k<<<dim3(NCH, 4), 256, 0, stream>>>(C1);
    scan1_k<<<4, 128, 0, stream>>>(cnt1, bktbase);

    P1P P1;
    for (int r = 0; r < 4; ++r) {
        P1.row[r] = rows_[r]; P1.col[r] = cols_[r]; P1.w[r] = w[r]; P1.bk[r] = bk[r];
    }
    P1.choff = cnt1;
    P1.bktbase = bktbase;
    part1_k<<<dim3(NCH, 4), 256, 0, stream>>>(P1);

    // ---- 4 global degree streams (partials in ep region, dead before part2) ----
    DegAP DA;
    DA.idx[0] = cols_[0]; DA.wgt[0] = w[0];   // gg dst
    DA.idx[1] = cols_[3]; DA.wgt[1] = w[3];   // rr dst
    DA.idx[2] = rows_[1]; DA.wgt[2] = w[1];   // gr src
    DA.idx[3] = rows_[2]; DA.wgt[3] = w[2];   // rg src
    DA.part = part_all;
    degAll_part_k<<<dim3(SB * 2, 4), 256, 0, stream>>>(DA);

    DegAS DAS;
    DAS.part = part_all;
    DAS.dinv[0] = dinv_gg;   DAS.selfw[0] = 1.f;
    DAS.dinv[1] = dinv_rr;   DAS.selfw[1] = 1.f;
    DAS.dinv[2] = dinv_gr_s; DAS.selfw[2] = 0.f;
    DAS.dinv[3] = dinv_rg_s; DAS.selfw[3] = 0.f;
    degAll_sum_k<<<dim3(ceil_div(NNODE, 256), 4), 256, 0, stream>>>(DAS);

    // ---- part2: bucket -> CSR segment (sequential ep writes) ----
    P2P P2;
    for (int r = 0; r < 4; ++r) { P2.bk[r] = bk[r]; P2.rowptr[r] = rowptr[r]; P2.ep[r] = ep[r]; }
    P2.bktbase = bktbase;
    P2.dS[0] = dinv_gg;   P2.dDg[0] = dinv_gg;   P2.self[0] = 1;
    P2.dS[1] = dinv_gr_s; P2.dDg[1] = nullptr;   P2.self[1] = 0;
    P2.dS[2] = dinv_rg_s; P2.dDg[2] = nullptr;   P2.self[2] = 0;
    P2.dS[3] = dinv_rr;   P2.dDg[3] = dinv_rr;   P2.self[3] = 1;
    part2_k<<<dim3(NBKT, 4), 256, 0, stream>>>(P2);

    // ---- fp16 features ----
    CvtP CV;
    CV.in[0] = x_gen;  CV.out[0] = xh_gen;
    CV.in[1] = x_rain; CV.out[1] = xh_rain;
    cvt_k<<<dim3(NNODE * DF / 4 / 256, 2), 256, 0, stream>>>(CV);

    // ---- layers ----
    for (int l = 0; l < 2; ++l) {
        SpmmP SP;
        for (int r = 0; r < 4; ++r) { SP.rowptr[r] = rowptr[r]; SP.ep[r] = ep[r]; }
        SP.x[0] = xh_gen; SP.x[1] = xh_gen; SP.x[2] = xh_rain; SP.x[3] = xh_rain;
        SP.out[0] = aggh_gg; SP.out[1] = aggh_gr; SP.out[2] = aggh_rg; SP.out[3] = aggh_rr;
        spmm4_k<<<20000, 256, 0, stream>>>(SP);

        Gemm2P GP;
        GP.A1[0] = aggh_gg; GP.A2[0] = aggh_rg;
        GP.A1[1] = aggh_gr; GP.A2[1] = aggh_rr;
        GP.Wt[0] = WtH + (size_t)(l * 2 + 0) * 128 * 256;
        GP.Wt[1] = WtH + (size_t)(l * 2 + 1) * 128 * 256;
        GP.bs[0] = bsum + (l * 2 + 0) * 128;
        GP.bs[1] = bsum + (l * 2 + 1) * 128;
        GP.out[0] = xh_gen;
        GP.out[1] = xh_rain;
        gemm2_k<<<dim3(ceil_div(NNODE, 64), 2), 256, 0, stream>>>(GP);
    }

    // ---- output heads ----
    Lin16P LP;
    LP.x[0] = xh_gen;  LP.W[0] = W_lg; LP.b[0] = b_lg; LP.out[0] = out_gen;
    LP.x[1] = xh_rain; LP.W[1] = W_lr; LP.b[1] = b_lr; LP.out[1] = out_rain;
    lin16_k<<<dim3(ceil_div(NNODE * DOUT, 256), 2), 256, 0, stream>>>(LP);
}

// Round 12
// 282.800 us; speedup vs baseline: 9.7577x; 1.0015x over previous
//
#include <hip/hip_runtime.h>
#include <hip/hip_fp16.h>

#define NNODE 20000
#define NE    600000
#define NES   (NE + NNODE)   // ep stride incl. self slots (used by gg, rr)
#define DF    128
#define DOUT  16
#define NBKT  80          // dst buckets
#define RNG   250         // nodes per bucket (80*250 = 20000 exact)
#define NCH   128         // partition chunks
#define CHE   4688        // edges per chunk (128*4688 >= NE)
#define P2CAP 12288       // part2 staging capacity
#define SB    32          // degree chunks per stream
#define CS    (NE/SB)     // 18750

typedef _Float16 f16x8 __attribute__((ext_vector_type(8)));
typedef _Float16 f16x2 __attribute__((ext_vector_type(2)));
typedef float f32x4 __attribute__((ext_vector_type(4)));

static inline int ceil_div(int a, int b) { return (a + b - 1) / b; }

// ---------------- fp32 -> fp16 conversion ----------------
struct CvtP { const float* in[2]; __half* out[2]; };
__global__ __launch_bounds__(256) void cvt_k(CvtP P) {
    int g = blockIdx.y;
    int i = blockIdx.x * 256 + threadIdx.x;
    const float4* in = (const float4*)P.in[g];
    __half2* out = (__half2*)P.out[g];
    float4 v = in[i];
    out[2 * i + 0] = __floats2half2_rn(v.x, v.y);
    out[2 * i + 1] = __floats2half2_rn(v.z, v.w);
}

// ---------------- W prep: combined, transposed, fp16 + folded bias ----------------
__global__ __launch_bounds__(256) void prepW_k(const float* __restrict__ W_conv,
                                               const float* __restrict__ b_conv,
                                               __half* __restrict__ WtH,
                                               float* __restrict__ bsum) {
    int lg = blockIdx.y;
    int l = lg >> 1, g = lg & 1;
    int ra = (g == 0) ? 0 : 1;
    int rb = (g == 0) ? 2 : 3;
    int idx = blockIdx.x * 256 + threadIdx.x;
    int col = idx >> 8, k = idx & 255;
    const float* Wa = W_conv + (size_t)(l * 4 + ra) * 128 * 128;
    const float* Wb = W_conv + (size_t)(l * 4 + rb) * 128 * 128;
    float v = (k < 128) ? Wa[k * 128 + col] : Wb[(k - 128) * 128 + col];
    WtH[((size_t)lg * 128 + col) * 256 + k] = __float2half(v);
    if (idx < 128)
        bsum[lg * 128 + idx] = 0.5f * (b_conv[(l * 4 + ra) * 128 + idx] +
                                       b_conv[(l * 4 + rb) * 128 + idx]);
}

// ---------------- bucket counts per (relation, chunk) ----------------
struct C1P { const int* col[4]; int* cnt1; };
__global__ __launch_bounds__(256) void count1_k(C1P P) {
    __shared__ int h[NBKT];
    int ch = blockIdx.x, r = blockIdx.y;
    for (int i = threadIdx.x; i < NBKT; i += 256) h[i] = 0;
    __syncthreads();
    const int* col = P.col[r];
    int e0 = ch * CHE, e1 = min(NE, e0 + CHE);
    for (int e = e0 + threadIdx.x; e < e1; e += 256) atomicAdd(&h[col[e] / RNG], 1);
    __syncthreads();
    int* out = P.cnt1 + (size_t)r * NBKT * NCH;
    for (int b = threadIdx.x; b < NBKT; b += 256) out[b * NCH + ch] = h[b];
}

// ---------------- scans: chunk offsets within bucket + bucket bases ----------------
__global__ __launch_bounds__(128) void scan1_k(int* __restrict__ cnt1, int* __restrict__ bktbase) {
    __shared__ int tot[NBKT];
    int r = blockIdx.x;
    int* base = cnt1 + (size_t)r * NBKT * NCH;
    for (int b = threadIdx.x; b < NBKT; b += 128) {
        int run = 0;
        int* pb = base + b * NCH;
        for (int ch = 0; ch < NCH; ++ch) { int v = pb[ch]; pb[ch] = run; run += v; }
        tot[b] = run;
    }
    __syncthreads();
    if (threadIdx.x == 0) {
        int run = 0;
        int* bb = bktbase + r * (NBKT + 1);
        for (int b = 0; b < NBKT; ++b) { bb[b] = run; run += tot[b]; }
        bb[NBKT] = run;
    }
}

// ---------------- part1: sort chunk by bucket in LDS, flush runs coalesced ----------------
struct P1P {
    const int* row[4]; const int* col[4]; const float* w[4];
    const int* choff;
    const int* bktbase;
    uint2* bk[4];
};
__global__ __launch_bounds__(256) void part1_k(P1P P) {
    __shared__ uint2 st[CHE];
    __shared__ int h[NBKT];
    __shared__ int hoff[NBKT];
    __shared__ int c2[NBKT];
    int ch = blockIdx.x, r = blockIdx.y;
    for (int i = threadIdx.x; i < NBKT; i += 256) { h[i] = 0; c2[i] = 0; }
    __syncthreads();
    const int* col = P.col[r];
    const int* row = P.row[r];
    const float* w = P.w[r];
    int e0 = ch * CHE, e1 = min(NE, e0 + CHE);
    for (int e = e0 + threadIdx.x; e < e1; e += 256) atomicAdd(&h[col[e] / RNG], 1);
    __syncthreads();
    if (threadIdx.x == 0) {
        int run = 0;
        for (int b = 0; b < NBKT; ++b) { hoff[b] = run; run += h[b]; }
    }
    __syncthreads();
    for (int e = e0 + threadIdx.x; e < e1; e += 256) {
        int c = col[e];
        int b = c / RNG;
        int slot = hoff[b] + atomicAdd(&c2[b], 1);
        uint2 v;
        v.x = ((unsigned)c << 15) | (unsigned)row[e];
        v.y = (unsigned)__float_as_int(w[e]);
        st[slot] = v;
    }
    __syncthreads();
    const int* choff = P.choff + (size_t)r * NBKT * NCH;
    const int* bb = P.bktbase + r * (NBKT + 1);
    uint2* bk = P.bk[r];
    for (int b = 0; b < NBKT; ++b) {
        int base = bb[b] + choff[b * NCH + ch];
        int m = h[b];
        int lo = hoff[b];
        for (int i = threadIdx.x; i < m; i += 256) bk[base + i] = st[lo + i];
    }
}

// ---------------- 4 global degree streams (gg col, rr col, gr row, rg row) ----------------
struct DegAP { const int* idx[4]; const float* wgt[4]; float* part; };
__global__ __launch_bounds__(256) void degAll_part_k(DegAP P) {
    __shared__ float t[NNODE / 2];
    int s = blockIdx.y;
    int chunk = blockIdx.x >> 1, half = blockIdx.x & 1;
    int nbase = half * (NNODE / 2);
    for (int i = threadIdx.x; i < NNODE / 2; i += 256) t[i] = 0.f;
    __syncthreads();
    const int* idx = P.idx[s];
    const float* w = P.wgt[s];
    int e0 = chunk * CS;
    for (int e = e0 + threadIdx.x; e < e0 + CS; e += 256) {
        int rr = idx[e] - nbase;
        if ((unsigned)rr < (unsigned)(NNODE / 2)) atomicAdd(&t[rr], w[e]);
    }
    __syncthreads();
    float* pp = P.part + ((size_t)s * SB + chunk) * NNODE + nbase;
    for (int i = threadIdx.x; i < NNODE / 2; i += 256) pp[i] = t[i];
}

struct DegAS { const float* part; float* dinv[4]; float selfw[4]; };
__global__ __launch_bounds__(256) void degAll_sum_k(DegAS P) {
    int s = blockIdx.y;
    int n = blockIdx.x * 256 + threadIdx.x;
    if (n >= NNODE) return;
    const float* pp = P.part + (size_t)s * SB * NNODE + n;
    float acc = P.selfw[s];
    for (int c = 0; c < SB; ++c) acc += pp[(size_t)c * NNODE];
    P.dinv[s][n] = acc > 0.f ? rsqrtf(acc) : 0.f;
}

// ---------------- part2: bucket -> CSR segment ----------------
struct P2P {
    const uint2* bk[4];
    const int* bktbase;
    const float* dS[4];
    const float* dDg[4];
    int self[4];
    int* rowptr[4];
    unsigned int* ep[4];
};
__global__ __launch_bounds__(256) void part2_k(P2P P) {
    __shared__ unsigned int st[P2CAP];
    __shared__ float wsum[RNG];
    __shared__ int cnt[RNG];
    __shared__ int off[RNG + 1];
    __shared__ int cur[RNG];
    int bkt = blockIdx.x, r = blockIdx.y;
    int selfF = P.self[r];
    const int* bb = P.bktbase + r * (NBKT + 1);
    int b0 = bb[bkt], n = bb[bkt + 1] - b0;
    for (int i = threadIdx.x; i < RNG; i += 256) { wsum[i] = 0.f; cnt[i] = 0; cur[i] = 0; }
    __syncthreads();
    const uint2* bk = P.bk[r];
    int nlo = bkt * RNG;
    for (int i = threadIdx.x; i < n; i += 256) {
        uint2 rec = bk[b0 + i];
        int cl = (int)(rec.x >> 15) - nlo;
        atomicAdd(&cnt[cl], 1);
        if (!selfF) atomicAdd(&wsum[cl], __int_as_float((int)rec.y));
    }
    __syncthreads();
    if (threadIdx.x == 0) {
        int run = 0;
        for (int c = 0; c < RNG; ++c) { off[c] = run; run += cnt[c] + selfF; }
        off[RNG] = run;
    }
    __syncthreads();
    int ntot = off[RNG];
    int epseg = b0 + (selfF ? nlo : 0);
    int* rp = P.rowptr[r];
    for (int c = threadIdx.x; c < RNG; c += 256) rp[nlo + c] = epseg + off[c];
    if (bkt == NBKT - 1 && threadIdx.x == 0) rp[NNODE] = epseg + ntot;
    const float* dDg = P.dDg[r];
    if (!selfF) {
        for (int c = threadIdx.x; c < RNG; c += 256) {
            float s = wsum[c];
            wsum[c] = s > 0.f ? rsqrtf(s) : 0.f;
        }
    }
    __syncthreads();
    if (selfF) {
        for (int c = threadIdx.x; c < RNG; c += 256) {
            float d = dDg[nlo + c];
            __half hh = __float2half(d * d);
            st[off[c]] = ((unsigned)(nlo + c) << 16) | *reinterpret_cast<unsigned short*>(&hh);
        }
    }
    const float* dS = P.dS[r];
    for (int i = threadIdx.x; i < n; i += 256) {
        uint2 rec = bk[b0 + i];
        int cg = (int)(rec.x >> 15);
        int cl = cg - nlo;
        int src = (int)(rec.x & 0x7fffu);
        float w = __int_as_float((int)rec.y);
        float dD = selfF ? dDg[cg] : wsum[cl];
        float nm = dS[src] * w * dD;
        int slot = off[cl] + selfF + atomicAdd(&cur[cl], 1);
        __half hh = __float2half(nm);
        st[slot] = ((unsigned)src << 16) | *reinterpret_cast<unsigned short*>(&hh);
    }
    __syncthreads();
    unsigned int* ep = P.ep[r];
    for (int i = threadIdx.x; i < ntot; i += 256) ep[epseg + i] = st[i];
}

// ---------------- pull-SpMM: quarter-wave gather + v_dot2_f32_f16 pairs ----------------
struct SpmmP {
    const __half* x[4]; const int* rowptr[4]; const unsigned int* ep[4]; __half* out[4];
};
__global__ __launch_bounds__(256) void spmm4_k(SpmmP P) {
    int b = blockIdx.x;
    int xcd = b & 7;
    int j = b >> 3;
    int r = ((xcd >> 2) << 1) + (j >= 1250 ? 1 : 0);
    int nodeblk = (xcd & 3) * 1250 + (j >= 1250 ? j - 1250 : j);
    int wid = nodeblk * 4 + (threadIdx.x >> 6);
    int lane = threadIdx.x & 63;
    int q = lane >> 4, c = lane & 15;
    const uint4* x4 = (const uint4*)P.x[r];
    const int* rp = P.rowptr[r];
    int bb = rp[wid], ee = rp[wid + 1];
    const unsigned int* ep = P.ep[r];
    float a[8];
#pragma unroll
    for (int t = 0; t < 8; ++t) a[t] = 0.f;

    auto decn = [](unsigned int v) -> float {
        unsigned short us = (unsigned short)(v & 0xffffu);
        __half h = *reinterpret_cast<__half*>(&us);
        return __half2float(h);
    };
    auto accum1 = [&](uint4 p, float n) {
        const __half2* ph = (const __half2*)&p;
#pragma unroll
        for (int t = 0; t < 4; ++t) {
            float2 f = __half22float2(ph[t]);
            a[2 * t]     = fmaf(f.x, n, a[2 * t]);
            a[2 * t + 1] = fmaf(f.y, n, a[2 * t + 1]);
        }
    };
    // two edges per call: acc[j] += x0[j]*n0 + x1[j]*n1 via v_perm + v_dot2_f32_f16
    auto accum2 = [&](uint4 p0, uint4 p1, unsigned n01) {
        f16x2 nn = __builtin_bit_cast(f16x2, n01);
        const unsigned* u0 = (const unsigned*)&p0;
        const unsigned* u1 = (const unsigned*)&p1;
#pragma unroll
        for (int t = 0; t < 4; ++t) {
            unsigned plo = __builtin_amdgcn_perm(u1[t], u0[t], 0x05040100u); // (x0.lo, x1.lo)
            unsigned phi = __builtin_amdgcn_perm(u1[t], u0[t], 0x07060302u); // (x0.hi, x1.hi)
            a[2 * t]     = __builtin_amdgcn_fdot2(__builtin_bit_cast(f16x2, plo), nn, a[2 * t], false);
            a[2 * t + 1] = __builtin_amdgcn_fdot2(__builtin_bit_cast(f16x2, phi), nn, a[2 * t + 1], false);
        }
    };

    int i = bb + q;
    for (; i + 12 < ee; i += 16) {                // 4 edges per quarter in flight
        unsigned v0 = ep[i], v1 = ep[i + 4], v2 = ep[i + 8], v3 = ep[i + 12];
        uint4 p0 = x4[(size_t)(v0 >> 16) * 16 + c];
        uint4 p1 = x4[(size_t)(v1 >> 16) * 16 + c];
        uint4 p2 = x4[(size_t)(v2 >> 16) * 16 + c];
        uint4 p3 = x4[(size_t)(v3 >> 16) * 16 + c];
        unsigned n01 = __builtin_amdgcn_perm(v1, v0, 0x05040100u);
        unsigned n23 = __builtin_amdgcn_perm(v3, v2, 0x05040100u);
        accum2(p0, p1, n01);
        accum2(p2, p3, n23);
    }
    for (; i + 4 < ee; i += 8) {                  // 2 edges
        unsigned v0 = ep[i], v1 = ep[i + 4];
        uint4 p0 = x4[(size_t)(v0 >> 16) * 16 + c];
        uint4 p1 = x4[(size_t)(v1 >> 16) * 16 + c];
        unsigned n01 = __builtin_amdgcn_perm(v1, v0, 0x05040100u);
        accum2(p0, p1, n01);
    }
    if (i < ee) {
        unsigned v0 = ep[i];
        uint4 p0 = x4[(size_t)(v0 >> 16) * 16 + c];
        accum1(p0, decn(v0));
    }
#pragma unroll
    for (int t = 0; t < 8; ++t) {
        a[t] += __shfl_xor(a[t], 16, 64);
        a[t] += __shfl_xor(a[t], 32, 64);
    }
    if (q == 0) {
        __half2 h[4];
#pragma unroll
        for (int t = 0; t < 4; ++t) h[t] = __floats2half2_rn(a[2 * t], a[2 * t + 1]);
        ((uint4*)P.out[r])[(size_t)wid * 16 + c] = *(uint4*)h;
    }
}

// ---------------- MFMA gemm2 ----------------
struct Gemm2P {
    const __half* A1[2]; const __half* A2[2];
    const __half* Wt[2];
    const float* bs[2];
    __half* out[2];
};
__global__ __launch_bounds__(256) void gemm2_k(Gemm2P P) {
    __shared__ __half sW[128 * 136];
    int g = blockIdx.y;
    int w = threadIdx.x >> 6, l = threadIdx.x & 63;
    int r0 = blockIdx.x * 64 + w * 16;
    int lm = l & 15, lh = l >> 4;
    f32x4 acc[8];
    f32x4 zero = {0.f, 0.f, 0.f, 0.f};
#pragma unroll
    for (int n = 0; n < 8; ++n) acc[n] = zero;
    const __half* As[2] = { P.A1[g], P.A2[g] };
    const uint4* wg = (const uint4*)P.Wt[g];
    int arow = r0 + lm;
    bool rok = arow < NNODE;
    for (int s = 0; s < 2; ++s) {
        __syncthreads();
        for (int u = threadIdx.x; u < 2048; u += 256) {
            int col = u >> 4, kb8 = u & 15;
            uint4 vv = wg[col * 32 + s * 16 + kb8];
            *(uint4*)&sW[col * 136 + kb8 * 8] = vv;
        }
        __syncthreads();
        const uint4* a4 = (const uint4*)As[s];
#pragma unroll
        for (int kk = 0; kk < 4; ++kk) {
            uint4 av = make_uint4(0, 0, 0, 0);
            if (rok) av = a4[(size_t)arow * 16 + kk * 4 + lh];
            f16x8 af = *(f16x8*)&av;
#pragma unroll
            for (int n = 0; n < 8; ++n) {
                uint4 bv = *(uint4*)&sW[(n * 16 + lm) * 136 + kk * 32 + lh * 8];
                f16x8 bf = *(f16x8*)&bv;
                acc[n] = __builtin_amdgcn_mfma_f32_16x16x32_f16(af, bf, acc[n], 0, 0, 0);
            }
        }
    }
    __half* out = P.out[g];
    const float* bs = P.bs[g];
#pragma unroll
    for (int n = 0; n < 8; ++n) {
        int colg = n * 16 + lm;
        float bb = bs[colg];
#pragma unroll
        for (int qq = 0; qq < 4; ++qq) {
            int rowg = r0 + lh * 4 + qq;
            if (rowg < NNODE) {
                float v = fmaf(acc[n][qq], 0.5f, bb);
                out[(size_t)rowg * 128 + colg] = __float2half(v > 0.f ? v : 0.f);
            }
        }
    }
}

struct Lin16P { const __half* x[2]; const float* W[2]; const float* b[2]; float* out[2]; };
__global__ __launch_bounds__(256) void lin16_k(Lin16P P) {
    int g = blockIdx.y;
    int idx = blockIdx.x * 256 + threadIdx.x;
    int row = idx >> 4, c = idx & 15;
    if (row >= NNODE) return;
    const __half* xr = P.x[g] + (size_t)row * 128;
    const float* W = P.W[g];
    float acc = P.b[g][c];
    for (int k = 0; k < 128; ++k) acc += __half2float(xr[k]) * W[k * 16 + c];
    P.out[g][(size_t)row * 16 + c] = acc;
}

extern "C" void kernel_launch(void* const* d_in, const int* in_sizes, int n_in,
                              void* d_out, int out_size, void* d_ws, size_t ws_size,
                              hipStream_t stream) {
    (void)in_sizes; (void)n_in; (void)out_size; (void)ws_size;

    const float* x_gen  = (const float*)d_in[0];
    const float* x_rain = (const float*)d_in[1];
    const int* ei[4] = {(const int*)d_in[2], (const int*)d_in[3], (const int*)d_in[4], (const int*)d_in[5]};
    const float* w[4] = {(const float*)d_in[6], (const float*)d_in[7], (const float*)d_in[8], (const float*)d_in[9]};
    const float* W_conv = (const float*)d_in[10];
    const float* b_conv = (const float*)d_in[11];
    const float* W_lg = (const float*)d_in[12];
    const float* b_lg = (const float*)d_in[13];
    const float* W_lr = (const float*)d_in[14];
    const float* b_lr = (const float*)d_in[15];

    float* out_gen  = (float*)d_out;
    float* out_rain = out_gen + (size_t)NNODE * DOUT;

    char* p = (char*)d_ws;
    auto alloc = [&](size_t bytes) -> void* {
        void* r = (void*)p;
        p += (bytes + 255) & ~(size_t)255;
        return r;
    };

    float* deg = (float*)alloc(4 * (size_t)NNODE * sizeof(float));
    float* dinv_gg   = deg + 0 * NNODE;
    float* dinv_rr   = deg + 1 * NNODE;
    float* dinv_gr_s = deg + 2 * NNODE;
    float* dinv_rg_s = deg + 3 * NNODE;

    int* rowptr_all = (int*)alloc(4 * (size_t)(NNODE + 1) * sizeof(int));
    int* cnt1       = (int*)alloc(4 * (size_t)NBKT * NCH * sizeof(int));
    int* bktbase    = (int*)alloc(4 * (size_t)(NBKT + 1) * sizeof(int));

    size_t epack_bytes = 4 * (size_t)NES * sizeof(unsigned int);
    size_t part_bytes  = 4 * (size_t)SB * NNODE * sizeof(float);
    unsigned int* epack_all = (unsigned int*)alloc(epack_bytes > part_bytes ? epack_bytes : part_bytes);
    float* part_all = (float*)epack_all;

    __half* agg_all = (__half*)alloc(4 * (size_t)NNODE * DF * sizeof(__half));
    __half* aggh_gg = agg_all + 0 * (size_t)NNODE * DF;
    __half* aggh_gr = agg_all + 1 * (size_t)NNODE * DF;
    __half* aggh_rg = agg_all + 2 * (size_t)NNODE * DF;
    __half* aggh_rr = agg_all + 3 * (size_t)NNODE * DF;
    uint2* bk_all = (uint2*)agg_all;

    __half* xh_gen  = (__half*)alloc((size_t)NNODE * DF * sizeof(__half));
    __half* xh_rain = (__half*)alloc((size_t)NNODE * DF * sizeof(__half));
    __half* WtH  = (__half*)alloc(4 * (size_t)128 * 256 * sizeof(__half));
    float*  bsum = (float*)alloc(4 * 128 * sizeof(float));

    int* rowptr[4]; unsigned int* ep[4]; uint2* bk[4];
    for (int r = 0; r < 4; ++r) {
        rowptr[r] = rowptr_all + (size_t)r * (NNODE + 1);
        ep[r]     = epack_all + (size_t)r * NES;
        bk[r]     = bk_all + (size_t)r * NE;
    }

    const int* rows_[4] = {ei[0], ei[1], ei[2], ei[3]};
    const int* cols_[4] = {ei[0] + NE, ei[1] + NE, ei[2] + NE, ei[3] + NE};

    prepW_k<<<dim3(128, 4), 256, 0, stream>>>(W_conv, b_conv, WtH, bsum);

    C1P C1;
    for (int r = 0; r < 4; ++r) C1.col[r] = cols_[r];
    C1.cnt1 = cnt1;
    count1_k<<<dim3(NCH, 4), 256, 0, stream>>>(C1);
    scan1_k<<<4, 128, 0, stream>>>(cnt1, bktbase);

    P1P P1;
    for (int r = 0; r < 4; ++r) {
        P1.row[r] = rows_[r]; P1.col[r] = cols_[r]; P1.w[r] = w[r]; P1.bk[r] = bk[r];
    }
    P1.choff = cnt1;
    P1.bktbase = bktbase;
    part1_k<<<dim3(NCH, 4), 256, 0, stream>>>(P1);

    DegAP DA;
    DA.idx[0] = cols_[0]; DA.wgt[0] = w[0];
    DA.idx[1] = cols_[3]; DA.wgt[1] = w[3];
    DA.idx[2] = rows_[1]; DA.wgt[2] = w[1];
    DA.idx[3] = rows_[2]; DA.wgt[3] = w[2];
    DA.part = part_all;
    degAll_part_k<<<dim3(SB * 2, 4), 256, 0, stream>>>(DA);

    DegAS DAS;
    DAS.part = part_all;
    DAS.dinv[0] = dinv_gg;   DAS.selfw[0] = 1.f;
    DAS.dinv[1] = dinv_rr;   DAS.selfw[1] = 1.f;
    DAS.dinv[2] = dinv_gr_s; DAS.selfw[2] = 0.f;
    DAS.dinv[3] = dinv_rg_s; DAS.selfw[3] = 0.f;
    degAll_sum_k<<<dim3(ceil_div(NNODE, 256), 4), 256, 0, stream>>>(DAS);

    P2P P2;
    for (int r = 0; r < 4; ++r) { P2.bk[r] = bk[r]; P2.rowptr[r] = rowptr[r]; P2.ep[r] = ep[r]; }
    P2.bktbase = bktbase;
    P2.dS[0] = dinv_gg;   P2.dDg[0] = dinv_gg;   P2.self[0] = 1;
    P2.dS[1] = dinv_gr_s; P2.dDg[1] = nullptr;   P2.self[1] = 0;
    P2.dS[2] = dinv_rg_s; P2.dDg[2] = nullptr;   P2.self[2] = 0;
    P2.dS[3] = dinv_rr;   P2.dDg[3] = dinv_rr;   P2.self[3] = 1;
    part2_k<<<dim3(NBKT, 4), 256, 0, stream>>>(P2);

    CvtP CV;
    CV.in[0] = x_gen;  CV.out[0] = xh_gen;
    CV.in[1] = x_rain; CV.out[1] = xh_rain;
    cvt_k<<<dim3(NNODE * DF / 4 / 256, 2), 256, 0, stream>>>(CV);

    for (int l = 0; l < 2; ++l) {
        SpmmP SP;
        for (int r = 0; r < 4; ++r) { SP.rowptr[r] = rowptr[r]; SP.ep[r] = ep[r]; }
        SP.x[0] = xh_gen; SP.x[1] = xh_gen; SP.x[2] = xh_rain; SP.x[3] = xh_rain;
        SP.out[0] = aggh_gg; SP.out[1] = aggh_gr; SP.out[2] = aggh_rg; SP.out[3] = aggh_rr;
        spmm4_k<<<20000, 256, 0, stream>>>(SP);

        Gemm2P GP;
        GP.A1[0] = aggh_gg; GP.A2[0] = aggh_rg;
        GP.A1[1] = aggh_gr; GP.A2[1] = aggh_rr;
        GP.Wt[0] = WtH + (size_t)(l * 2 + 0) * 128 * 256;
        GP.Wt[1] = WtH + (size_t)(l * 2 + 1) * 128 * 256;
        GP.bs[0] = bsum + (l * 2 + 0) * 128;
        GP.bs[1] = bsum + (l * 2 + 1) * 128;
        GP.out[0] = xh_gen;
        GP.out[1] = xh_rain;
        gemm2_k<<<dim3(ceil_div(NNODE, 64), 2), 256, 0, stream>>>(GP);
    }

    Lin16P LP;
    LP.x[0] = xh_gen;  LP.W[0] = W_lg; LP.b[0] = b_lg; LP.out[0] = out_gen;
    LP.x[1] = xh_rain; LP.W[1] = W_lr; LP.b[1] = b_lr; LP.out[1] = out_rain;
    lin16_k<<<dim3(ceil_div(NNODE * DOUT, 256), 2), 256, 0, stream>>>(LP);
}